// Round 1
// baseline (2879.006 us; speedup 1.0000x reference)
//
#include <hip/hip_runtime.h>

#define BATCH 32
#define NPT   1024
#define CC    14
#define KNN   9
#define EDIM  128
#define HDIM  128
#define NCLS  25
#define FEAT1 452            // 2*E + C*C
#define BN    (BATCH*NPT)
#define NPB   2              // nodes per block in edge kernels

__device__ __forceinline__ float silu_f(float x) { return x / (1.0f + __expf(-x)); }

// ---------------- K1: Hh = emb[S] + time_emb(t) ----------------
__global__ __launch_bounds__(128) void k_hh(
    const float* __restrict__ t, const int* __restrict__ S,
    const float* __restrict__ emb,
    const float* __restrict__ Wt1, const float* __restrict__ bt1,
    const float* __restrict__ Wt2, const float* __restrict__ bt2,
    float* __restrict__ Hh)
{
    const int tid  = threadIdx.x;
    const int base = blockIdx.x * 8;
    __shared__ __align__(16) float sf[8][128];

    const float step  = 1.0f / 127.0f;
    const float coeff = -0.5f / (step * step);
    const float off   = step * (float)tid;

    #pragma unroll
    for (int r = 0; r < 8; ++r) {
        float d = t[base + r] - off + 1e-6f;
        sf[r][tid] = __expf(coeff * d * d);
    }
    __syncthreads();

    float acc[8];
    #pragma unroll
    for (int r = 0; r < 8; ++r) acc[r] = 0.0f;
    for (int f4 = 0; f4 < 32; ++f4) {
        const float w0 = Wt1[(4*f4+0)*HDIM + tid];
        const float w1 = Wt1[(4*f4+1)*HDIM + tid];
        const float w2 = Wt1[(4*f4+2)*HDIM + tid];
        const float w3 = Wt1[(4*f4+3)*HDIM + tid];
        #pragma unroll
        for (int r = 0; r < 8; ++r) {
            const float4 v = *(const float4*)&sf[r][4*f4];
            float a = acc[r];
            a = fmaf(v.x, w0, a); a = fmaf(v.y, w1, a);
            a = fmaf(v.z, w2, a); a = fmaf(v.w, w3, a);
            acc[r] = a;
        }
    }
    __syncthreads();
    const float b1 = bt1[tid];
    #pragma unroll
    for (int r = 0; r < 8; ++r) sf[r][tid] = fmaxf(acc[r] + b1, 0.0f);
    __syncthreads();

    #pragma unroll
    for (int r = 0; r < 8; ++r) acc[r] = 0.0f;
    for (int f4 = 0; f4 < 32; ++f4) {
        const float w0 = Wt2[(4*f4+0)*EDIM + tid];
        const float w1 = Wt2[(4*f4+1)*EDIM + tid];
        const float w2 = Wt2[(4*f4+2)*EDIM + tid];
        const float w3 = Wt2[(4*f4+3)*EDIM + tid];
        #pragma unroll
        for (int r = 0; r < 8; ++r) {
            const float4 v = *(const float4*)&sf[r][4*f4];
            float a = acc[r];
            a = fmaf(v.x, w0, a); a = fmaf(v.y, w1, a);
            a = fmaf(v.z, w2, a); a = fmaf(v.w, w3, a);
            acc[r] = a;
        }
    }
    const float b2 = bt2[tid];
    #pragma unroll
    for (int r = 0; r < 8; ++r) {
        const int node = base + r;
        Hh[(size_t)node * EDIM + tid] = emb[S[node] * EDIM + tid] + acc[r] + b2;
    }
}

// ---------------- K2: KNN top-9 by squared distance on X[:,:,1,:] ----------------
__global__ __launch_bounds__(64) void k_knn(
    const float* __restrict__ X, int* __restrict__ idxb)
{
    const int node = blockIdx.x * 64 + threadIdx.x;
    const int b = node >> 10, n = node & 1023;
    const float* Xb = X + (size_t)b * NPT * CC * 3;

    const float cx = Xb[(n*CC + 1)*3 + 0];
    const float cy = Xb[(n*CC + 1)*3 + 1];
    const float cz = Xb[(n*CC + 1)*3 + 2];

    float dist[KNN]; int ind[KNN];
    #pragma unroll
    for (int k = 0; k < KNN; ++k) { dist[k] = 3.0e38f; ind[k] = -1; }

    for (int j = 0; j < NPT; ++j) {
        const float dx = __fsub_rn(cx, Xb[(j*CC + 1)*3 + 0]);
        const float dy = __fsub_rn(cy, Xb[(j*CC + 1)*3 + 1]);
        const float dz = __fsub_rn(cz, Xb[(j*CC + 1)*3 + 2]);
        // match numpy: (dx*dx + dy*dy) + dz*dz, no fma contraction
        float d = __fadd_rn(__fadd_rn(__fmul_rn(dx,dx), __fmul_rn(dy,dy)), __fmul_rn(dz,dz));
        if (j == n) d = __fadd_rn(d, 1e10f);
        if (d < dist[KNN-1]) {
            dist[KNN-1] = d; ind[KNN-1] = j;
            #pragma unroll
            for (int p = KNN-1; p > 0; --p) {
                if (dist[p] < dist[p-1]) {
                    float td = dist[p]; dist[p] = dist[p-1]; dist[p-1] = td;
                    int   ti = ind[p];  ind[p]  = ind[p-1];  ind[p-1]  = ti;
                }
            }
        }
    }
    #pragma unroll
    for (int k = 0; k < KNN; ++k) idxb[(size_t)node*KNN + k] = ind[k];
}

// ---------------- K3: edge features -> m -> (msum, w) ----------------
__global__ __launch_bounds__(128) void k_edge(
    const float* __restrict__ X, const float* __restrict__ Hh,
    const int* __restrict__ idxb,
    const float* __restrict__ We1, const float* __restrict__ be1,
    const float* __restrict__ We2, const float* __restrict__ be2,
    const float* __restrict__ Wx1, const float* __restrict__ bx1,
    const float* __restrict__ Wx2, const float* __restrict__ bx2,
    float* __restrict__ msum, float* __restrict__ wbuf)
{
    const int tid  = threadIdx.x;
    const int base = blockIdx.x * NPB;

    __shared__ __align__(16) float feat[NPB][KNN][FEAT1];   // silu'd input features
    __shared__ __align__(16) float sil1[NPB][KNN][HDIM];
    __shared__ float rl[NPB][CC*3];

    // ---- stage features (silu applied) ----
    for (int r = 0; r < NPB; ++r) {
        const int node = base + r;
        const int b = node >> 10, n = node & 1023;
        const float shi = silu_f(Hh[(size_t)node * EDIM + tid]);
        for (int k = 0; k < KNN; ++k) {
            const int j = idxb[(size_t)node*KNN + k];
            feat[r][k][tid]        = shi;
            feat[r][k][EDIM + tid] = silu_f(Hh[((size_t)(b << 10) + j) * EDIM + tid]);
            __syncthreads();   // previous iteration's radial reads of rl done
            if (tid < CC*3) {
                const int c = tid / 3, dc = tid % 3;
                rl[r][tid] = X[(((size_t)node)*CC + c)*3 + dc]
                           - X[(((size_t)(b << 10) + j)*CC + c)*3 + dc];
            }
            __syncthreads();
            {
                const int q = tid;           // 0..127
                const int c = q / CC, e = q % CC;
                float v = (rl[r][3*c]*rl[r][3*e] + rl[r][3*c+1]*rl[r][3*e+1]
                         + rl[r][3*c+2]*rl[r][3*e+2]) / 14.0f;
                feat[r][k][2*EDIM + q] = silu_f(v);
            }
            if (tid < CC*CC - 128) {         // q = 128..195
                const int q = tid + 128;
                const int c = q / CC, e = q % CC;
                float v = (rl[r][3*c]*rl[r][3*e] + rl[r][3*c+1]*rl[r][3*e+1]
                         + rl[r][3*c+2]*rl[r][3*e+2]) / 14.0f;
                feat[r][k][2*EDIM + q] = silu_f(v);
            }
        }
    }
    __syncthreads();

    // ---- layer 1: 452 -> 128 ----
    float acc1[NPB][KNN];
    #pragma unroll
    for (int r = 0; r < NPB; ++r)
        #pragma unroll
        for (int k = 0; k < KNN; ++k) acc1[r][k] = 0.0f;

    for (int f4 = 0; f4 < FEAT1/4; ++f4) {
        const float w0 = We1[(4*f4+0)*HDIM + tid];
        const float w1 = We1[(4*f4+1)*HDIM + tid];
        const float w2 = We1[(4*f4+2)*HDIM + tid];
        const float w3 = We1[(4*f4+3)*HDIM + tid];
        #pragma unroll
        for (int r = 0; r < NPB; ++r)
            #pragma unroll
            for (int k = 0; k < KNN; ++k) {
                const float4 v = *(const float4*)&feat[r][k][4*f4];
                float a = acc1[r][k];
                a = fmaf(v.x, w0, a); a = fmaf(v.y, w1, a);
                a = fmaf(v.z, w2, a); a = fmaf(v.w, w3, a);
                acc1[r][k] = a;
            }
    }
    const float b1 = be1[tid];
    #pragma unroll
    for (int r = 0; r < NPB; ++r)
        #pragma unroll
        for (int k = 0; k < KNN; ++k) sil1[r][k][tid] = silu_f(acc1[r][k] + b1);
    __syncthreads();

    // ---- layer 2: 128 -> 128, m ----
    float acc2[NPB][KNN];
    #pragma unroll
    for (int r = 0; r < NPB; ++r)
        #pragma unroll
        for (int k = 0; k < KNN; ++k) acc2[r][k] = 0.0f;
    for (int f4 = 0; f4 < HDIM/4; ++f4) {
        const float w0 = We2[(4*f4+0)*HDIM + tid];
        const float w1 = We2[(4*f4+1)*HDIM + tid];
        const float w2 = We2[(4*f4+2)*HDIM + tid];
        const float w3 = We2[(4*f4+3)*HDIM + tid];
        #pragma unroll
        for (int r = 0; r < NPB; ++r)
            #pragma unroll
            for (int k = 0; k < KNN; ++k) {
                const float4 v = *(const float4*)&sil1[r][k][4*f4];
                float a = acc2[r][k];
                a = fmaf(v.x, w0, a); a = fmaf(v.y, w1, a);
                a = fmaf(v.z, w2, a); a = fmaf(v.w, w3, a);
                acc2[r][k] = a;
            }
    }
    const float b2 = be2[tid];
    float ms[NPB];
    #pragma unroll
    for (int r = 0; r < NPB; ++r) {
        ms[r] = 0.0f;
        #pragma unroll
        for (int k = 0; k < KNN; ++k) { acc2[r][k] += b2; ms[r] += acc2[r][k]; }
    }
    __syncthreads();   // all reads of sil1 done
    #pragma unroll
    for (int r = 0; r < NPB; ++r)
        #pragma unroll
        for (int k = 0; k < KNN; ++k) sil1[r][k][tid] = silu_f(acc2[r][k]);
    __syncthreads();
    #pragma unroll
    for (int r = 0; r < NPB; ++r) msum[(size_t)(base + r)*HDIM + tid] = ms[r];

    // ---- w = ffn(m): 128 -> 128 -> 1 ----
    float acc3[NPB][KNN];
    #pragma unroll
    for (int r = 0; r < NPB; ++r)
        #pragma unroll
        for (int k = 0; k < KNN; ++k) acc3[r][k] = 0.0f;
    for (int f4 = 0; f4 < HDIM/4; ++f4) {
        const float w0 = Wx1[(4*f4+0)*HDIM + tid];
        const float w1 = Wx1[(4*f4+1)*HDIM + tid];
        const float w2 = Wx1[(4*f4+2)*HDIM + tid];
        const float w3 = Wx1[(4*f4+3)*HDIM + tid];
        #pragma unroll
        for (int r = 0; r < NPB; ++r)
            #pragma unroll
            for (int k = 0; k < KNN; ++k) {
                const float4 v = *(const float4*)&sil1[r][k][4*f4];
                float a = acc3[r][k];
                a = fmaf(v.x, w0, a); a = fmaf(v.y, w1, a);
                a = fmaf(v.z, w2, a); a = fmaf(v.w, w3, a);
                acc3[r][k] = a;
            }
    }
    const float bx = bx1[tid];
    const float wx2 = Wx2[tid];
    float p[NPB][KNN];
    #pragma unroll
    for (int r = 0; r < NPB; ++r)
        #pragma unroll
        for (int k = 0; k < KNN; ++k) p[r][k] = silu_f(acc3[r][k] + bx) * wx2;
    __syncthreads();
    float* red = &feat[0][0][0];   // reuse: 18*128 floats needed
    #pragma unroll
    for (int r = 0; r < NPB; ++r)
        #pragma unroll
        for (int k = 0; k < KNN; ++k) red[((r*KNN) + k)*128 + tid] = p[r][k];
    __syncthreads();
    if (tid < NPB*KNN) {
        float s = 0.0f;
        for (int i = 0; i < 128; ++i) s += red[tid*128 + i];
        const int r = tid / KNN, k = tid % KNN;
        wbuf[(size_t)(base + r)*KNN + k] = s + bx2[0];
    }
}

// ---------------- K4: Hn = Hh + ffn([Hh, msum]);  X_out ----------------
__global__ __launch_bounds__(128) void k_node(
    const float* __restrict__ X, const float* __restrict__ Hh,
    const float* __restrict__ msum, const int* __restrict__ idxb,
    const float* __restrict__ wbuf,
    const float* __restrict__ Wh1, const float* __restrict__ bh1,
    const float* __restrict__ Wh2, const float* __restrict__ bh2,
    float* __restrict__ Hn, float* __restrict__ outX)
{
    const int tid  = threadIdx.x;
    const int base = blockIdx.x * 8;
    __shared__ __align__(16) float sf[8][2*HDIM];
    __shared__ __align__(16) float sh[8][HDIM];

    #pragma unroll
    for (int r = 0; r < 8; ++r) {
        const int node = base + r;
        sf[r][tid]        = silu_f(Hh[(size_t)node*EDIM + tid]);
        sf[r][HDIM + tid] = silu_f(msum[(size_t)node*HDIM + tid]);
    }
    __syncthreads();

    float acc[8];
    #pragma unroll
    for (int r = 0; r < 8; ++r) acc[r] = 0.0f;
    for (int f4 = 0; f4 < 64; ++f4) {
        const float w0 = Wh1[(4*f4+0)*HDIM + tid];
        const float w1 = Wh1[(4*f4+1)*HDIM + tid];
        const float w2 = Wh1[(4*f4+2)*HDIM + tid];
        const float w3 = Wh1[(4*f4+3)*HDIM + tid];
        #pragma unroll
        for (int r = 0; r < 8; ++r) {
            const float4 v = *(const float4*)&sf[r][4*f4];
            float a = acc[r];
            a = fmaf(v.x, w0, a); a = fmaf(v.y, w1, a);
            a = fmaf(v.z, w2, a); a = fmaf(v.w, w3, a);
            acc[r] = a;
        }
    }
    const float b1 = bh1[tid];
    #pragma unroll
    for (int r = 0; r < 8; ++r) sh[r][tid] = silu_f(acc[r] + b1);
    __syncthreads();

    float acc2[8];
    #pragma unroll
    for (int r = 0; r < 8; ++r) acc2[r] = 0.0f;
    for (int f4 = 0; f4 < 32; ++f4) {
        const float w0 = Wh2[(4*f4+0)*EDIM + tid];
        const float w1 = Wh2[(4*f4+1)*EDIM + tid];
        const float w2 = Wh2[(4*f4+2)*EDIM + tid];
        const float w3 = Wh2[(4*f4+3)*EDIM + tid];
        #pragma unroll
        for (int r = 0; r < 8; ++r) {
            const float4 v = *(const float4*)&sh[r][4*f4];
            float a = acc2[r];
            a = fmaf(v.x, w0, a); a = fmaf(v.y, w1, a);
            a = fmaf(v.z, w2, a); a = fmaf(v.w, w3, a);
            acc2[r] = a;
        }
    }
    const float b2 = bh2[tid];
    #pragma unroll
    for (int r = 0; r < 8; ++r) {
        const int node = base + r;
        Hn[(size_t)node*EDIM + tid] = Hh[(size_t)node*EDIM + tid] + acc2[r] + b2;
    }

    // X_out = X + mean_k(rel * w)
    for (int o = tid; o < 8*CC*3; o += 128) {
        const int r = o / (CC*3), q = o % (CC*3);
        const int node = base + r;
        const int b = node >> 10;
        const int c = q / 3, dc = q % 3;
        const float xv = X[((size_t)node*CC + c)*3 + dc];
        float a = 0.0f;
        for (int k = 0; k < KNN; ++k) {
            const int j = idxb[(size_t)node*KNN + k];
            const float xj = X[(((size_t)(b << 10) + j)*CC + c)*3 + dc];
            a += (xv - xj) * wbuf[(size_t)node*KNN + k];
        }
        outX[(size_t)node*CC*3 + q] = xv + a / 9.0f;
    }
}

// ---------------- K5: pd ----------------
__global__ __launch_bounds__(128) void k_pd(
    const float* __restrict__ Hn, const int* __restrict__ idxb,
    const float* __restrict__ Wd1, const float* __restrict__ bd1,
    const float* __restrict__ Wd2, const float* __restrict__ bd2,
    float* __restrict__ outPd)
{
    const int tid  = threadIdx.x;
    const int base = blockIdx.x * NPB;
    __shared__ __align__(16) float siln[NPB][HDIM];
    __shared__ __align__(16) float silj[NPB][KNN][HDIM];

    for (int r = 0; r < NPB; ++r) {
        const int node = base + r;
        const int b = node >> 10;
        siln[r][tid] = silu_f(Hn[(size_t)node*EDIM + tid]);
        for (int k = 0; k < KNN; ++k) {
            const int j = idxb[(size_t)node*KNN + k];
            silj[r][k][tid] = silu_f(Hn[((size_t)(b << 10) + j)*EDIM + tid]);
        }
    }
    __syncthreads();

    float aAn[NPB], aBn[NPB], aAj[NPB][KNN], aBj[NPB][KNN];
    #pragma unroll
    for (int r = 0; r < NPB; ++r) {
        aAn[r] = 0.0f; aBn[r] = 0.0f;
        #pragma unroll
        for (int k = 0; k < KNN; ++k) { aAj[r][k] = 0.0f; aBj[r][k] = 0.0f; }
    }

    for (int f4 = 0; f4 < 32; ++f4) {
        float wA[4], wB[4];
        #pragma unroll
        for (int i = 0; i < 4; ++i) {
            wA[i] = Wd1[(4*f4+i)*HDIM + tid];
            wB[i] = Wd1[(128 + 4*f4+i)*HDIM + tid];
        }
        #pragma unroll
        for (int r = 0; r < NPB; ++r) {
            const float4 vn = *(const float4*)&siln[r][4*f4];
            aAn[r] = fmaf(vn.x, wA[0], fmaf(vn.y, wA[1], fmaf(vn.z, wA[2], fmaf(vn.w, wA[3], aAn[r]))));
            aBn[r] = fmaf(vn.x, wB[0], fmaf(vn.y, wB[1], fmaf(vn.z, wB[2], fmaf(vn.w, wB[3], aBn[r]))));
            #pragma unroll
            for (int k = 0; k < KNN; ++k) {
                const float4 vj = *(const float4*)&silj[r][k][4*f4];
                aAj[r][k] = fmaf(vj.x, wA[0], fmaf(vj.y, wA[1], fmaf(vj.z, wA[2], fmaf(vj.w, wA[3], aAj[r][k]))));
                aBj[r][k] = fmaf(vj.x, wB[0], fmaf(vj.y, wB[1], fmaf(vj.z, wB[2], fmaf(vj.w, wB[3], aBj[r][k]))));
            }
        }
    }

    const float b1 = bd1[tid];
    const float w2 = Wd2[tid];
    float p[NPB][KNN];
    #pragma unroll
    for (int r = 0; r < NPB; ++r)
        #pragma unroll
        for (int k = 0; k < KNN; ++k) {
            const float h1 = silu_f(aAn[r] + aBj[r][k] + b1);
            const float h2 = silu_f(aAj[r][k] + aBn[r] + b1);
            p[r][k] = (h1 + h2) * w2;
        }
    __syncthreads();
    float* red = &silj[0][0][0];
    #pragma unroll
    for (int r = 0; r < NPB; ++r)
        #pragma unroll
        for (int k = 0; k < KNN; ++k) red[((r*KNN) + k)*128 + tid] = p[r][k];
    __syncthreads();
    if (tid < NPB*KNN) {
        float s = 0.0f;
        for (int i = 0; i < 128; ++i) s += red[tid*128 + i];
        const int r = tid / KNN, k = tid % KNN;
        outPd[(size_t)(base + r)*KNN + k] = s + 2.0f * bd2[0];
    }
}

// ---------------- K6: gate + logits ----------------
__global__ __launch_bounds__(128) void k_logits(
    const float* __restrict__ Hn, const int* __restrict__ S,
    const float* __restrict__ emb,
    const float* __restrict__ Wp1, const float* __restrict__ bp1,
    const float* __restrict__ Wr1, const float* __restrict__ br1,
    const float* __restrict__ Wr2, const float* __restrict__ br2,
    float* __restrict__ outL)
{
    const int tid  = threadIdx.x;
    const int base = blockIdx.x * 8;
    __shared__ __align__(16) float s1[8][HDIM];
    __shared__ __align__(16) float s2[8][HDIM];

    #pragma unroll
    for (int r = 0; r < 8; ++r) s1[r][tid] = silu_f(Hn[(size_t)(base + r)*EDIM + tid]);
    __syncthreads();

    float acc[8];
    #pragma unroll
    for (int r = 0; r < 8; ++r) acc[r] = 0.0f;
    for (int f4 = 0; f4 < 32; ++f4) {
        const float w0 = Wp1[(4*f4+0)*EDIM + tid];
        const float w1 = Wp1[(4*f4+1)*EDIM + tid];
        const float w2 = Wp1[(4*f4+2)*EDIM + tid];
        const float w3 = Wp1[(4*f4+3)*EDIM + tid];
        #pragma unroll
        for (int r = 0; r < 8; ++r) {
            const float4 v = *(const float4*)&s1[r][4*f4];
            float a = acc[r];
            a = fmaf(v.x, w0, a); a = fmaf(v.y, w1, a);
            a = fmaf(v.z, w2, a); a = fmaf(v.w, w3, a);
            acc[r] = a;
        }
    }
    const float bp = bp1[tid];
    #pragma unroll
    for (int r = 0; r < 8; ++r) {
        const float g = 1.0f / (1.0f + __expf(-(acc[r] + bp)));
        const float x = emb[S[base + r]*EDIM + tid] * g;
        s2[r][tid] = silu_f(x);
    }
    __syncthreads();

    float acc2[8];
    #pragma unroll
    for (int r = 0; r < 8; ++r) acc2[r] = 0.0f;
    for (int f4 = 0; f4 < 32; ++f4) {
        const float w0 = Wr1[(4*f4+0)*HDIM + tid];
        const float w1 = Wr1[(4*f4+1)*HDIM + tid];
        const float w2 = Wr1[(4*f4+2)*HDIM + tid];
        const float w3 = Wr1[(4*f4+3)*HDIM + tid];
        #pragma unroll
        for (int r = 0; r < 8; ++r) {
            const float4 v = *(const float4*)&s2[r][4*f4];
            float a = acc2[r];
            a = fmaf(v.x, w0, a); a = fmaf(v.y, w1, a);
            a = fmaf(v.z, w2, a); a = fmaf(v.w, w3, a);
            acc2[r] = a;
        }
    }
    const float br = br1[tid];
    #pragma unroll
    for (int r = 0; r < 8; ++r) s1[r][tid] = silu_f(acc2[r] + br);
    __syncthreads();

    for (int o = tid; o < 8*NCLS; o += 128) {
        const int r = o / NCLS, j = o % NCLS;
        float s = 0.0f;
        for (int i = 0; i < 128; ++i) s += s1[r][i] * Wr2[i*NCLS + j];
        outL[(size_t)(base + r)*NCLS + j] = s + br2[j];
    }
}

extern "C" void kernel_launch(void* const* d_in, const int* in_sizes, int n_in,
                              void* d_out, int out_size, void* d_ws, size_t ws_size,
                              hipStream_t stream)
{
    const float* X   = (const float*)d_in[0];
    const int*   S   = (const int*)  d_in[1];
    const float* t   = (const float*)d_in[2];
    const float* emb = (const float*)d_in[3];
    const float* Wt1 = (const float*)d_in[4];
    const float* bt1 = (const float*)d_in[5];
    const float* Wt2 = (const float*)d_in[6];
    const float* bt2 = (const float*)d_in[7];
    const float* We1 = (const float*)d_in[8];
    const float* be1 = (const float*)d_in[9];
    const float* We2 = (const float*)d_in[10];
    const float* be2 = (const float*)d_in[11];
    const float* Wx1 = (const float*)d_in[12];
    const float* bx1 = (const float*)d_in[13];
    const float* Wx2 = (const float*)d_in[14];
    const float* bx2 = (const float*)d_in[15];
    const float* Wh1 = (const float*)d_in[16];
    const float* bh1 = (const float*)d_in[17];
    const float* Wh2 = (const float*)d_in[18];
    const float* bh2 = (const float*)d_in[19];
    const float* Wd1 = (const float*)d_in[20];
    const float* bd1 = (const float*)d_in[21];
    const float* Wd2 = (const float*)d_in[22];
    const float* bd2 = (const float*)d_in[23];
    const float* Wp1 = (const float*)d_in[24];
    const float* bp1 = (const float*)d_in[25];
    const float* Wr1 = (const float*)d_in[26];
    const float* br1 = (const float*)d_in[27];
    const float* Wr2 = (const float*)d_in[28];
    const float* br2 = (const float*)d_in[29];

    float* out     = (float*)d_out;
    float* outL    = out;                                   // BN*25
    float* outX    = out + (size_t)BN*NCLS;                 // BN*42
    float* outPd   = outX + (size_t)BN*CC*3;                // BN*9

    float* Hh   = (float*)d_ws;
    float* msum = Hh   + (size_t)BN*EDIM;
    float* Hn   = msum + (size_t)BN*HDIM;
    float* wbuf = Hn   + (size_t)BN*EDIM;
    int*   idxb = (int*)(wbuf + (size_t)BN*KNN);

    k_hh    <<<BN/8,   128, 0, stream>>>(t, S, emb, Wt1, bt1, Wt2, bt2, Hh);
    k_knn   <<<BN/64,   64, 0, stream>>>(X, idxb);
    k_edge  <<<BN/NPB, 128, 0, stream>>>(X, Hh, idxb, We1, be1, We2, be2,
                                         Wx1, bx1, Wx2, bx2, msum, wbuf);
    k_node  <<<BN/8,   128, 0, stream>>>(X, Hh, msum, idxb, wbuf,
                                         Wh1, bh1, Wh2, bh2, Hn, outX);
    k_pd    <<<BN/NPB, 128, 0, stream>>>(Hn, idxb, Wd1, bd1, Wd2, bd2, outPd);
    k_logits<<<BN/8,   128, 0, stream>>>(Hn, S, emb, Wp1, bp1, Wr1, br1, Wr2, br2, outL);
}

// Round 2
// 1433.221 us; speedup vs baseline: 2.0088x; 2.0088x over previous
//
#include <hip/hip_runtime.h>

#define BATCH 32
#define NPT   1024
#define CC    14
#define KNN   9
#define EDIM  128
#define HDIM  128
#define NCLS  25
#define BN    (BATCH*NPT)

__device__ __forceinline__ float silu_f(float x) { return x / (1.0f + __expf(-x)); }

// ---------------- K1: Hh = emb[S] + time_emb(t) ----------------
__global__ __launch_bounds__(128) void k_hh(
    const float* __restrict__ t, const int* __restrict__ S,
    const float* __restrict__ emb,
    const float* __restrict__ Wt1, const float* __restrict__ bt1,
    const float* __restrict__ Wt2, const float* __restrict__ bt2,
    float* __restrict__ Hh)
{
    const int tid  = threadIdx.x;
    const int base = blockIdx.x * 8;
    __shared__ __align__(16) float sf[8][128];

    const float step  = 1.0f / 127.0f;
    const float coeff = -0.5f / (step * step);
    const float off   = step * (float)tid;

    #pragma unroll
    for (int r = 0; r < 8; ++r) {
        float d = t[base + r] - off + 1e-6f;
        sf[r][tid] = __expf(coeff * d * d);
    }
    __syncthreads();

    float acc[8];
    #pragma unroll
    for (int r = 0; r < 8; ++r) acc[r] = 0.0f;
    for (int f4 = 0; f4 < 32; ++f4) {
        const float w0 = Wt1[(4*f4+0)*HDIM + tid];
        const float w1 = Wt1[(4*f4+1)*HDIM + tid];
        const float w2 = Wt1[(4*f4+2)*HDIM + tid];
        const float w3 = Wt1[(4*f4+3)*HDIM + tid];
        #pragma unroll
        for (int r = 0; r < 8; ++r) {
            const float4 v = *(const float4*)&sf[r][4*f4];
            float a = acc[r];
            a = fmaf(v.x, w0, a); a = fmaf(v.y, w1, a);
            a = fmaf(v.z, w2, a); a = fmaf(v.w, w3, a);
            acc[r] = a;
        }
    }
    __syncthreads();
    const float b1 = bt1[tid];
    #pragma unroll
    for (int r = 0; r < 8; ++r) sf[r][tid] = fmaxf(acc[r] + b1, 0.0f);
    __syncthreads();

    #pragma unroll
    for (int r = 0; r < 8; ++r) acc[r] = 0.0f;
    for (int f4 = 0; f4 < 32; ++f4) {
        const float w0 = Wt2[(4*f4+0)*EDIM + tid];
        const float w1 = Wt2[(4*f4+1)*EDIM + tid];
        const float w2 = Wt2[(4*f4+2)*EDIM + tid];
        const float w3 = Wt2[(4*f4+3)*EDIM + tid];
        #pragma unroll
        for (int r = 0; r < 8; ++r) {
            const float4 v = *(const float4*)&sf[r][4*f4];
            float a = acc[r];
            a = fmaf(v.x, w0, a); a = fmaf(v.y, w1, a);
            a = fmaf(v.z, w2, a); a = fmaf(v.w, w3, a);
            acc[r] = a;
        }
    }
    const float b2 = bt2[tid];
    #pragma unroll
    for (int r = 0; r < 8; ++r) {
        const int node = base + r;
        Hh[(size_t)node * EDIM + tid] = emb[S[node] * EDIM + tid] + acc[r] + b2;
    }
}

// ---------------- K2: KNN top-9 ----------------
__global__ __launch_bounds__(64) void k_knn(
    const float* __restrict__ X, int* __restrict__ idxb)
{
    const int node = blockIdx.x * 64 + threadIdx.x;
    const int b = node >> 10, n = node & 1023;
    const float* Xb = X + (size_t)b * NPT * CC * 3;

    const float cx = Xb[(n*CC + 1)*3 + 0];
    const float cy = Xb[(n*CC + 1)*3 + 1];
    const float cz = Xb[(n*CC + 1)*3 + 2];

    float dist[KNN]; int ind[KNN];
    #pragma unroll
    for (int k = 0; k < KNN; ++k) { dist[k] = 3.0e38f; ind[k] = -1; }

    for (int j = 0; j < NPT; ++j) {
        const float dx = __fsub_rn(cx, Xb[(j*CC + 1)*3 + 0]);
        const float dy = __fsub_rn(cy, Xb[(j*CC + 1)*3 + 1]);
        const float dz = __fsub_rn(cz, Xb[(j*CC + 1)*3 + 2]);
        float d = __fadd_rn(__fadd_rn(__fmul_rn(dx,dx), __fmul_rn(dy,dy)), __fmul_rn(dz,dz));
        if (j == n) d = __fadd_rn(d, 1e10f);
        if (d < dist[KNN-1]) {
            dist[KNN-1] = d; ind[KNN-1] = j;
            #pragma unroll
            for (int p = KNN-1; p > 0; --p) {
                if (dist[p] < dist[p-1]) {
                    float td = dist[p]; dist[p] = dist[p-1]; dist[p-1] = td;
                    int   ti = ind[p];  ind[p]  = ind[p-1];  ind[p-1]  = ti;
                }
            }
        }
    }
    #pragma unroll
    for (int k = 0; k < KNN; ++k) idxb[(size_t)node*KNN + k] = ind[k];
}

// ---------------- K3: per-node GEMV: P[n][0:256] = silu(Hin[n]) @ W[0:256 rows] ----------------
// tid<128 -> col tid with W rows [0,128); tid>=128 -> col tid-128 with W rows [128,256)
// foldb (if non-null) added to first 128 output cols.
__global__ __launch_bounds__(256) void k_gemv256(
    const float* __restrict__ Hin, const float* __restrict__ W,
    const float* __restrict__ foldb, float* __restrict__ P)
{
    const int tid  = threadIdx.x;
    const int base = blockIdx.x * 8;
    __shared__ __align__(16) float sf[8][128];

    for (int o = tid; o < 8*128; o += 256)
        sf[o >> 7][o & 127] = silu_f(Hin[(size_t)base*128 + o]);
    __syncthreads();

    const int c = tid & 127;
    const float* Wp = W + (size_t)(tid >> 7) * 128 * 128;

    float acc[8];
    #pragma unroll
    for (int r = 0; r < 8; ++r) acc[r] = 0.0f;
    for (int f4 = 0; f4 < 32; ++f4) {
        const float w0 = Wp[(4*f4+0)*128 + c];
        const float w1 = Wp[(4*f4+1)*128 + c];
        const float w2 = Wp[(4*f4+2)*128 + c];
        const float w3 = Wp[(4*f4+3)*128 + c];
        #pragma unroll
        for (int r = 0; r < 8; ++r) {
            const float4 v = *(const float4*)&sf[r][4*f4];
            float a = acc[r];
            a = fmaf(v.x, w0, a); a = fmaf(v.y, w1, a);
            a = fmaf(v.z, w2, a); a = fmaf(v.w, w3, a);
            acc[r] = a;
        }
    }
    const float fb = (foldb != nullptr && tid < 128) ? foldb[c] : 0.0f;
    #pragma unroll
    for (int r = 0; r < 8; ++r)
        P[(size_t)(base + r)*256 + tid] = acc[r] + fb;
}

// ---------------- K4: edge pipeline (radial GEMV + layer2 + w-FFN) ----------------
// One wave per node; each lane owns output cols (lane, lane+64).
__global__ __launch_bounds__(128) void k_edge(
    const float* __restrict__ X, const int* __restrict__ idxb,
    const float* __restrict__ P,
    const float* __restrict__ We1, const float* __restrict__ be1,
    const float* __restrict__ We2, const float* __restrict__ be2,
    const float* __restrict__ Wx1, const float* __restrict__ bx1,
    const float* __restrict__ Wx2, const float* __restrict__ bx2,
    float* __restrict__ msum, float* __restrict__ wbuf)
{
    const int tid  = threadIdx.x;
    const int lane = tid & 63, wv = tid >> 6;
    const int node = blockIdx.x * 2 + wv;
    const int b    = node >> 10;
    const int c0   = lane, c1 = lane + 64;

    __shared__ __align__(16) float radF[2][KNN][196];   // silu(radial)
    __shared__ __align__(16) float sil1[2][KNN][128];
    __shared__ float rl[2][44];
    __shared__ int   jidx[2][KNN];

    if (lane < KNN) jidx[wv][lane] = idxb[(size_t)node*KNN + lane];
    const float xl = (lane < 42) ? X[(size_t)node*42 + lane] : 0.0f;
    __syncthreads();

    // ---- stage silu(radial) per edge ----
    for (int k = 0; k < KNN; ++k) {
        const int jn = (b << 10) + jidx[wv][k];
        if (lane < 42) rl[wv][lane] = xl - X[(size_t)jn*42 + lane];
        __syncthreads();
        #pragma unroll
        for (int p = 0; p < 4; ++p) {
            const int f = p*64 + lane;
            if (f < 196) {
                const int c = f / CC, e = f % CC;
                const float v = (rl[wv][3*c+0]*rl[wv][3*e+0]
                               + rl[wv][3*c+1]*rl[wv][3*e+1]
                               + rl[wv][3*c+2]*rl[wv][3*e+2]) / 14.0f;
                radF[wv][k][f] = silu_f(v);
            }
        }
        __syncthreads();
    }

    // ---- layer 1: y = P1[n] + P2[j] + be1 + silu(radial) @ We1[256:452] ----
    const float be1c0 = be1[c0], be1c1 = be1[c1];
    const float Pn0 = P[(size_t)node*256 + c0];
    const float Pn1 = P[(size_t)node*256 + c1];
    float aA[KNN], aB[KNN];
    #pragma unroll
    for (int e = 0; e < KNN; ++e) {
        const size_t jn = (size_t)((b << 10) + jidx[wv][e]);
        aA[e] = Pn0 + P[jn*256 + 128 + c0] + be1c0;
        aB[e] = Pn1 + P[jn*256 + 128 + c1] + be1c1;
    }
    const float* W1 = We1 + 256*128;
    for (int f4 = 0; f4 < 49; ++f4) {
        const float w0 = W1[(4*f4+0)*128 + c0], u0 = W1[(4*f4+0)*128 + c1];
        const float w1 = W1[(4*f4+1)*128 + c0], u1 = W1[(4*f4+1)*128 + c1];
        const float w2 = W1[(4*f4+2)*128 + c0], u2 = W1[(4*f4+2)*128 + c1];
        const float w3 = W1[(4*f4+3)*128 + c0], u3 = W1[(4*f4+3)*128 + c1];
        #pragma unroll
        for (int e = 0; e < KNN; ++e) {
            const float4 v = *(const float4*)&radF[wv][e][4*f4];
            aA[e] = fmaf(v.w, w3, fmaf(v.z, w2, fmaf(v.y, w1, fmaf(v.x, w0, aA[e]))));
            aB[e] = fmaf(v.w, u3, fmaf(v.z, u2, fmaf(v.y, u1, fmaf(v.x, u0, aB[e]))));
        }
    }
    #pragma unroll
    for (int e = 0; e < KNN; ++e) {
        sil1[wv][e][c0] = silu_f(aA[e]);
        sil1[wv][e][c1] = silu_f(aB[e]);
    }
    __syncthreads();

    // ---- layer 2: m = sil1 @ We2 + be2 ----
    float mA[KNN], mB[KNN];
    #pragma unroll
    for (int e = 0; e < KNN; ++e) { mA[e] = 0.0f; mB[e] = 0.0f; }
    for (int f4 = 0; f4 < 32; ++f4) {
        const float w0 = We2[(4*f4+0)*128 + c0], u0 = We2[(4*f4+0)*128 + c1];
        const float w1 = We2[(4*f4+1)*128 + c0], u1 = We2[(4*f4+1)*128 + c1];
        const float w2 = We2[(4*f4+2)*128 + c0], u2 = We2[(4*f4+2)*128 + c1];
        const float w3 = We2[(4*f4+3)*128 + c0], u3 = We2[(4*f4+3)*128 + c1];
        #pragma unroll
        for (int e = 0; e < KNN; ++e) {
            const float4 v = *(const float4*)&sil1[wv][e][4*f4];
            mA[e] = fmaf(v.w, w3, fmaf(v.z, w2, fmaf(v.y, w1, fmaf(v.x, w0, mA[e]))));
            mB[e] = fmaf(v.w, u3, fmaf(v.z, u2, fmaf(v.y, u1, fmaf(v.x, u0, mB[e]))));
        }
    }
    const float be2c0 = be2[c0], be2c1 = be2[c1];
    float s0 = 0.0f, s1 = 0.0f;
    #pragma unroll
    for (int e = 0; e < KNN; ++e) {
        mA[e] += be2c0; mB[e] += be2c1;
        s0 += mA[e];    s1 += mB[e];
    }
    msum[(size_t)node*128 + c0] = s0;
    msum[(size_t)node*128 + c1] = s1;
    __syncthreads();
    #pragma unroll
    for (int e = 0; e < KNN; ++e) {
        sil1[wv][e][c0] = silu_f(mA[e]);
        sil1[wv][e][c1] = silu_f(mB[e]);
    }
    __syncthreads();

    // ---- w = silu(silu(m) @ Wx1 + bx1) @ Wx2 + bx2 ----
    float hA[KNN], hB[KNN];
    #pragma unroll
    for (int e = 0; e < KNN; ++e) { hA[e] = 0.0f; hB[e] = 0.0f; }
    for (int f4 = 0; f4 < 32; ++f4) {
        const float w0 = Wx1[(4*f4+0)*128 + c0], u0 = Wx1[(4*f4+0)*128 + c1];
        const float w1 = Wx1[(4*f4+1)*128 + c0], u1 = Wx1[(4*f4+1)*128 + c1];
        const float w2 = Wx1[(4*f4+2)*128 + c0], u2 = Wx1[(4*f4+2)*128 + c1];
        const float w3 = Wx1[(4*f4+3)*128 + c0], u3 = Wx1[(4*f4+3)*128 + c1];
        #pragma unroll
        for (int e = 0; e < KNN; ++e) {
            const float4 v = *(const float4*)&sil1[wv][e][4*f4];
            hA[e] = fmaf(v.w, w3, fmaf(v.z, w2, fmaf(v.y, w1, fmaf(v.x, w0, hA[e]))));
            hB[e] = fmaf(v.w, u3, fmaf(v.z, u2, fmaf(v.y, u1, fmaf(v.x, u0, hB[e]))));
        }
    }
    const float bxc0 = bx1[c0], bxc1 = bx1[c1];
    const float wxc0 = Wx2[c0], wxc1 = Wx2[c1];
    const float bx2v = bx2[0];
    #pragma unroll
    for (int e = 0; e < KNN; ++e) {
        float p = silu_f(hA[e] + bxc0) * wxc0 + silu_f(hB[e] + bxc1) * wxc1;
        #pragma unroll
        for (int off = 32; off; off >>= 1) p += __shfl_xor(p, off, 64);
        if (lane == 0) wbuf[(size_t)node*KNN + e] = p + bx2v;
    }
}

// ---------------- K5: Hn = Hh + ffn([Hh, msum]);  X_out ----------------
__global__ __launch_bounds__(128) void k_node(
    const float* __restrict__ X, const float* __restrict__ Hh,
    const float* __restrict__ msum, const int* __restrict__ idxb,
    const float* __restrict__ wbuf,
    const float* __restrict__ Wh1, const float* __restrict__ bh1,
    const float* __restrict__ Wh2, const float* __restrict__ bh2,
    float* __restrict__ Hn, float* __restrict__ outX)
{
    const int tid  = threadIdx.x;
    const int base = blockIdx.x * 8;
    __shared__ __align__(16) float sf[8][2*HDIM];
    __shared__ __align__(16) float sh[8][HDIM];

    #pragma unroll
    for (int r = 0; r < 8; ++r) {
        const int node = base + r;
        sf[r][tid]        = silu_f(Hh[(size_t)node*EDIM + tid]);
        sf[r][HDIM + tid] = silu_f(msum[(size_t)node*HDIM + tid]);
    }
    __syncthreads();

    float acc[8];
    #pragma unroll
    for (int r = 0; r < 8; ++r) acc[r] = 0.0f;
    for (int f4 = 0; f4 < 64; ++f4) {
        const float w0 = Wh1[(4*f4+0)*HDIM + tid];
        const float w1 = Wh1[(4*f4+1)*HDIM + tid];
        const float w2 = Wh1[(4*f4+2)*HDIM + tid];
        const float w3 = Wh1[(4*f4+3)*HDIM + tid];
        #pragma unroll
        for (int r = 0; r < 8; ++r) {
            const float4 v = *(const float4*)&sf[r][4*f4];
            float a = acc[r];
            a = fmaf(v.x, w0, a); a = fmaf(v.y, w1, a);
            a = fmaf(v.z, w2, a); a = fmaf(v.w, w3, a);
            acc[r] = a;
        }
    }
    const float b1 = bh1[tid];
    #pragma unroll
    for (int r = 0; r < 8; ++r) sh[r][tid] = silu_f(acc[r] + b1);
    __syncthreads();

    float acc2[8];
    #pragma unroll
    for (int r = 0; r < 8; ++r) acc2[r] = 0.0f;
    for (int f4 = 0; f4 < 32; ++f4) {
        const float w0 = Wh2[(4*f4+0)*EDIM + tid];
        const float w1 = Wh2[(4*f4+1)*EDIM + tid];
        const float w2 = Wh2[(4*f4+2)*EDIM + tid];
        const float w3 = Wh2[(4*f4+3)*EDIM + tid];
        #pragma unroll
        for (int r = 0; r < 8; ++r) {
            const float4 v = *(const float4*)&sh[r][4*f4];
            float a = acc2[r];
            a = fmaf(v.x, w0, a); a = fmaf(v.y, w1, a);
            a = fmaf(v.z, w2, a); a = fmaf(v.w, w3, a);
            acc2[r] = a;
        }
    }
    const float b2 = bh2[tid];
    #pragma unroll
    for (int r = 0; r < 8; ++r) {
        const int node = base + r;
        Hn[(size_t)node*EDIM + tid] = Hh[(size_t)node*EDIM + tid] + acc2[r] + b2;
    }

    for (int o = tid; o < 8*CC*3; o += 128) {
        const int r = o / (CC*3), q = o % (CC*3);
        const int node = base + r;
        const int b = node >> 10;
        const int c = q / 3, dc = q % 3;
        const float xv = X[((size_t)node*CC + c)*3 + dc];
        float a = 0.0f;
        for (int k = 0; k < KNN; ++k) {
            const int j = idxb[(size_t)node*KNN + k];
            const float xj = X[(((size_t)(b << 10) + j)*CC + c)*3 + dc];
            a += (xv - xj) * wbuf[(size_t)node*KNN + k];
        }
        outX[(size_t)node*CC*3 + q] = xv + a / 9.0f;
    }
}

// ---------------- K6: pd from precomputed A,B ----------------
__global__ __launch_bounds__(128) void k_pd2(
    const float* __restrict__ AB, const int* __restrict__ idxb,
    const float* __restrict__ Wd2, const float* __restrict__ bd2,
    float* __restrict__ outPd)
{
    const int tid  = threadIdx.x;
    const int lane = tid & 63, wv = tid >> 6;
    const int node = blockIdx.x * 2 + wv;
    const int b    = node >> 10;
    const int c0   = lane, c1 = lane + 64;

    const float An0 = AB[(size_t)node*256 + c0];
    const float An1 = AB[(size_t)node*256 + c1];
    const float Bn0 = AB[(size_t)node*256 + 128 + c0];
    const float Bn1 = AB[(size_t)node*256 + 128 + c1];
    const float w0  = Wd2[c0], w1 = Wd2[c1];
    const float b2  = 2.0f * bd2[0];

    for (int e = 0; e < KNN; ++e) {
        const size_t jn = (size_t)((b << 10) + idxb[(size_t)node*KNN + e]);
        const float Aj0 = AB[jn*256 + c0],       Aj1 = AB[jn*256 + c1];
        const float Bj0 = AB[jn*256 + 128 + c0], Bj1 = AB[jn*256 + 128 + c1];
        float p = (silu_f(An0 + Bj0) + silu_f(Aj0 + Bn0)) * w0
                + (silu_f(An1 + Bj1) + silu_f(Aj1 + Bn1)) * w1;
        #pragma unroll
        for (int off = 32; off; off >>= 1) p += __shfl_xor(p, off, 64);
        if (lane == 0) outPd[(size_t)node*KNN + e] = p + b2;
    }
}

// ---------------- K7: gate + logits ----------------
__global__ __launch_bounds__(128) void k_logits(
    const float* __restrict__ Hn, const int* __restrict__ S,
    const float* __restrict__ emb,
    const float* __restrict__ Wp1, const float* __restrict__ bp1,
    const float* __restrict__ Wr1, const float* __restrict__ br1,
    const float* __restrict__ Wr2, const float* __restrict__ br2,
    float* __restrict__ outL)
{
    const int tid  = threadIdx.x;
    const int base = blockIdx.x * 8;
    __shared__ __align__(16) float s1[8][HDIM];
    __shared__ __align__(16) float s2[8][HDIM];

    #pragma unroll
    for (int r = 0; r < 8; ++r) s1[r][tid] = silu_f(Hn[(size_t)(base + r)*EDIM + tid]);
    __syncthreads();

    float acc[8];
    #pragma unroll
    for (int r = 0; r < 8; ++r) acc[r] = 0.0f;
    for (int f4 = 0; f4 < 32; ++f4) {
        const float w0 = Wp1[(4*f4+0)*EDIM + tid];
        const float w1 = Wp1[(4*f4+1)*EDIM + tid];
        const float w2 = Wp1[(4*f4+2)*EDIM + tid];
        const float w3 = Wp1[(4*f4+3)*EDIM + tid];
        #pragma unroll
        for (int r = 0; r < 8; ++r) {
            const float4 v = *(const float4*)&s1[r][4*f4];
            float a = acc[r];
            a = fmaf(v.x, w0, a); a = fmaf(v.y, w1, a);
            a = fmaf(v.z, w2, a); a = fmaf(v.w, w3, a);
            acc[r] = a;
        }
    }
    const float bp = bp1[tid];
    #pragma unroll
    for (int r = 0; r < 8; ++r) {
        const float g = 1.0f / (1.0f + __expf(-(acc[r] + bp)));
        const float x = emb[S[base + r]*EDIM + tid] * g;
        s2[r][tid] = silu_f(x);
    }
    __syncthreads();

    float acc2[8];
    #pragma unroll
    for (int r = 0; r < 8; ++r) acc2[r] = 0.0f;
    for (int f4 = 0; f4 < 32; ++f4) {
        const float w0 = Wr1[(4*f4+0)*HDIM + tid];
        const float w1 = Wr1[(4*f4+1)*HDIM + tid];
        const float w2 = Wr1[(4*f4+2)*HDIM + tid];
        const float w3 = Wr1[(4*f4+3)*HDIM + tid];
        #pragma unroll
        for (int r = 0; r < 8; ++r) {
            const float4 v = *(const float4*)&s2[r][4*f4];
            float a = acc2[r];
            a = fmaf(v.x, w0, a); a = fmaf(v.y, w1, a);
            a = fmaf(v.z, w2, a); a = fmaf(v.w, w3, a);
            acc2[r] = a;
        }
    }
    const float br = br1[tid];
    #pragma unroll
    for (int r = 0; r < 8; ++r) s1[r][tid] = silu_f(acc2[r] + br);
    __syncthreads();

    for (int o = tid; o < 8*NCLS; o += 128) {
        const int r = o / NCLS, j = o % NCLS;
        float s = 0.0f;
        for (int i = 0; i < 128; ++i) s += s1[r][i] * Wr2[i*NCLS + j];
        outL[(size_t)(base + r)*NCLS + j] = s + br2[j];
    }
}

extern "C" void kernel_launch(void* const* d_in, const int* in_sizes, int n_in,
                              void* d_out, int out_size, void* d_ws, size_t ws_size,
                              hipStream_t stream)
{
    const float* X   = (const float*)d_in[0];
    const int*   S   = (const int*)  d_in[1];
    const float* t   = (const float*)d_in[2];
    const float* emb = (const float*)d_in[3];
    const float* Wt1 = (const float*)d_in[4];
    const float* bt1 = (const float*)d_in[5];
    const float* Wt2 = (const float*)d_in[6];
    const float* bt2 = (const float*)d_in[7];
    const float* We1 = (const float*)d_in[8];
    const float* be1 = (const float*)d_in[9];
    const float* We2 = (const float*)d_in[10];
    const float* be2 = (const float*)d_in[11];
    const float* Wx1 = (const float*)d_in[12];
    const float* bx1 = (const float*)d_in[13];
    const float* Wx2 = (const float*)d_in[14];
    const float* bx2 = (const float*)d_in[15];
    const float* Wh1 = (const float*)d_in[16];
    const float* bh1 = (const float*)d_in[17];
    const float* Wh2 = (const float*)d_in[18];
    const float* bh2 = (const float*)d_in[19];
    const float* Wd1 = (const float*)d_in[20];
    const float* bd1 = (const float*)d_in[21];
    const float* Wd2 = (const float*)d_in[22];
    const float* bd2 = (const float*)d_in[23];
    const float* Wp1 = (const float*)d_in[24];
    const float* bp1 = (const float*)d_in[25];
    const float* Wr1 = (const float*)d_in[26];
    const float* br1 = (const float*)d_in[27];
    const float* Wr2 = (const float*)d_in[28];
    const float* br2 = (const float*)d_in[29];

    float* out   = (float*)d_out;
    float* outL  = out;                               // BN*25
    float* outX  = out + (size_t)BN*NCLS;             // BN*42
    float* outPd = outX + (size_t)BN*CC*3;            // BN*9

    float* Hh   = (float*)d_ws;
    float* msum = Hh   + (size_t)BN*EDIM;
    float* Hn   = msum + (size_t)BN*HDIM;
    float* wbuf = Hn   + (size_t)BN*EDIM;
    float* P    = wbuf + (size_t)BN*KNN;              // BN*256, reused as AB after k_edge
    int*   idxb = (int*)(P + (size_t)BN*256);

    k_hh     <<<BN/8,  128, 0, stream>>>(t, S, emb, Wt1, bt1, Wt2, bt2, Hh);
    k_knn    <<<BN/64,  64, 0, stream>>>(X, idxb);
    k_gemv256<<<BN/8,  256, 0, stream>>>(Hh, We1, nullptr, P);
    k_edge   <<<BN/2,  128, 0, stream>>>(X, idxb, P, We1, be1, We2, be2,
                                         Wx1, bx1, Wx2, bx2, msum, wbuf);
    k_node   <<<BN/8,  128, 0, stream>>>(X, Hh, msum, idxb, wbuf,
                                         Wh1, bh1, Wh2, bh2, Hn, outX);
    k_gemv256<<<BN/8,  256, 0, stream>>>(Hn, Wd1, bd1, P);   // AB for pd
    k_pd2    <<<BN/2,  128, 0, stream>>>(P, idxb, Wd2, bd2, outPd);
    k_logits <<<BN/8,  128, 0, stream>>>(Hn, S, emb, Wp1, bp1, Wr1, br1, Wr2, br2, outL);
}

// Round 3
// 1053.243 us; speedup vs baseline: 2.7335x; 1.3608x over previous
//
#include <hip/hip_runtime.h>

#define BATCH 32
#define NPT   1024
#define CC    14
#define KNN   9
#define EDIM  128
#define HDIM  128
#define NCLS  25
#define BN    (BATCH*NPT)

typedef float  v4f __attribute__((ext_vector_type(4)));
typedef __bf16 v8bf __attribute__((ext_vector_type(8)));

__device__ __forceinline__ float silu_f(float x) { return x / (1.0f + __expf(-x)); }

__device__ __forceinline__ unsigned short f2bf(float f) {
    union { float f; unsigned u; } v; v.f = f;
    unsigned r = v.u + 0x7fffu + ((v.u >> 16) & 1u);
    return (unsigned short)(r >> 16);
}

// ---------------- K0: weight prep (transpose + bf16) ----------------
// WeRt[128][224]: We1 rows 256..451 transposed, K padded 196->224 with zeros
// We2t[128][128], Wx1t[128][128]: transposed
__global__ __launch_bounds__(256) void k_prep(
    const float* __restrict__ We1, const float* __restrict__ We2,
    const float* __restrict__ Wx1,
    unsigned short* __restrict__ WeRt, unsigned short* __restrict__ We2t,
    unsigned short* __restrict__ Wx1t)
{
    int i = blockIdx.x * 256 + threadIdx.x;
    if (i < 128*224) {
        const int chan = i / 224, k = i % 224;
        WeRt[i] = (k < 196) ? f2bf(We1[(size_t)(256 + k)*128 + chan]) : (unsigned short)0;
        return;
    }
    int i2 = i - 128*224;
    if (i2 < 128*128) {
        const int chan = i2 / 128, k = i2 % 128;
        We2t[i2] = f2bf(We2[(size_t)k*128 + chan]);
        return;
    }
    i2 -= 128*128;
    if (i2 < 128*128) {
        const int chan = i2 / 128, k = i2 % 128;
        Wx1t[i2] = f2bf(Wx1[(size_t)k*128 + chan]);
    }
}

// ---------------- K1: Hh = emb[S] + time_emb(t) ----------------
__global__ __launch_bounds__(128) void k_hh(
    const float* __restrict__ t, const int* __restrict__ S,
    const float* __restrict__ emb,
    const float* __restrict__ Wt1, const float* __restrict__ bt1,
    const float* __restrict__ Wt2, const float* __restrict__ bt2,
    float* __restrict__ Hh)
{
    const int tid  = threadIdx.x;
    const int base = blockIdx.x * 8;
    __shared__ __align__(16) float sf[8][128];

    const float step  = 1.0f / 127.0f;
    const float coeff = -0.5f / (step * step);
    const float off   = step * (float)tid;

    #pragma unroll
    for (int r = 0; r < 8; ++r) {
        float d = t[base + r] - off + 1e-6f;
        sf[r][tid] = __expf(coeff * d * d);
    }
    __syncthreads();

    float acc[8];
    #pragma unroll
    for (int r = 0; r < 8; ++r) acc[r] = 0.0f;
    for (int f4 = 0; f4 < 32; ++f4) {
        const float w0 = Wt1[(4*f4+0)*HDIM + tid];
        const float w1 = Wt1[(4*f4+1)*HDIM + tid];
        const float w2 = Wt1[(4*f4+2)*HDIM + tid];
        const float w3 = Wt1[(4*f4+3)*HDIM + tid];
        #pragma unroll
        for (int r = 0; r < 8; ++r) {
            const float4 v = *(const float4*)&sf[r][4*f4];
            float a = acc[r];
            a = fmaf(v.x, w0, a); a = fmaf(v.y, w1, a);
            a = fmaf(v.z, w2, a); a = fmaf(v.w, w3, a);
            acc[r] = a;
        }
    }
    __syncthreads();
    const float b1 = bt1[tid];
    #pragma unroll
    for (int r = 0; r < 8; ++r) sf[r][tid] = fmaxf(acc[r] + b1, 0.0f);
    __syncthreads();

    #pragma unroll
    for (int r = 0; r < 8; ++r) acc[r] = 0.0f;
    for (int f4 = 0; f4 < 32; ++f4) {
        const float w0 = Wt2[(4*f4+0)*EDIM + tid];
        const float w1 = Wt2[(4*f4+1)*EDIM + tid];
        const float w2 = Wt2[(4*f4+2)*EDIM + tid];
        const float w3 = Wt2[(4*f4+3)*EDIM + tid];
        #pragma unroll
        for (int r = 0; r < 8; ++r) {
            const float4 v = *(const float4*)&sf[r][4*f4];
            float a = acc[r];
            a = fmaf(v.x, w0, a); a = fmaf(v.y, w1, a);
            a = fmaf(v.z, w2, a); a = fmaf(v.w, w3, a);
            acc[r] = a;
        }
    }
    const float b2 = bt2[tid];
    #pragma unroll
    for (int r = 0; r < 8; ++r) {
        const int node = base + r;
        Hh[(size_t)node * EDIM + tid] = emb[S[node] * EDIM + tid] + acc[r] + b2;
    }
}

// ---------------- K2: KNN top-9 with LDS-staged coordinates ----------------
__global__ __launch_bounds__(64) void k_knn(
    const float* __restrict__ X, int* __restrict__ idxb)
{
    __shared__ __align__(16) float4 Cc[NPT];   // 16 KB
    const int bb = blockIdx.x >> 4;            // 16 blocks per batch
    const int n0 = (blockIdx.x & 15) << 6;
    const float* Xb = X + (size_t)bb * NPT * 42;

    for (int i = threadIdx.x; i < NPT; i += 64) {
        const float* p = Xb + (size_t)i*42 + 3;   // channel 1
        Cc[i] = make_float4(p[0], p[1], p[2], 0.0f);
    }
    __syncthreads();

    const int n = n0 + threadIdx.x;
    const int node = (bb << 10) + n;
    const float4 c = Cc[n];

    float dist[KNN]; int ind[KNN];
    #pragma unroll
    for (int k = 0; k < KNN; ++k) { dist[k] = 3.0e38f; ind[k] = -1; }

    for (int j = 0; j < NPT; ++j) {
        const float4 q = Cc[j];
        const float dx = __fsub_rn(c.x, q.x);
        const float dy = __fsub_rn(c.y, q.y);
        const float dz = __fsub_rn(c.z, q.z);
        float d = __fadd_rn(__fadd_rn(__fmul_rn(dx,dx), __fmul_rn(dy,dy)), __fmul_rn(dz,dz));
        if (j == n) d = __fadd_rn(d, 1e10f);
        if (d < dist[KNN-1]) {
            dist[KNN-1] = d; ind[KNN-1] = j;
            #pragma unroll
            for (int p = KNN-1; p > 0; --p) {
                if (dist[p] < dist[p-1]) {
                    float td = dist[p]; dist[p] = dist[p-1]; dist[p-1] = td;
                    int   ti = ind[p];  ind[p]  = ind[p-1];  ind[p-1]  = ti;
                }
            }
        }
    }
    #pragma unroll
    for (int k = 0; k < KNN; ++k) idxb[(size_t)node*KNN + k] = ind[k];
}

// ---------------- K3: per-node GEMV: P[n][0:256] = silu(Hin[n]) @ W + foldb ----------------
__global__ __launch_bounds__(256) void k_gemv256(
    const float* __restrict__ Hin, const float* __restrict__ W,
    const float* __restrict__ foldb, float* __restrict__ P)
{
    const int tid  = threadIdx.x;
    const int base = blockIdx.x * 8;
    __shared__ __align__(16) float sf[8][128];

    for (int o = tid; o < 8*128; o += 256)
        sf[o >> 7][o & 127] = silu_f(Hin[(size_t)base*128 + o]);
    __syncthreads();

    const int c = tid & 127;
    const float* Wp = W + (size_t)(tid >> 7) * 128 * 128;

    float acc[8];
    #pragma unroll
    for (int r = 0; r < 8; ++r) acc[r] = 0.0f;
    for (int f4 = 0; f4 < 32; ++f4) {
        const float w0 = Wp[(4*f4+0)*128 + c];
        const float w1 = Wp[(4*f4+1)*128 + c];
        const float w2 = Wp[(4*f4+2)*128 + c];
        const float w3 = Wp[(4*f4+3)*128 + c];
        #pragma unroll
        for (int r = 0; r < 8; ++r) {
            const float4 v = *(const float4*)&sf[r][4*f4];
            float a = acc[r];
            a = fmaf(v.x, w0, a); a = fmaf(v.y, w1, a);
            a = fmaf(v.z, w2, a); a = fmaf(v.w, w3, a);
            acc[r] = a;
        }
    }
    const float fb = (foldb != nullptr && tid < 128) ? foldb[c] : 0.0f;
    #pragma unroll
    for (int r = 0; r < 8; ++r)
        P[(size_t)(base + r)*256 + tid] = acc[r] + fb;
}

// ---------------- K4: MFMA edge pipeline ----------------
// One node per wave; 16-row MFMA tiles (rows 0..8 real edges, 9..15 garbage).
// Per-wave LDS regions only -> no barriers needed after own-wave staging
// (LDS ops from one wave complete in order).
__global__ __launch_bounds__(256) void k_edge(
    const float* __restrict__ X, const int* __restrict__ idxb,
    const float* __restrict__ P,     // be1 folded in (A half)
    const unsigned short* __restrict__ WeRt,
    const unsigned short* __restrict__ We2t,
    const unsigned short* __restrict__ Wx1t,
    const float* __restrict__ be2,
    const float* __restrict__ bx1, const float* __restrict__ Wx2,
    const float* __restrict__ bx2,
    float* __restrict__ msum, float* __restrict__ wbuf)
{
    __shared__ unsigned short radF[4][16][224];   // 28 KB (bf16)
    __shared__ unsigned short sil [4][16][128];   // 16 KB (bf16)

    const int tid  = threadIdx.x;
    const int wv   = tid >> 6, lane = tid & 63;
    const int node = blockIdx.x * 4 + wv;
    const int b    = node >> 10;
    const int quad = lane >> 4, r16 = lane & 15;

    int jv = 0;
    if (lane < KNN) jv = idxb[(size_t)node*KNN + lane];
    const float xn = (lane < 42) ? X[(size_t)node*42 + lane] : 0.0f;

    // ---- stage silu(radial) as bf16, K padded to 224 ----
    for (int e = 0; e < KNN; ++e) {
        const int j = __shfl(jv, e);
        const size_t jn = (size_t)((b << 10) + j);
        float rel = 0.0f;
        if (lane < 42) rel = xn - X[jn*42 + lane];
        #pragma unroll
        for (int rr = 0; rr < 4; ++rr) {
            const int f  = rr*64 + lane;
            const int fc = (f < 196) ? f : 0;
            const int cI = fc / 14, eI = fc % 14;
            const float v = (__shfl(rel, 3*cI  ) * __shfl(rel, 3*eI  )
                           + __shfl(rel, 3*cI+1) * __shfl(rel, 3*eI+1)
                           + __shfl(rel, 3*cI+2) * __shfl(rel, 3*eI+2)) * (1.0f/14.0f);
            if (f < 196)       radF[wv][e][f] = f2bf(silu_f(v));
            else if (f < 224)  radF[wv][e][f] = 0;
        }
    }

    // neighbor index per C-row (edge = quad*4+rr)
    int jrow[4];
    #pragma unroll
    for (int rr = 0; rr < 4; ++rr) {
        const int e = quad*4 + rr;
        jrow[rr] = __shfl(jv, (e < KNN) ? e : (KNN-1));
    }

    // ---- layer 1: radial part via MFMA, K=224 ----
    v4f acc[8];
    #pragma unroll
    for (int ct = 0; ct < 8; ++ct) acc[ct] = (v4f){0.f, 0.f, 0.f, 0.f};
    {
        const unsigned short* aP = &radF[wv][r16][quad*8];
        #pragma unroll
        for (int ks = 0; ks < 7; ++ks) {
            const v8bf a = *(const v8bf*)(aP + ks*32);
            #pragma unroll
            for (int ct = 0; ct < 8; ++ct) {
                const v8bf bb = *(const v8bf*)(WeRt + (size_t)(ct*16 + r16)*224 + ks*32 + quad*8);
                acc[ct] = __builtin_amdgcn_mfma_f32_16x16x32_bf16(a, bb, acc[ct], 0, 0, 0);
            }
        }
    }
    // epilogue 1: + Pn + Pj (be1 already folded), silu -> sil (bf16)
    #pragma unroll
    for (int ct = 0; ct < 8; ++ct) {
        const int chan = ct*16 + r16;
        const float Pn = P[(size_t)node*256 + chan];
        #pragma unroll
        for (int rr = 0; rr < 4; ++rr) {
            const size_t jn = (size_t)((b << 10) + jrow[rr]);
            const float y = acc[ct][rr] + Pn + P[jn*256 + 128 + chan];
            sil[wv][quad*4 + rr][chan] = f2bf(silu_f(y));
        }
    }

    // ---- layer 2: m = sil @ We2 + be2 ----
    v4f acc2[8];
    #pragma unroll
    for (int ct = 0; ct < 8; ++ct) acc2[ct] = (v4f){0.f, 0.f, 0.f, 0.f};
    {
        const unsigned short* sP = &sil[wv][r16][quad*8];
        #pragma unroll
        for (int ks = 0; ks < 4; ++ks) {
            const v8bf a = *(const v8bf*)(sP + ks*32);
            #pragma unroll
            for (int ct = 0; ct < 8; ++ct) {
                const v8bf bb = *(const v8bf*)(We2t + (size_t)(ct*16 + r16)*128 + ks*32 + quad*8);
                acc2[ct] = __builtin_amdgcn_mfma_f32_16x16x32_bf16(a, bb, acc2[ct], 0, 0, 0);
            }
        }
    }
    // epilogue 2: msum (masked row-reduction) + silu(m) -> sil
    #pragma unroll
    for (int ct = 0; ct < 8; ++ct) {
        const int chan = ct*16 + r16;
        const float b2c = be2[chan];
        float mv[4]; float s = 0.0f;
        #pragma unroll
        for (int rr = 0; rr < 4; ++rr) {
            const float m = acc2[ct][rr] + b2c;
            mv[rr] = m;
            if (quad*4 + rr < KNN) s += m;
        }
        s += __shfl_xor(s, 16);
        s += __shfl_xor(s, 32);
        if (lane < 16) msum[(size_t)node*128 + ct*16 + lane] = s;
        #pragma unroll
        for (int rr = 0; rr < 4; ++rr)
            sil[wv][quad*4 + rr][chan] = f2bf(silu_f(mv[rr]));
    }

    // ---- layer 3: h = sil @ Wx1 ----
    v4f acc3[8];
    #pragma unroll
    for (int ct = 0; ct < 8; ++ct) acc3[ct] = (v4f){0.f, 0.f, 0.f, 0.f};
    {
        const unsigned short* sP = &sil[wv][r16][quad*8];
        #pragma unroll
        for (int ks = 0; ks < 4; ++ks) {
            const v8bf a = *(const v8bf*)(sP + ks*32);
            #pragma unroll
            for (int ct = 0; ct < 8; ++ct) {
                const v8bf bb = *(const v8bf*)(Wx1t + (size_t)(ct*16 + r16)*128 + ks*32 + quad*8);
                acc3[ct] = __builtin_amdgcn_mfma_f32_16x16x32_bf16(a, bb, acc3[ct], 0, 0, 0);
            }
        }
    }
    // epilogue 3: w[edge] = sum_chan silu(h + bx1)*Wx2 + bx2
    float pr[4] = {0.f, 0.f, 0.f, 0.f};
    #pragma unroll
    for (int ct = 0; ct < 8; ++ct) {
        const int chan = ct*16 + r16;
        const float bxc = bx1[chan];
        const float wxc = Wx2[chan];
        #pragma unroll
        for (int rr = 0; rr < 4; ++rr)
            pr[rr] += silu_f(acc3[ct][rr] + bxc) * wxc;
    }
    #pragma unroll
    for (int rr = 0; rr < 4; ++rr) {
        pr[rr] += __shfl_xor(pr[rr], 1);
        pr[rr] += __shfl_xor(pr[rr], 2);
        pr[rr] += __shfl_xor(pr[rr], 4);
        pr[rr] += __shfl_xor(pr[rr], 8);
    }
    const float bxv = bx2[0];
    if (r16 == 0) {
        #pragma unroll
        for (int rr = 0; rr < 4; ++rr) {
            const int e = quad*4 + rr;
            if (e < KNN) wbuf[(size_t)node*KNN + e] = pr[rr] + bxv;
        }
    }
}

// ---------------- K5: Hn = Hh + ffn([Hh, msum]);  X_out ----------------
__global__ __launch_bounds__(128) void k_node(
    const float* __restrict__ X, const float* __restrict__ Hh,
    const float* __restrict__ msum, const int* __restrict__ idxb,
    const float* __restrict__ wbuf,
    const float* __restrict__ Wh1, const float* __restrict__ bh1,
    const float* __restrict__ Wh2, const float* __restrict__ bh2,
    float* __restrict__ Hn, float* __restrict__ outX)
{
    const int tid  = threadIdx.x;
    const int base = blockIdx.x * 8;
    __shared__ __align__(16) float sf[8][2*HDIM];
    __shared__ __align__(16) float sh[8][HDIM];

    #pragma unroll
    for (int r = 0; r < 8; ++r) {
        const int node = base + r;
        sf[r][tid]        = silu_f(Hh[(size_t)node*EDIM + tid]);
        sf[r][HDIM + tid] = silu_f(msum[(size_t)node*HDIM + tid]);
    }
    __syncthreads();

    float acc[8];
    #pragma unroll
    for (int r = 0; r < 8; ++r) acc[r] = 0.0f;
    for (int f4 = 0; f4 < 64; ++f4) {
        const float w0 = Wh1[(4*f4+0)*HDIM + tid];
        const float w1 = Wh1[(4*f4+1)*HDIM + tid];
        const float w2 = Wh1[(4*f4+2)*HDIM + tid];
        const float w3 = Wh1[(4*f4+3)*HDIM + tid];
        #pragma unroll
        for (int r = 0; r < 8; ++r) {
            const float4 v = *(const float4*)&sf[r][4*f4];
            float a = acc[r];
            a = fmaf(v.x, w0, a); a = fmaf(v.y, w1, a);
            a = fmaf(v.z, w2, a); a = fmaf(v.w, w3, a);
            acc[r] = a;
        }
    }
    const float b1 = bh1[tid];
    #pragma unroll
    for (int r = 0; r < 8; ++r) sh[r][tid] = silu_f(acc[r] + b1);
    __syncthreads();

    float acc2[8];
    #pragma unroll
    for (int r = 0; r < 8; ++r) acc2[r] = 0.0f;
    for (int f4 = 0; f4 < 32; ++f4) {
        const float w0 = Wh2[(4*f4+0)*EDIM + tid];
        const float w1 = Wh2[(4*f4+1)*EDIM + tid];
        const float w2 = Wh2[(4*f4+2)*EDIM + tid];
        const float w3 = Wh2[(4*f4+3)*EDIM + tid];
        #pragma unroll
        for (int r = 0; r < 8; ++r) {
            const float4 v = *(const float4*)&sh[r][4*f4];
            float a = acc2[r];
            a = fmaf(v.x, w0, a); a = fmaf(v.y, w1, a);
            a = fmaf(v.z, w2, a); a = fmaf(v.w, w3, a);
            acc2[r] = a;
        }
    }
    const float b2 = bh2[tid];
    #pragma unroll
    for (int r = 0; r < 8; ++r) {
        const int node = base + r;
        Hn[(size_t)node*EDIM + tid] = Hh[(size_t)node*EDIM + tid] + acc2[r] + b2;
    }

    for (int o = tid; o < 8*CC*3; o += 128) {
        const int r = o / (CC*3), q = o % (CC*3);
        const int node = base + r;
        const int b = node >> 10;
        const int c = q / 3, dc = q % 3;
        const float xv = X[((size_t)node*CC + c)*3 + dc];
        float a = 0.0f;
        for (int k = 0; k < KNN; ++k) {
            const int j = idxb[(size_t)node*KNN + k];
            const float xj = X[(((size_t)(b << 10) + j)*CC + c)*3 + dc];
            a += (xv - xj) * wbuf[(size_t)node*KNN + k];
        }
        outX[(size_t)node*CC*3 + q] = xv + a / 9.0f;
    }
}

// ---------------- K6: pd from precomputed A,B ----------------
__global__ __launch_bounds__(128) void k_pd2(
    const float* __restrict__ AB, const int* __restrict__ idxb,
    const float* __restrict__ Wd2, const float* __restrict__ bd2,
    float* __restrict__ outPd)
{
    const int tid  = threadIdx.x;
    const int lane = tid & 63, wv = tid >> 6;
    const int node = blockIdx.x * 2 + wv;
    const int b    = node >> 10;
    const int c0   = lane, c1 = lane + 64;

    const float An0 = AB[(size_t)node*256 + c0];
    const float An1 = AB[(size_t)node*256 + c1];
    const float Bn0 = AB[(size_t)node*256 + 128 + c0];
    const float Bn1 = AB[(size_t)node*256 + 128 + c1];
    const float w0  = Wd2[c0], w1 = Wd2[c1];
    const float b2  = 2.0f * bd2[0];

    for (int e = 0; e < KNN; ++e) {
        const size_t jn = (size_t)((b << 10) + idxb[(size_t)node*KNN + e]);
        const float Aj0 = AB[jn*256 + c0],       Aj1 = AB[jn*256 + c1];
        const float Bj0 = AB[jn*256 + 128 + c0], Bj1 = AB[jn*256 + 128 + c1];
        float p = (silu_f(An0 + Bj0) + silu_f(Aj0 + Bn0)) * w0
                + (silu_f(An1 + Bj1) + silu_f(Aj1 + Bn1)) * w1;
        #pragma unroll
        for (int off = 32; off; off >>= 1) p += __shfl_xor(p, off, 64);
        if (lane == 0) outPd[(size_t)node*KNN + e] = p + b2;
    }
}

// ---------------- K7: gate + logits ----------------
__global__ __launch_bounds__(128) void k_logits(
    const float* __restrict__ Hn, const int* __restrict__ S,
    const float* __restrict__ emb,
    const float* __restrict__ Wp1, const float* __restrict__ bp1,
    const float* __restrict__ Wr1, const float* __restrict__ br1,
    const float* __restrict__ Wr2, const float* __restrict__ br2,
    float* __restrict__ outL)
{
    const int tid  = threadIdx.x;
    const int base = blockIdx.x * 8;
    __shared__ __align__(16) float s1[8][HDIM];
    __shared__ __align__(16) float s2[8][HDIM];

    #pragma unroll
    for (int r = 0; r < 8; ++r) s1[r][tid] = silu_f(Hn[(size_t)(base + r)*EDIM + tid]);
    __syncthreads();

    float acc[8];
    #pragma unroll
    for (int r = 0; r < 8; ++r) acc[r] = 0.0f;
    for (int f4 = 0; f4 < 32; ++f4) {
        const float w0 = Wp1[(4*f4+0)*EDIM + tid];
        const float w1 = Wp1[(4*f4+1)*EDIM + tid];
        const float w2 = Wp1[(4*f4+2)*EDIM + tid];
        const float w3 = Wp1[(4*f4+3)*EDIM + tid];
        #pragma unroll
        for (int r = 0; r < 8; ++r) {
            const float4 v = *(const float4*)&s1[r][4*f4];
            float a = acc[r];
            a = fmaf(v.x, w0, a); a = fmaf(v.y, w1, a);
            a = fmaf(v.z, w2, a); a = fmaf(v.w, w3, a);
            acc[r] = a;
        }
    }
    const float bp = bp1[tid];
    #pragma unroll
    for (int r = 0; r < 8; ++r) {
        const float g = 1.0f / (1.0f + __expf(-(acc[r] + bp)));
        const float x = emb[S[base + r]*EDIM + tid] * g;
        s2[r][tid] = silu_f(x);
    }
    __syncthreads();

    float acc2[8];
    #pragma unroll
    for (int r = 0; r < 8; ++r) acc2[r] = 0.0f;
    for (int f4 = 0; f4 < 32; ++f4) {
        const float w0 = Wr1[(4*f4+0)*HDIM + tid];
        const float w1 = Wr1[(4*f4+1)*HDIM + tid];
        const float w2 = Wr1[(4*f4+2)*HDIM + tid];
        const float w3 = Wr1[(4*f4+3)*HDIM + tid];
        #pragma unroll
        for (int r = 0; r < 8; ++r) {
            const float4 v = *(const float4*)&s2[r][4*f4];
            float a = acc2[r];
            a = fmaf(v.x, w0, a); a = fmaf(v.y, w1, a);
            a = fmaf(v.z, w2, a); a = fmaf(v.w, w3, a);
            acc2[r] = a;
        }
    }
    const float br = br1[tid];
    #pragma unroll
    for (int r = 0; r < 8; ++r) s1[r][tid] = silu_f(acc2[r] + br);
    __syncthreads();

    for (int o = tid; o < 8*NCLS; o += 128) {
        const int r = o / NCLS, j = o % NCLS;
        float s = 0.0f;
        for (int i = 0; i < 128; ++i) s += s1[r][i] * Wr2[i*NCLS + j];
        outL[(size_t)(base + r)*NCLS + j] = s + br2[j];
    }
}

extern "C" void kernel_launch(void* const* d_in, const int* in_sizes, int n_in,
                              void* d_out, int out_size, void* d_ws, size_t ws_size,
                              hipStream_t stream)
{
    const float* X   = (const float*)d_in[0];
    const int*   S   = (const int*)  d_in[1];
    const float* t   = (const float*)d_in[2];
    const float* emb = (const float*)d_in[3];
    const float* Wt1 = (const float*)d_in[4];
    const float* bt1 = (const float*)d_in[5];
    const float* Wt2 = (const float*)d_in[6];
    const float* bt2 = (const float*)d_in[7];
    const float* We1 = (const float*)d_in[8];
    const float* be1 = (const float*)d_in[9];
    const float* We2 = (const float*)d_in[10];
    const float* be2 = (const float*)d_in[11];
    const float* Wx1 = (const float*)d_in[12];
    const float* bx1 = (const float*)d_in[13];
    const float* Wx2 = (const float*)d_in[14];
    const float* bx2 = (const float*)d_in[15];
    const float* Wh1 = (const float*)d_in[16];
    const float* bh1 = (const float*)d_in[17];
    const float* Wh2 = (const float*)d_in[18];
    const float* bh2 = (const float*)d_in[19];
    const float* Wd1 = (const float*)d_in[20];
    const float* bd1 = (const float*)d_in[21];
    const float* Wd2 = (const float*)d_in[22];
    const float* bd2 = (const float*)d_in[23];
    const float* Wp1 = (const float*)d_in[24];
    const float* bp1 = (const float*)d_in[25];
    const float* Wr1 = (const float*)d_in[26];
    const float* br1 = (const float*)d_in[27];
    const float* Wr2 = (const float*)d_in[28];
    const float* br2 = (const float*)d_in[29];

    float* out   = (float*)d_out;
    float* outL  = out;                               // BN*25
    float* outX  = out + (size_t)BN*NCLS;             // BN*42
    float* outPd = outX + (size_t)BN*CC*3;            // BN*9

    // workspace layout (16B-aligned chunks; bf16 weights first)
    unsigned short* WeRt = (unsigned short*)d_ws;            // 128*224
    unsigned short* We2t = WeRt + 128*224;                   // 128*128
    unsigned short* Wx1t = We2t + 128*128;                   // 128*128
    float* Hh   = (float*)(Wx1t + 128*128);
    float* msum = Hh   + (size_t)BN*EDIM;
    float* Hn   = msum + (size_t)BN*HDIM;
    float* wbuf = Hn   + (size_t)BN*EDIM;
    float* P    = wbuf + (size_t)BN*KNN;              // BN*256, reused as AB for pd
    int*   idxb = (int*)(P + (size_t)BN*256);

    k_prep   <<<240,   256, 0, stream>>>(We1, We2, Wx1, WeRt, We2t, Wx1t);
    k_hh     <<<BN/8,  128, 0, stream>>>(t, S, emb, Wt1, bt1, Wt2, bt2, Hh);
    k_knn    <<<BN/64,  64, 0, stream>>>(X, idxb);
    k_gemv256<<<BN/8,  256, 0, stream>>>(Hh, We1, be1, P);   // be1 folded into A half
    k_edge   <<<BN/4,  256, 0, stream>>>(X, idxb, P, WeRt, We2t, Wx1t,
                                         be2, bx1, Wx2, bx2, msum, wbuf);
    k_node   <<<BN/8,  128, 0, stream>>>(X, Hh, msum, idxb, wbuf,
                                         Wh1, bh1, Wh2, bh2, Hn, outX);
    k_gemv256<<<BN/8,  256, 0, stream>>>(Hn, Wd1, bd1, P);   // AB for pd
    k_pd2    <<<BN/2,  128, 0, stream>>>(P, idxb, Wd2, bd2, outPd);
    k_logits <<<BN/8,  128, 0, stream>>>(Hn, S, emb, Wp1, bp1, Wr1, br1, Wr2, br2, outL);
}

// Round 4
// 960.225 us; speedup vs baseline: 2.9983x; 1.0969x over previous
//
#include <hip/hip_runtime.h>

#define BATCH 32
#define NPT   1024
#define CC    14
#define KNN   9
#define EDIM  128
#define HDIM  128
#define NCLS  25
#define BN    (BATCH*NPT)

typedef float  v4f __attribute__((ext_vector_type(4)));
typedef __bf16 v8bf __attribute__((ext_vector_type(8)));

__device__ __forceinline__ float silu_f(float x) { return x / (1.0f + __expf(-x)); }

__device__ __forceinline__ unsigned short f2bf(float f) {
    union { float f; unsigned u; } v; v.f = f;
    unsigned r = v.u + 0x7fffu + ((v.u >> 16) & 1u);
    return (unsigned short)(r >> 16);
}

// ---------------- K0: weight prep (transpose + bf16) ----------------
__global__ __launch_bounds__(256) void k_prep(
    const float* __restrict__ We1, const float* __restrict__ We2,
    const float* __restrict__ Wx1,
    unsigned short* __restrict__ WeRt, unsigned short* __restrict__ We2t,
    unsigned short* __restrict__ Wx1t)
{
    int i = blockIdx.x * 256 + threadIdx.x;
    if (i < 128*224) {
        const int chan = i / 224, k = i % 224;
        WeRt[i] = (k < 196) ? f2bf(We1[(size_t)(256 + k)*128 + chan]) : (unsigned short)0;
        return;
    }
    int i2 = i - 128*224;
    if (i2 < 128*128) {
        const int chan = i2 / 128, k = i2 % 128;
        We2t[i2] = f2bf(We2[(size_t)k*128 + chan]);
        return;
    }
    i2 -= 128*128;
    if (i2 < 128*128) {
        const int chan = i2 / 128, k = i2 % 128;
        Wx1t[i2] = f2bf(Wx1[(size_t)k*128 + chan]);
    }
}

// ---------------- K1: Hh = emb[S] + time_emb(t), 16 rows/block ----------------
__global__ __launch_bounds__(128) void k_hh(
    const float* __restrict__ t, const int* __restrict__ S,
    const float* __restrict__ emb,
    const float* __restrict__ Wt1, const float* __restrict__ bt1,
    const float* __restrict__ Wt2, const float* __restrict__ bt2,
    float* __restrict__ Hh)
{
    const int tid  = threadIdx.x;
    const int base = blockIdx.x * 16;
    __shared__ __align__(16) float sf[16][128];

    const float step  = 1.0f / 127.0f;
    const float coeff = -0.5f / (step * step);
    const float off   = step * (float)tid;

    #pragma unroll
    for (int r = 0; r < 16; ++r) {
        float d = t[base + r] - off + 1e-6f;
        sf[r][tid] = __expf(coeff * d * d);
    }
    __syncthreads();

    float acc[16];
    #pragma unroll
    for (int r = 0; r < 16; ++r) acc[r] = 0.0f;
    for (int f4 = 0; f4 < 32; ++f4) {
        const float w0 = Wt1[(4*f4+0)*HDIM + tid];
        const float w1 = Wt1[(4*f4+1)*HDIM + tid];
        const float w2 = Wt1[(4*f4+2)*HDIM + tid];
        const float w3 = Wt1[(4*f4+3)*HDIM + tid];
        #pragma unroll
        for (int r = 0; r < 16; ++r) {
            const float4 v = *(const float4*)&sf[r][4*f4];
            float a = acc[r];
            a = fmaf(v.x, w0, a); a = fmaf(v.y, w1, a);
            a = fmaf(v.z, w2, a); a = fmaf(v.w, w3, a);
            acc[r] = a;
        }
    }
    __syncthreads();
    const float b1 = bt1[tid];
    #pragma unroll
    for (int r = 0; r < 16; ++r) sf[r][tid] = fmaxf(acc[r] + b1, 0.0f);
    __syncthreads();

    #pragma unroll
    for (int r = 0; r < 16; ++r) acc[r] = 0.0f;
    for (int f4 = 0; f4 < 32; ++f4) {
        const float w0 = Wt2[(4*f4+0)*EDIM + tid];
        const float w1 = Wt2[(4*f4+1)*EDIM + tid];
        const float w2 = Wt2[(4*f4+2)*EDIM + tid];
        const float w3 = Wt2[(4*f4+3)*EDIM + tid];
        #pragma unroll
        for (int r = 0; r < 16; ++r) {
            const float4 v = *(const float4*)&sf[r][4*f4];
            float a = acc[r];
            a = fmaf(v.x, w0, a); a = fmaf(v.y, w1, a);
            a = fmaf(v.z, w2, a); a = fmaf(v.w, w3, a);
            acc[r] = a;
        }
    }
    const float b2 = bt2[tid];
    #pragma unroll
    for (int r = 0; r < 16; ++r) {
        const int node = base + r;
        Hh[(size_t)node * EDIM + tid] = emb[S[node] * EDIM + tid] + acc[r] + b2;
    }
}

// ---------------- K2: KNN top-9 with LDS-staged coordinates ----------------
__global__ __launch_bounds__(64) void k_knn(
    const float* __restrict__ X, int* __restrict__ idxb)
{
    __shared__ __align__(16) float4 Cc[NPT];
    const int bb = blockIdx.x >> 4;
    const int n0 = (blockIdx.x & 15) << 6;
    const float* Xb = X + (size_t)bb * NPT * 42;

    for (int i = threadIdx.x; i < NPT; i += 64) {
        const float* p = Xb + (size_t)i*42 + 3;
        Cc[i] = make_float4(p[0], p[1], p[2], 0.0f);
    }
    __syncthreads();

    const int n = n0 + threadIdx.x;
    const int node = (bb << 10) + n;
    const float4 c = Cc[n];

    float dist[KNN]; int ind[KNN];
    #pragma unroll
    for (int k = 0; k < KNN; ++k) { dist[k] = 3.0e38f; ind[k] = -1; }

    for (int j = 0; j < NPT; ++j) {
        const float4 q = Cc[j];
        const float dx = __fsub_rn(c.x, q.x);
        const float dy = __fsub_rn(c.y, q.y);
        const float dz = __fsub_rn(c.z, q.z);
        float d = __fadd_rn(__fadd_rn(__fmul_rn(dx,dx), __fmul_rn(dy,dy)), __fmul_rn(dz,dz));
        if (j == n) d = __fadd_rn(d, 1e10f);
        if (d < dist[KNN-1]) {
            dist[KNN-1] = d; ind[KNN-1] = j;
            #pragma unroll
            for (int p = KNN-1; p > 0; --p) {
                if (dist[p] < dist[p-1]) {
                    float td = dist[p]; dist[p] = dist[p-1]; dist[p-1] = td;
                    int   ti = ind[p];  ind[p]  = ind[p-1];  ind[p-1]  = ti;
                }
            }
        }
    }
    #pragma unroll
    for (int k = 0; k < KNN; ++k) idxb[(size_t)node*KNN + k] = ind[k];
}

// ---------------- K3: P[n][0:256] = silu(Hin[n]) @ W (+foldb on first 128), 16 rows ----------------
__global__ __launch_bounds__(256) void k_gemv256(
    const float* __restrict__ Hin, const float* __restrict__ W,
    const float* __restrict__ foldb, float* __restrict__ P)
{
    const int tid  = threadIdx.x;
    const int base = blockIdx.x * 16;
    __shared__ __align__(16) float sf[16][128];

    for (int o = tid; o < 16*128; o += 256)
        sf[o >> 7][o & 127] = silu_f(Hin[(size_t)base*128 + o]);
    __syncthreads();

    const int c = tid & 127;
    const float* Wp = W + (size_t)(tid >> 7) * 128 * 128;

    float acc[16];
    #pragma unroll
    for (int r = 0; r < 16; ++r) acc[r] = 0.0f;
    for (int f4 = 0; f4 < 32; ++f4) {
        const float w0 = Wp[(4*f4+0)*128 + c];
        const float w1 = Wp[(4*f4+1)*128 + c];
        const float w2 = Wp[(4*f4+2)*128 + c];
        const float w3 = Wp[(4*f4+3)*128 + c];
        #pragma unroll
        for (int r = 0; r < 16; ++r) {
            const float4 v = *(const float4*)&sf[r][4*f4];
            float a = acc[r];
            a = fmaf(v.x, w0, a); a = fmaf(v.y, w1, a);
            a = fmaf(v.z, w2, a); a = fmaf(v.w, w3, a);
            acc[r] = a;
        }
    }
    const float fb = (foldb != nullptr && tid < 128) ? foldb[c] : 0.0f;
    #pragma unroll
    for (int r = 0; r < 16; ++r)
        P[(size_t)(base + r)*256 + tid] = acc[r] + fb;
}

// ---------------- K4: MFMA edge pipeline, ct-split across waves ----------------
// Block = 4 nodes, 4 waves. Wave w owns column-tiles ct in {2w, 2w+1} and
// loops over all 4 nodes; B-fragments live in VGPRs, loaded once per block.
// LDS: radF region per node (16 rows x 232 bf16, padded stride), sil overlays it
// (16 x 136). Padded strides -> 2-way LDS conflicts only (free).
__global__ __launch_bounds__(256) void k_edge(
    const float* __restrict__ X, const int* __restrict__ idxb,
    const float* __restrict__ P,
    const unsigned short* __restrict__ WeRt,
    const unsigned short* __restrict__ We2t,
    const unsigned short* __restrict__ Wx1t,
    const float* __restrict__ be2,
    const float* __restrict__ bx1, const float* __restrict__ Wx2,
    const float* __restrict__ bx2,
    float* __restrict__ msum, float* __restrict__ wbuf)
{
    __shared__ unsigned short smem[4*16*232];   // 29696 B; per-node region 3712 ushorts
    __shared__ float wred[4][KNN][4];
    __shared__ int   jsh[4][16];

    const int tid  = threadIdx.x;
    const int wv   = tid >> 6, lane = tid & 63;
    const int quad = lane >> 4, r16 = lane & 15;
    const int node0  = blockIdx.x * 4;
    const int mynode = node0 + wv;
    const int b      = node0 >> 10;
    const int chan0  = (wv*2 + 0)*16 + r16;
    const int chan1  = (wv*2 + 1)*16 + r16;

    // ---- B-fragments for layer 1 (held in regs, reused across 4 nodes) ----
    v8bf B1[2][7];
    #pragma unroll
    for (int c2 = 0; c2 < 2; ++c2) {
        const int ct = wv*2 + c2;
        #pragma unroll
        for (int ks = 0; ks < 7; ++ks)
            B1[c2][ks] = *(const v8bf*)(WeRt + (size_t)(ct*16 + r16)*224 + ks*32 + quad*8);
    }

    // ---- stage silu(radial) for my node, bf16, stride 232 ----
    int jv = 0;
    if (lane < KNN) jv = idxb[(size_t)mynode*KNN + lane];
    if (lane < KNN) jsh[wv][lane] = jv;
    const float xn = (lane < 42) ? X[(size_t)mynode*42 + lane] : 0.0f;

    for (int e = 0; e < KNN; ++e) {
        const int j = __shfl(jv, e);
        const size_t jn = (size_t)((b << 10) + j);
        float rel = 0.0f;
        if (lane < 42) rel = xn - X[jn*42 + lane];
        #pragma unroll
        for (int rr = 0; rr < 4; ++rr) {
            const int f  = rr*64 + lane;
            const int fc = (f < 196) ? f : 0;
            const int cI = fc / 14, eI = fc % 14;
            const float v = (__shfl(rel, 3*cI  ) * __shfl(rel, 3*eI  )
                           + __shfl(rel, 3*cI+1) * __shfl(rel, 3*eI+1)
                           + __shfl(rel, 3*cI+2) * __shfl(rel, 3*eI+2)) * (1.0f/14.0f);
            if (f < 196)       smem[wv*3712 + e*232 + f] = f2bf(silu_f(v));
            else if (f < 224)  smem[wv*3712 + e*232 + f] = 0;
        }
    }
    __syncthreads();

    // ---- layer 1 MFMA: all nodes, my 2 column-tiles ----
    v4f acc1[4][2];
    #pragma unroll
    for (int n = 0; n < 4; ++n) { acc1[n][0] = (v4f){0,0,0,0}; acc1[n][1] = (v4f){0,0,0,0}; }
    #pragma unroll
    for (int n = 0; n < 4; ++n) {
        v8bf a[7];
        #pragma unroll
        for (int ks = 0; ks < 7; ++ks)
            a[ks] = *(const v8bf*)(smem + n*3712 + r16*232 + ks*32 + quad*8);
        #pragma unroll
        for (int ks = 0; ks < 7; ++ks) {
            acc1[n][0] = __builtin_amdgcn_mfma_f32_16x16x32_bf16(a[ks], B1[0][ks], acc1[n][0], 0, 0, 0);
            acc1[n][1] = __builtin_amdgcn_mfma_f32_16x16x32_bf16(a[ks], B1[1][ks], acc1[n][1], 0, 0, 0);
        }
    }
    __syncthreads();   // all radF reads done before sil overlay writes

    // ---- epilogue 1: + Pn + Pj, silu -> sil (overlay) ----
    {
        float pn[4][2], pj[4][2][4];
        #pragma unroll
        for (int n = 0; n < 4; ++n) {
            pn[n][0] = P[(size_t)(node0 + n)*256 + chan0];
            pn[n][1] = P[(size_t)(node0 + n)*256 + chan1];
            #pragma unroll
            for (int rr = 0; rr < 4; ++rr) {
                const int e = quad*4 + rr;
                const int jq = jsh[n][(e < KNN) ? e : (KNN-1)];
                const size_t jrow = (size_t)((b << 10) + jq)*256 + 128;
                pj[n][0][rr] = P[jrow + chan0];
                pj[n][1][rr] = P[jrow + chan1];
            }
        }
        #pragma unroll
        for (int n = 0; n < 4; ++n)
            #pragma unroll
            for (int rr = 0; rr < 4; ++rr) {
                const int row = quad*4 + rr;
                smem[n*3712 + row*136 + chan0] = f2bf(silu_f(acc1[n][0][rr] + pn[n][0] + pj[n][0][rr]));
                smem[n*3712 + row*136 + chan1] = f2bf(silu_f(acc1[n][1][rr] + pn[n][1] + pj[n][1][rr]));
            }
    }
    // B-fragments for layer 2
    v8bf B2[2][4];
    #pragma unroll
    for (int c2 = 0; c2 < 2; ++c2) {
        const int ct = wv*2 + c2;
        #pragma unroll
        for (int ks = 0; ks < 4; ++ks)
            B2[c2][ks] = *(const v8bf*)(We2t + (size_t)(ct*16 + r16)*128 + ks*32 + quad*8);
    }
    __syncthreads();

    // ---- layer 2 MFMA ----
    v4f acc2[4][2];
    #pragma unroll
    for (int n = 0; n < 4; ++n) { acc2[n][0] = (v4f){0,0,0,0}; acc2[n][1] = (v4f){0,0,0,0}; }
    #pragma unroll
    for (int n = 0; n < 4; ++n) {
        v8bf a[4];
        #pragma unroll
        for (int ks = 0; ks < 4; ++ks)
            a[ks] = *(const v8bf*)(smem + n*3712 + r16*136 + ks*32 + quad*8);
        #pragma unroll
        for (int ks = 0; ks < 4; ++ks) {
            acc2[n][0] = __builtin_amdgcn_mfma_f32_16x16x32_bf16(a[ks], B2[0][ks], acc2[n][0], 0, 0, 0);
            acc2[n][1] = __builtin_amdgcn_mfma_f32_16x16x32_bf16(a[ks], B2[1][ks], acc2[n][1], 0, 0, 0);
        }
    }
    __syncthreads();   // sil reads done before overwrite

    // ---- epilogue 2: msum (masked row-sum) + silu(m) -> sil ----
    {
        const float be2c0 = be2[chan0], be2c1 = be2[chan1];
        #pragma unroll
        for (int n = 0; n < 4; ++n) {
            float m0[4], m1[4];
            float s0 = 0.0f, s1 = 0.0f;
            #pragma unroll
            for (int rr = 0; rr < 4; ++rr) {
                m0[rr] = acc2[n][0][rr] + be2c0;
                m1[rr] = acc2[n][1][rr] + be2c1;
                if (quad*4 + rr < KNN) { s0 += m0[rr]; s1 += m1[rr]; }
            }
            s0 += __shfl_xor(s0, 16); s0 += __shfl_xor(s0, 32);
            s1 += __shfl_xor(s1, 16); s1 += __shfl_xor(s1, 32);
            if (quad == 0) {
                msum[(size_t)(node0 + n)*128 + chan0] = s0;
                msum[(size_t)(node0 + n)*128 + chan1] = s1;
            }
            #pragma unroll
            for (int rr = 0; rr < 4; ++rr) {
                const int row = quad*4 + rr;
                smem[n*3712 + row*136 + chan0] = f2bf(silu_f(m0[rr]));
                smem[n*3712 + row*136 + chan1] = f2bf(silu_f(m1[rr]));
            }
        }
    }
    // B-fragments for layer 3
    v8bf B3[2][4];
    #pragma unroll
    for (int c2 = 0; c2 < 2; ++c2) {
        const int ct = wv*2 + c2;
        #pragma unroll
        for (int ks = 0; ks < 4; ++ks)
            B3[c2][ks] = *(const v8bf*)(Wx1t + (size_t)(ct*16 + r16)*128 + ks*32 + quad*8);
    }
    __syncthreads();

    // ---- layer 3 MFMA ----
    v4f acc3[4][2];
    #pragma unroll
    for (int n = 0; n < 4; ++n) { acc3[n][0] = (v4f){0,0,0,0}; acc3[n][1] = (v4f){0,0,0,0}; }
    #pragma unroll
    for (int n = 0; n < 4; ++n) {
        v8bf a[4];
        #pragma unroll
        for (int ks = 0; ks < 4; ++ks)
            a[ks] = *(const v8bf*)(smem + n*3712 + r16*136 + ks*32 + quad*8);
        #pragma unroll
        for (int ks = 0; ks < 4; ++ks) {
            acc3[n][0] = __builtin_amdgcn_mfma_f32_16x16x32_bf16(a[ks], B3[0][ks], acc3[n][0], 0, 0, 0);
            acc3[n][1] = __builtin_amdgcn_mfma_f32_16x16x32_bf16(a[ks], B3[1][ks], acc3[n][1], 0, 0, 0);
        }
    }

    // ---- epilogue 3: w partials, cross-wave reduce via LDS ----
    {
        const float bxc0 = bx1[chan0], bxc1 = bx1[chan1];
        const float wxc0 = Wx2[chan0], wxc1 = Wx2[chan1];
        #pragma unroll
        for (int n = 0; n < 4; ++n) {
            float pr[4];
            #pragma unroll
            for (int rr = 0; rr < 4; ++rr)
                pr[rr] = silu_f(acc3[n][0][rr] + bxc0) * wxc0
                       + silu_f(acc3[n][1][rr] + bxc1) * wxc1;
            #pragma unroll
            for (int rr = 0; rr < 4; ++rr) {
                pr[rr] += __shfl_xor(pr[rr], 1);
                pr[rr] += __shfl_xor(pr[rr], 2);
                pr[rr] += __shfl_xor(pr[rr], 4);
                pr[rr] += __shfl_xor(pr[rr], 8);
            }
            if (r16 == 0) {
                #pragma unroll
                for (int rr = 0; rr < 4; ++rr) {
                    const int e = quad*4 + rr;
                    if (e < KNN) wred[n][e][wv] = pr[rr];
                }
            }
        }
    }
    __syncthreads();
    if (tid < 4*KNN) {
        const int n = tid / KNN, e = tid % KNN;
        wbuf[(size_t)(node0 + n)*KNN + e] =
            wred[n][e][0] + wred[n][e][1] + wred[n][e][2] + wred[n][e][3] + bx2[0];
    }
}

// ---------------- K5: Hn = Hh + ffn([Hh, msum]);  X_out  (16 rows) ----------------
__global__ __launch_bounds__(128) void k_node(
    const float* __restrict__ X, const float* __restrict__ Hh,
    const float* __restrict__ msum, const int* __restrict__ idxb,
    const float* __restrict__ wbuf,
    const float* __restrict__ Wh1, const float* __restrict__ bh1,
    const float* __restrict__ Wh2, const float* __restrict__ bh2,
    float* __restrict__ Hn, float* __restrict__ outX)
{
    const int tid  = threadIdx.x;
    const int base = blockIdx.x * 16;
    __shared__ __align__(16) float sf[16][2*HDIM];
    __shared__ __align__(16) float sh[16][HDIM];

    #pragma unroll
    for (int r = 0; r < 16; ++r) {
        const int node = base + r;
        sf[r][tid]        = silu_f(Hh[(size_t)node*EDIM + tid]);
        sf[r][HDIM + tid] = silu_f(msum[(size_t)node*HDIM + tid]);
    }
    __syncthreads();

    float acc[16];
    #pragma unroll
    for (int r = 0; r < 16; ++r) acc[r] = 0.0f;
    for (int f4 = 0; f4 < 64; ++f4) {
        const float w0 = Wh1[(4*f4+0)*HDIM + tid];
        const float w1 = Wh1[(4*f4+1)*HDIM + tid];
        const float w2 = Wh1[(4*f4+2)*HDIM + tid];
        const float w3 = Wh1[(4*f4+3)*HDIM + tid];
        #pragma unroll
        for (int r = 0; r < 16; ++r) {
            const float4 v = *(const float4*)&sf[r][4*f4];
            float a = acc[r];
            a = fmaf(v.x, w0, a); a = fmaf(v.y, w1, a);
            a = fmaf(v.z, w2, a); a = fmaf(v.w, w3, a);
            acc[r] = a;
        }
    }
    const float b1 = bh1[tid];
    #pragma unroll
    for (int r = 0; r < 16; ++r) sh[r][tid] = silu_f(acc[r] + b1);
    __syncthreads();

    float acc2[16];
    #pragma unroll
    for (int r = 0; r < 16; ++r) acc2[r] = 0.0f;
    for (int f4 = 0; f4 < 32; ++f4) {
        const float w0 = Wh2[(4*f4+0)*EDIM + tid];
        const float w1 = Wh2[(4*f4+1)*EDIM + tid];
        const float w2 = Wh2[(4*f4+2)*EDIM + tid];
        const float w3 = Wh2[(4*f4+3)*EDIM + tid];
        #pragma unroll
        for (int r = 0; r < 16; ++r) {
            const float4 v = *(const float4*)&sh[r][4*f4];
            float a = acc2[r];
            a = fmaf(v.x, w0, a); a = fmaf(v.y, w1, a);
            a = fmaf(v.z, w2, a); a = fmaf(v.w, w3, a);
            acc2[r] = a;
        }
    }
    const float b2 = bh2[tid];
    #pragma unroll
    for (int r = 0; r < 16; ++r) {
        const int node = base + r;
        Hn[(size_t)node*EDIM + tid] = Hh[(size_t)node*EDIM + tid] + acc2[r] + b2;
    }

    for (int o = tid; o < 16*CC*3; o += 128) {
        const int r = o / (CC*3), q = o % (CC*3);
        const int node = base + r;
        const int b = node >> 10;
        const int c = q / 3, dc = q % 3;
        const float xv = X[((size_t)node*CC + c)*3 + dc];
        float a = 0.0f;
        for (int k = 0; k < KNN; ++k) {
            const int j = idxb[(size_t)node*KNN + k];
            const float xj = X[(((size_t)(b << 10) + j)*CC + c)*3 + dc];
            a += (xv - xj) * wbuf[(size_t)node*KNN + k];
        }
        outX[(size_t)node*CC*3 + q] = xv + a / 9.0f;
    }
}

// ---------------- K6: pd from precomputed A,B (prefetched gathers) ----------------
__global__ __launch_bounds__(128) void k_pd2(
    const float* __restrict__ AB, const int* __restrict__ idxb,
    const float* __restrict__ Wd2, const float* __restrict__ bd2,
    float* __restrict__ outPd)
{
    const int tid  = threadIdx.x;
    const int lane = tid & 63, wv = tid >> 6;
    const int node = blockIdx.x * 2 + wv;
    const int b    = node >> 10;
    const int c0   = lane, c1 = lane + 64;

    int jv = 0;
    if (lane < KNN) jv = idxb[(size_t)node*KNN + lane];

    const float An0 = AB[(size_t)node*256 + c0];
    const float An1 = AB[(size_t)node*256 + c1];
    const float Bn0 = AB[(size_t)node*256 + 128 + c0];
    const float Bn1 = AB[(size_t)node*256 + 128 + c1];
    const float w0  = Wd2[c0], w1 = Wd2[c1];
    const float b2  = 2.0f * bd2[0];

    float Aj0[KNN], Aj1[KNN], Bj0[KNN], Bj1[KNN];
    #pragma unroll
    for (int e = 0; e < KNN; ++e) {
        const size_t jn = (size_t)((b << 10) + __shfl(jv, e)) * 256;
        Aj0[e] = AB[jn + c0];       Aj1[e] = AB[jn + c1];
        Bj0[e] = AB[jn + 128 + c0]; Bj1[e] = AB[jn + 128 + c1];
    }
    #pragma unroll
    for (int e = 0; e < KNN; ++e) {
        float p = (silu_f(An0 + Bj0[e]) + silu_f(Aj0[e] + Bn0)) * w0
                + (silu_f(An1 + Bj1[e]) + silu_f(Aj1[e] + Bn1)) * w1;
        #pragma unroll
        for (int off = 32; off; off >>= 1) p += __shfl_xor(p, off, 64);
        if (lane == 0) outPd[(size_t)node*KNN + e] = p + b2;
    }
}

// ---------------- K7: gate + logits (16 rows) ----------------
__global__ __launch_bounds__(128) void k_logits(
    const float* __restrict__ Hn, const int* __restrict__ S,
    const float* __restrict__ emb,
    const float* __restrict__ Wp1, const float* __restrict__ bp1,
    const float* __restrict__ Wr1, const float* __restrict__ br1,
    const float* __restrict__ Wr2, const float* __restrict__ br2,
    float* __restrict__ outL)
{
    const int tid  = threadIdx.x;
    const int base = blockIdx.x * 16;
    __shared__ __align__(16) float s1[16][HDIM];
    __shared__ __align__(16) float s2[16][HDIM];

    #pragma unroll
    for (int r = 0; r < 16; ++r) s1[r][tid] = silu_f(Hn[(size_t)(base + r)*EDIM + tid]);
    __syncthreads();

    float acc[16];
    #pragma unroll
    for (int r = 0; r < 16; ++r) acc[r] = 0.0f;
    for (int f4 = 0; f4 < 32; ++f4) {
        const float w0 = Wp1[(4*f4+0)*EDIM + tid];
        const float w1 = Wp1[(4*f4+1)*EDIM + tid];
        const float w2 = Wp1[(4*f4+2)*EDIM + tid];
        const float w3 = Wp1[(4*f4+3)*EDIM + tid];
        #pragma unroll
        for (int r = 0; r < 16; ++r) {
            const float4 v = *(const float4*)&s1[r][4*f4];
            float a = acc[r];
            a = fmaf(v.x, w0, a); a = fmaf(v.y, w1, a);
            a = fmaf(v.z, w2, a); a = fmaf(v.w, w3, a);
            acc[r] = a;
        }
    }
    const float bp = bp1[tid];
    #pragma unroll
    for (int r = 0; r < 16; ++r) {
        const float g = 1.0f / (1.0f + __expf(-(acc[r] + bp)));
        const float x = emb[S[base + r]*EDIM + tid] * g;
        s2[r][tid] = silu_f(x);
    }
    __syncthreads();

    float acc2[16];
    #pragma unroll
    for (int r = 0; r < 16; ++r) acc2[r] = 0.0f;
    for (int f4 = 0; f4 < 32; ++f4) {
        const float w0 = Wr1[(4*f4+0)*HDIM + tid];
        const float w1 = Wr1[(4*f4+1)*HDIM + tid];
        const float w2 = Wr1[(4*f4+2)*HDIM + tid];
        const float w3 = Wr1[(4*f4+3)*HDIM + tid];
        #pragma unroll
        for (int r = 0; r < 16; ++r) {
            const float4 v = *(const float4*)&s2[r][4*f4];
            float a = acc2[r];
            a = fmaf(v.x, w0, a); a = fmaf(v.y, w1, a);
            a = fmaf(v.z, w2, a); a = fmaf(v.w, w3, a);
            acc2[r] = a;
        }
    }
    const float br = br1[tid];
    #pragma unroll
    for (int r = 0; r < 16; ++r) s1[r][tid] = silu_f(acc2[r] + br);
    __syncthreads();

    for (int o = tid; o < 16*NCLS; o += 128) {
        const int r = o / NCLS, j = o % NCLS;
        float s = 0.0f;
        for (int i = 0; i < 128; ++i) s += s1[r][i] * Wr2[i*NCLS + j];
        outL[(size_t)(base + r)*NCLS + j] = s + br2[j];
    }
}

extern "C" void kernel_launch(void* const* d_in, const int* in_sizes, int n_in,
                              void* d_out, int out_size, void* d_ws, size_t ws_size,
                              hipStream_t stream)
{
    const float* X   = (const float*)d_in[0];
    const int*   S   = (const int*)  d_in[1];
    const float* t   = (const float*)d_in[2];
    const float* emb = (const float*)d_in[3];
    const float* Wt1 = (const float*)d_in[4];
    const float* bt1 = (const float*)d_in[5];
    const float* Wt2 = (const float*)d_in[6];
    const float* bt2 = (const float*)d_in[7];
    const float* We1 = (const float*)d_in[8];
    const float* be1 = (const float*)d_in[9];
    const float* We2 = (const float*)d_in[10];
    const float* be2 = (const float*)d_in[11];
    const float* Wx1 = (const float*)d_in[12];
    const float* bx1 = (const float*)d_in[13];
    const float* Wx2 = (const float*)d_in[14];
    const float* bx2 = (const float*)d_in[15];
    const float* Wh1 = (const float*)d_in[16];
    const float* bh1 = (const float*)d_in[17];
    const float* Wh2 = (const float*)d_in[18];
    const float* bh2 = (const float*)d_in[19];
    const float* Wd1 = (const float*)d_in[20];
    const float* bd1 = (const float*)d_in[21];
    const float* Wd2 = (const float*)d_in[22];
    const float* bd2 = (const float*)d_in[23];
    const float* Wp1 = (const float*)d_in[24];
    const float* bp1 = (const float*)d_in[25];
    const float* Wr1 = (const float*)d_in[26];
    const float* br1 = (const float*)d_in[27];
    const float* Wr2 = (const float*)d_in[28];
    const float* br2 = (const float*)d_in[29];

    float* out   = (float*)d_out;
    float* outL  = out;
    float* outX  = out + (size_t)BN*NCLS;
    float* outPd = outX + (size_t)BN*CC*3;

    unsigned short* WeRt = (unsigned short*)d_ws;            // 128*224
    unsigned short* We2t = WeRt + 128*224;                   // 128*128
    unsigned short* Wx1t = We2t + 128*128;                   // 128*128
    float* Hh   = (float*)(Wx1t + 128*128);
    float* msum = Hh   + (size_t)BN*EDIM;
    float* Hn   = msum + (size_t)BN*HDIM;
    float* wbuf = Hn   + (size_t)BN*EDIM;
    float* P    = wbuf + (size_t)BN*KNN;
    int*   idxb = (int*)(P + (size_t)BN*256);

    k_prep   <<<240,    256, 0, stream>>>(We1, We2, Wx1, WeRt, We2t, Wx1t);
    k_hh     <<<BN/16,  128, 0, stream>>>(t, S, emb, Wt1, bt1, Wt2, bt2, Hh);
    k_knn    <<<BN/64,   64, 0, stream>>>(X, idxb);
    k_gemv256<<<BN/16,  256, 0, stream>>>(Hh, We1, be1, P);
    k_edge   <<<BN/4,   256, 0, stream>>>(X, idxb, P, WeRt, We2t, Wx1t,
                                          be2, bx1, Wx2, bx2, msum, wbuf);
    k_node   <<<BN/16,  128, 0, stream>>>(X, Hh, msum, idxb, wbuf,
                                          Wh1, bh1, Wh2, bh2, Hn, outX);
    k_gemv256<<<BN/16,  256, 0, stream>>>(Hn, Wd1, bd1, P);
    k_pd2    <<<BN/2,   128, 0, stream>>>(P, idxb, Wd2, bd2, outPd);
    k_logits <<<BN/16,  128, 0, stream>>>(Hn, S, emb, Wp1, bp1, Wr1, br1, Wr2, br2, outL);
}

// Round 5
// 744.880 us; speedup vs baseline: 3.8651x; 1.2891x over previous
//
#include <hip/hip_runtime.h>

#define BATCH 32
#define NPT   1024
#define CC    14
#define KNN   9
#define EDIM  128
#define HDIM  128
#define NCLS  25
#define BN    (BATCH*NPT)

typedef float  v4f __attribute__((ext_vector_type(4)));
typedef __bf16 v8bf __attribute__((ext_vector_type(8)));

__device__ __forceinline__ float silu_f(float x) { return x / (1.0f + __expf(-x)); }

__device__ __forceinline__ unsigned short f2bf(float f) {
    union { float f; unsigned u; } v; v.f = f;
    unsigned r = v.u + 0x7fffu + ((v.u >> 16) & 1u);
    return (unsigned short)(r >> 16);
}

// ---------------- K0: weight prep (transpose + bf16) ----------------
__global__ __launch_bounds__(256) void k_prep(
    const float* __restrict__ We1, const float* __restrict__ We2,
    const float* __restrict__ Wx1,
    unsigned short* __restrict__ WeRt, unsigned short* __restrict__ We2t,
    unsigned short* __restrict__ Wx1t)
{
    int i = blockIdx.x * 256 + threadIdx.x;
    if (i < 128*224) {
        const int chan = i / 224, k = i % 224;
        WeRt[i] = (k < 196) ? f2bf(We1[(size_t)(256 + k)*128 + chan]) : (unsigned short)0;
        return;
    }
    int i2 = i - 128*224;
    if (i2 < 128*128) {
        const int chan = i2 / 128, k = i2 % 128;
        We2t[i2] = f2bf(We2[(size_t)k*128 + chan]);
        return;
    }
    i2 -= 128*128;
    if (i2 < 128*128) {
        const int chan = i2 / 128, k = i2 % 128;
        Wx1t[i2] = f2bf(Wx1[(size_t)k*128 + chan]);
    }
}

// ---------------- K1: fused Hh + P = silu(Hh)@We1[0:256]+be1 ----------------
__global__ __launch_bounds__(256) void k_hhP(
    const float* __restrict__ t, const int* __restrict__ S,
    const float* __restrict__ emb,
    const float* __restrict__ Wt1, const float* __restrict__ bt1,
    const float* __restrict__ Wt2, const float* __restrict__ bt2,
    const float* __restrict__ We1, const float* __restrict__ be1,
    float* __restrict__ Hh, float* __restrict__ P)
{
    const int tid = threadIdx.x;
    const int col = tid & 127, rh = tid >> 7;
    const int base = blockIdx.x * 16;
    __shared__ __align__(16) float sg[16][128];
    __shared__ __align__(16) float sh[16][128];

    const float step  = 1.0f / 127.0f;
    const float coeff = -0.5f / (step * step);
    const float off   = step * (float)col;

    #pragma unroll
    for (int rr = 0; rr < 8; ++rr) {
        const int r = rh*8 + rr;
        float d = t[base + r] - off + 1e-6f;
        sg[r][col] = __expf(coeff * d * d);
    }
    __syncthreads();

    float acc[8];
    #pragma unroll
    for (int rr = 0; rr < 8; ++rr) acc[rr] = 0.0f;
    for (int f4 = 0; f4 < 32; ++f4) {
        const float w0 = Wt1[(4*f4+0)*128 + col];
        const float w1 = Wt1[(4*f4+1)*128 + col];
        const float w2 = Wt1[(4*f4+2)*128 + col];
        const float w3 = Wt1[(4*f4+3)*128 + col];
        #pragma unroll
        for (int rr = 0; rr < 8; ++rr) {
            const float4 v = *(const float4*)&sg[rh*8 + rr][4*f4];
            float a = acc[rr];
            a = fmaf(v.x, w0, a); a = fmaf(v.y, w1, a);
            a = fmaf(v.z, w2, a); a = fmaf(v.w, w3, a);
            acc[rr] = a;
        }
    }
    const float b1 = bt1[col];
    #pragma unroll
    for (int rr = 0; rr < 8; ++rr) sh[rh*8 + rr][col] = fmaxf(acc[rr] + b1, 0.0f);
    __syncthreads();

    #pragma unroll
    for (int rr = 0; rr < 8; ++rr) acc[rr] = 0.0f;
    for (int f4 = 0; f4 < 32; ++f4) {
        const float w0 = Wt2[(4*f4+0)*128 + col];
        const float w1 = Wt2[(4*f4+1)*128 + col];
        const float w2 = Wt2[(4*f4+2)*128 + col];
        const float w3 = Wt2[(4*f4+3)*128 + col];
        #pragma unroll
        for (int rr = 0; rr < 8; ++rr) {
            const float4 v = *(const float4*)&sh[rh*8 + rr][4*f4];
            float a = acc[rr];
            a = fmaf(v.x, w0, a); a = fmaf(v.y, w1, a);
            a = fmaf(v.z, w2, a); a = fmaf(v.w, w3, a);
            acc[rr] = a;
        }
    }
    const float b2 = bt2[col];
    #pragma unroll
    for (int rr = 0; rr < 8; ++rr) {
        const int r = rh*8 + rr;
        const int node = base + r;
        const float hh = emb[S[node]*128 + col] + acc[rr] + b2;
        Hh[(size_t)node*128 + col] = hh;
        sg[r][col] = silu_f(hh);
    }
    __syncthreads();

    // gemv1: P[node][tid]
    {
        const float* Wp = We1 + (size_t)(tid >> 7) * 128 * 128;
        float a16[16];
        #pragma unroll
        for (int r = 0; r < 16; ++r) a16[r] = 0.0f;
        for (int f4 = 0; f4 < 32; ++f4) {
            const float w0 = Wp[(4*f4+0)*128 + col];
            const float w1 = Wp[(4*f4+1)*128 + col];
            const float w2 = Wp[(4*f4+2)*128 + col];
            const float w3 = Wp[(4*f4+3)*128 + col];
            #pragma unroll
            for (int r = 0; r < 16; ++r) {
                const float4 v = *(const float4*)&sg[r][4*f4];
                float a = a16[r];
                a = fmaf(v.x, w0, a); a = fmaf(v.y, w1, a);
                a = fmaf(v.z, w2, a); a = fmaf(v.w, w3, a);
                a16[r] = a;
            }
        }
        const float fb = (tid < 128) ? be1[col] : 0.0f;
        #pragma unroll
        for (int r = 0; r < 16; ++r)
            P[(size_t)(base + r)*256 + tid] = a16[r] + fb;
    }
}

// ---------------- K2: KNN top-9, 4 waves split the scan ----------------
__global__ __launch_bounds__(256) void k_knn(
    const float* __restrict__ X, int* __restrict__ idxb)
{
    __shared__ __align__(16) float4 Cc[NPT];      // 16 KB
    __shared__ float dsh[4][64][KNN];
    __shared__ int   ish[4][64][KNN];

    const int tid = threadIdx.x, lane = tid & 63, wv = tid >> 6;
    const int bb = blockIdx.x >> 4;
    const int n0 = (blockIdx.x & 15) << 6;
    const float* Xb = X + (size_t)bb * NPT * 42;

    for (int i = tid; i < NPT; i += 256) {
        const float* p = Xb + (size_t)i*42 + 3;
        Cc[i] = make_float4(p[0], p[1], p[2], 0.0f);
    }
    __syncthreads();

    const int n = n0 + lane;
    const float4 c = Cc[n];

    float dist[KNN]; int ind[KNN];
    #pragma unroll
    for (int k = 0; k < KNN; ++k) { dist[k] = 3.0e38f; ind[k] = -1; }

    const int j0 = wv * 256;
    for (int jj = 0; jj < 256; ++jj) {
        const int j = j0 + jj;
        const float4 q = Cc[j];
        const float dx = __fsub_rn(c.x, q.x);
        const float dy = __fsub_rn(c.y, q.y);
        const float dz = __fsub_rn(c.z, q.z);
        float d = __fadd_rn(__fadd_rn(__fmul_rn(dx,dx), __fmul_rn(dy,dy)), __fmul_rn(dz,dz));
        if (j == n) d = __fadd_rn(d, 1e10f);
        if (d < dist[KNN-1]) {
            dist[KNN-1] = d; ind[KNN-1] = j;
            #pragma unroll
            for (int p = KNN-1; p > 0; --p) {
                if (dist[p] < dist[p-1]) {
                    float td = dist[p]; dist[p] = dist[p-1]; dist[p-1] = td;
                    int   ti = ind[p];  ind[p]  = ind[p-1];  ind[p-1]  = ti;
                }
            }
        }
    }
    #pragma unroll
    for (int k = 0; k < KNN; ++k) { dsh[wv][lane][k] = dist[k]; ish[wv][lane][k] = ind[k]; }
    __syncthreads();

    if (tid < 64) {
        float fd[KNN]; int fi[KNN];
        #pragma unroll
        for (int k = 0; k < KNN; ++k) { fd[k] = 3.0e38f; fi[k] = -1; }
        // merge in w-ascending (= j-ascending) order; strict < keeps lowest index on ties
        for (int w = 0; w < 4; ++w)
            #pragma unroll
            for (int k = 0; k < KNN; ++k) {
                const float d = dsh[w][tid][k];
                const int   i = ish[w][tid][k];
                if (d < fd[KNN-1]) {
                    fd[KNN-1] = d; fi[KNN-1] = i;
                    #pragma unroll
                    for (int p = KNN-1; p > 0; --p) {
                        if (fd[p] < fd[p-1]) {
                            float td = fd[p]; fd[p] = fd[p-1]; fd[p-1] = td;
                            int   ti = fi[p]; fi[p] = fi[p-1]; fi[p-1] = ti;
                        }
                    }
                }
            }
        const int node = (bb << 10) + n0 + tid;
        #pragma unroll
        for (int k = 0; k < KNN; ++k) idxb[(size_t)node*KNN + k] = fi[k];
    }
}

// ---------------- K4: MFMA edge pipeline, LDS-read staging ----------------
__global__ __launch_bounds__(256) void k_edge(
    const float* __restrict__ X, const int* __restrict__ idxb,
    const float* __restrict__ P,
    const unsigned short* __restrict__ WeRt,
    const unsigned short* __restrict__ We2t,
    const unsigned short* __restrict__ Wx1t,
    const float* __restrict__ be2,
    const float* __restrict__ bx1, const float* __restrict__ Wx2,
    const float* __restrict__ bx2,
    float* __restrict__ msum, float* __restrict__ wbuf)
{
    __shared__ unsigned short smem[4*16*232];     // 29696 B
    __shared__ __align__(16) float relS[4][KNN][64];  // 9216 B
    __shared__ float wred[4][KNN][4];
    __shared__ int   jsh[4][16];

    const int tid  = threadIdx.x;
    const int wv   = tid >> 6, lane = tid & 63;
    const int quad = lane >> 4, r16 = lane & 15;
    const int node0  = blockIdx.x * 4;
    const int mynode = node0 + wv;
    const int b      = node0 >> 10;
    const int chan0  = (wv*2 + 0)*16 + r16;
    const int chan1  = (wv*2 + 1)*16 + r16;

    // B-fragments for layer 1 (regs, reused across 4 nodes)
    v8bf B1[2][7];
    #pragma unroll
    for (int c2 = 0; c2 < 2; ++c2) {
        const int ct = wv*2 + c2;
        #pragma unroll
        for (int ks = 0; ks < 7; ++ks)
            B1[c2][ks] = *(const v8bf*)(WeRt + (size_t)(ct*16 + r16)*224 + ks*32 + quad*8);
    }

    int jv = 0;
    if (lane < KNN) jv = idxb[(size_t)mynode*KNN + lane];
    if (lane < KNN) jsh[wv][lane] = jv;
    const float xn = (lane < 42) ? X[(size_t)mynode*42 + lane] : 0.0f;

    // zero the K-pad rows (196..223) once
    for (int z = lane; z < KNN*28; z += 64)
        smem[wv*3712 + (z/28)*232 + 196 + (z%28)] = 0;

    // rel into per-wave LDS, padded [c][4]
    #pragma unroll
    for (int e = 0; e < KNN; ++e) {
        const int j = __shfl(jv, e);
        if (lane < 42)
            relS[wv][e][(lane/3)*4 + (lane%3)] = xn - X[(size_t)((b << 10) + j)*42 + lane];
    }

    // per-lane feature coords (hoisted)
    int offC[3], offE[3];
    #pragma unroll
    for (int rr = 0; rr < 3; ++rr) {
        const int f = rr*64 + lane;
        offC[rr] = (f / 14) * 4;
        offE[rr] = (f % 14) * 4;
    }
    const int f3 = 192 + lane;
    const int offC3 = (f3 / 14) * 4, offE3 = (f3 % 14) * 4;

    // silu(radial) -> bf16 LDS
    #pragma unroll
    for (int e = 0; e < KNN; ++e) {
        const float* rb = &relS[wv][e][0];
        #pragma unroll
        for (int rr = 0; rr < 3; ++rr) {
            const float4 a  = *(const float4*)(rb + offC[rr]);
            const float4 bb = *(const float4*)(rb + offE[rr]);
            const float v = (a.x*bb.x + a.y*bb.y + a.z*bb.z) * (1.0f/14.0f);
            smem[wv*3712 + e*232 + rr*64 + lane] = f2bf(silu_f(v));
        }
        if (lane < 4) {
            const float4 a  = *(const float4*)(rb + offC3);
            const float4 bb = *(const float4*)(rb + offE3);
            const float v = (a.x*bb.x + a.y*bb.y + a.z*bb.z) * (1.0f/14.0f);
            smem[wv*3712 + e*232 + 192 + lane] = f2bf(silu_f(v));
        }
    }
    __syncthreads();

    // ---- layer 1 MFMA ----
    v4f acc1[4][2];
    #pragma unroll
    for (int n = 0; n < 4; ++n) { acc1[n][0] = (v4f){0,0,0,0}; acc1[n][1] = (v4f){0,0,0,0}; }
    #pragma unroll
    for (int n = 0; n < 4; ++n) {
        v8bf a[7];
        #pragma unroll
        for (int ks = 0; ks < 7; ++ks)
            a[ks] = *(const v8bf*)(smem + n*3712 + r16*232 + ks*32 + quad*8);
        #pragma unroll
        for (int ks = 0; ks < 7; ++ks) {
            acc1[n][0] = __builtin_amdgcn_mfma_f32_16x16x32_bf16(a[ks], B1[0][ks], acc1[n][0], 0, 0, 0);
            acc1[n][1] = __builtin_amdgcn_mfma_f32_16x16x32_bf16(a[ks], B1[1][ks], acc1[n][1], 0, 0, 0);
        }
    }
    __syncthreads();

    // ---- epilogue 1: + Pn + Pj, silu -> sil (overlay stride 136) ----
    {
        float pn[4][2], pj[4][2][4];
        #pragma unroll
        for (int n = 0; n < 4; ++n) {
            pn[n][0] = P[(size_t)(node0 + n)*256 + chan0];
            pn[n][1] = P[(size_t)(node0 + n)*256 + chan1];
            #pragma unroll
            for (int rr = 0; rr < 4; ++rr) {
                const int e = quad*4 + rr;
                const int jq = jsh[n][(e < KNN) ? e : (KNN-1)];
                const size_t jrow = (size_t)((b << 10) + jq)*256 + 128;
                pj[n][0][rr] = P[jrow + chan0];
                pj[n][1][rr] = P[jrow + chan1];
            }
        }
        #pragma unroll
        for (int n = 0; n < 4; ++n)
            #pragma unroll
            for (int rr = 0; rr < 4; ++rr) {
                const int row = quad*4 + rr;
                smem[n*3712 + row*136 + chan0] = f2bf(silu_f(acc1[n][0][rr] + pn[n][0] + pj[n][0][rr]));
                smem[n*3712 + row*136 + chan1] = f2bf(silu_f(acc1[n][1][rr] + pn[n][1] + pj[n][1][rr]));
            }
    }
    v8bf B2[2][4];
    #pragma unroll
    for (int c2 = 0; c2 < 2; ++c2) {
        const int ct = wv*2 + c2;
        #pragma unroll
        for (int ks = 0; ks < 4; ++ks)
            B2[c2][ks] = *(const v8bf*)(We2t + (size_t)(ct*16 + r16)*128 + ks*32 + quad*8);
    }
    __syncthreads();

    // ---- layer 2 MFMA ----
    v4f acc2[4][2];
    #pragma unroll
    for (int n = 0; n < 4; ++n) { acc2[n][0] = (v4f){0,0,0,0}; acc2[n][1] = (v4f){0,0,0,0}; }
    #pragma unroll
    for (int n = 0; n < 4; ++n) {
        v8bf a[4];
        #pragma unroll
        for (int ks = 0; ks < 4; ++ks)
            a[ks] = *(const v8bf*)(smem + n*3712 + r16*136 + ks*32 + quad*8);
        #pragma unroll
        for (int ks = 0; ks < 4; ++ks) {
            acc2[n][0] = __builtin_amdgcn_mfma_f32_16x16x32_bf16(a[ks], B2[0][ks], acc2[n][0], 0, 0, 0);
            acc2[n][1] = __builtin_amdgcn_mfma_f32_16x16x32_bf16(a[ks], B2[1][ks], acc2[n][1], 0, 0, 0);
        }
    }
    __syncthreads();

    // ---- epilogue 2: msum + silu(m) -> sil ----
    {
        const float be2c0 = be2[chan0], be2c1 = be2[chan1];
        #pragma unroll
        for (int n = 0; n < 4; ++n) {
            float m0[4], m1[4];
            float s0 = 0.0f, s1 = 0.0f;
            #pragma unroll
            for (int rr = 0; rr < 4; ++rr) {
                m0[rr] = acc2[n][0][rr] + be2c0;
                m1[rr] = acc2[n][1][rr] + be2c1;
                if (quad*4 + rr < KNN) { s0 += m0[rr]; s1 += m1[rr]; }
            }
            s0 += __shfl_xor(s0, 16); s0 += __shfl_xor(s0, 32);
            s1 += __shfl_xor(s1, 16); s1 += __shfl_xor(s1, 32);
            if (quad == 0) {
                msum[(size_t)(node0 + n)*128 + chan0] = s0;
                msum[(size_t)(node0 + n)*128 + chan1] = s1;
            }
            #pragma unroll
            for (int rr = 0; rr < 4; ++rr) {
                const int row = quad*4 + rr;
                smem[n*3712 + row*136 + chan0] = f2bf(silu_f(m0[rr]));
                smem[n*3712 + row*136 + chan1] = f2bf(silu_f(m1[rr]));
            }
        }
    }
    v8bf B3[2][4];
    #pragma unroll
    for (int c2 = 0; c2 < 2; ++c2) {
        const int ct = wv*2 + c2;
        #pragma unroll
        for (int ks = 0; ks < 4; ++ks)
            B3[c2][ks] = *(const v8bf*)(Wx1t + (size_t)(ct*16 + r16)*128 + ks*32 + quad*8);
    }
    __syncthreads();

    // ---- layer 3 MFMA ----
    v4f acc3[4][2];
    #pragma unroll
    for (int n = 0; n < 4; ++n) { acc3[n][0] = (v4f){0,0,0,0}; acc3[n][1] = (v4f){0,0,0,0}; }
    #pragma unroll
    for (int n = 0; n < 4; ++n) {
        v8bf a[4];
        #pragma unroll
        for (int ks = 0; ks < 4; ++ks)
            a[ks] = *(const v8bf*)(smem + n*3712 + r16*136 + ks*32 + quad*8);
        #pragma unroll
        for (int ks = 0; ks < 4; ++ks) {
            acc3[n][0] = __builtin_amdgcn_mfma_f32_16x16x32_bf16(a[ks], B3[0][ks], acc3[n][0], 0, 0, 0);
            acc3[n][1] = __builtin_amdgcn_mfma_f32_16x16x32_bf16(a[ks], B3[1][ks], acc3[n][1], 0, 0, 0);
        }
    }

    // ---- epilogue 3 ----
    {
        const float bxc0 = bx1[chan0], bxc1 = bx1[chan1];
        const float wxc0 = Wx2[chan0], wxc1 = Wx2[chan1];
        #pragma unroll
        for (int n = 0; n < 4; ++n) {
            float pr[4];
            #pragma unroll
            for (int rr = 0; rr < 4; ++rr)
                pr[rr] = silu_f(acc3[n][0][rr] + bxc0) * wxc0
                       + silu_f(acc3[n][1][rr] + bxc1) * wxc1;
            #pragma unroll
            for (int rr = 0; rr < 4; ++rr) {
                pr[rr] += __shfl_xor(pr[rr], 1);
                pr[rr] += __shfl_xor(pr[rr], 2);
                pr[rr] += __shfl_xor(pr[rr], 4);
                pr[rr] += __shfl_xor(pr[rr], 8);
            }
            if (r16 == 0) {
                #pragma unroll
                for (int rr = 0; rr < 4; ++rr) {
                    const int e = quad*4 + rr;
                    if (e < KNN) wred[n][e][wv] = pr[rr];
                }
            }
        }
    }
    __syncthreads();
    if (tid < 4*KNN) {
        const int n = tid / KNN, e = tid % KNN;
        wbuf[(size_t)(node0 + n)*KNN + e] =
            wred[n][e][0] + wred[n][e][1] + wred[n][e][2] + wred[n][e][3] + bx2[0];
    }
}

// ---------------- K5: fused node update + AB gemv + logits + X_out ----------------
__global__ __launch_bounds__(256) void k_nodeF(
    const float* __restrict__ X, const float* __restrict__ Hh,
    const float* __restrict__ msum, const int* __restrict__ idxb,
    const float* __restrict__ wbuf,
    const float* __restrict__ Wh1, const float* __restrict__ bh1,
    const float* __restrict__ Wh2, const float* __restrict__ bh2,
    const float* __restrict__ Wd1, const float* __restrict__ bd1,
    const int* __restrict__ S, const float* __restrict__ emb,
    const float* __restrict__ Wp1, const float* __restrict__ bp1,
    const float* __restrict__ Wr1, const float* __restrict__ br1,
    const float* __restrict__ Wr2, const float* __restrict__ br2,
    float* __restrict__ Hn, float* __restrict__ AB,
    float* __restrict__ outL, float* __restrict__ outX)
{
    const int tid = threadIdx.x;
    const int col = tid & 127, rh = tid >> 7;
    const int base = blockIdx.x * 16;
    __shared__ __align__(16) float sfA[16][256];   // staged [silu(Hh), silu(msum)]
    __shared__ __align__(16) float sh[16][128];
    __shared__ __align__(16) float ssil[16][128];

    #pragma unroll
    for (int r = 0; r < 16; ++r) {
        const int node = base + r;
        sfA[r][tid] = (tid < 128) ? silu_f(Hh[(size_t)node*128 + tid])
                                  : silu_f(msum[(size_t)node*128 + (tid - 128)]);
    }
    __syncthreads();

    // Wh1: K=256, split rows
    float acc[8];
    #pragma unroll
    for (int rr = 0; rr < 8; ++rr) acc[rr] = 0.0f;
    for (int f4 = 0; f4 < 64; ++f4) {
        const float w0 = Wh1[(4*f4+0)*128 + col];
        const float w1 = Wh1[(4*f4+1)*128 + col];
        const float w2 = Wh1[(4*f4+2)*128 + col];
        const float w3 = Wh1[(4*f4+3)*128 + col];
        #pragma unroll
        for (int rr = 0; rr < 8; ++rr) {
            const float4 v = *(const float4*)&sfA[rh*8 + rr][4*f4];
            float a = acc[rr];
            a = fmaf(v.x, w0, a); a = fmaf(v.y, w1, a);
            a = fmaf(v.z, w2, a); a = fmaf(v.w, w3, a);
            acc[rr] = a;
        }
    }
    const float b1 = bh1[col];
    #pragma unroll
    for (int rr = 0; rr < 8; ++rr) sh[rh*8 + rr][col] = silu_f(acc[rr] + b1);
    __syncthreads();

    // Wh2: K=128, split rows -> Hn + ssil
    #pragma unroll
    for (int rr = 0; rr < 8; ++rr) acc[rr] = 0.0f;
    for (int f4 = 0; f4 < 32; ++f4) {
        const float w0 = Wh2[(4*f4+0)*128 + col];
        const float w1 = Wh2[(4*f4+1)*128 + col];
        const float w2 = Wh2[(4*f4+2)*128 + col];
        const float w3 = Wh2[(4*f4+3)*128 + col];
        #pragma unroll
        for (int rr = 0; rr < 8; ++rr) {
            const float4 v = *(const float4*)&sh[rh*8 + rr][4*f4];
            float a = acc[rr];
            a = fmaf(v.x, w0, a); a = fmaf(v.y, w1, a);
            a = fmaf(v.z, w2, a); a = fmaf(v.w, w3, a);
            acc[rr] = a;
        }
    }
    const float b2 = bh2[col];
    #pragma unroll
    for (int rr = 0; rr < 8; ++rr) {
        const int r = rh*8 + rr;
        const int node = base + r;
        const float hn = Hh[(size_t)node*128 + col] + acc[rr] + b2;
        Hn[(size_t)node*128 + col] = hn;
        ssil[r][col] = silu_f(hn);
    }
    __syncthreads();

    // AB gemv (Wd1, 256 cols): thread owns col tid
    {
        const float* Wp = Wd1 + (size_t)(tid >> 7) * 128 * 128;
        float a16[16];
        #pragma unroll
        for (int r = 0; r < 16; ++r) a16[r] = 0.0f;
        for (int f4 = 0; f4 < 32; ++f4) {
            const float w0 = Wp[(4*f4+0)*128 + col];
            const float w1 = Wp[(4*f4+1)*128 + col];
            const float w2 = Wp[(4*f4+2)*128 + col];
            const float w3 = Wp[(4*f4+3)*128 + col];
            #pragma unroll
            for (int r = 0; r < 16; ++r) {
                const float4 v = *(const float4*)&ssil[r][4*f4];
                float a = a16[r];
                a = fmaf(v.x, w0, a); a = fmaf(v.y, w1, a);
                a = fmaf(v.z, w2, a); a = fmaf(v.w, w3, a);
                a16[r] = a;
            }
        }
        const float fb = (tid < 128) ? bd1[col] : 0.0f;
        #pragma unroll
        for (int r = 0; r < 16; ++r)
            AB[(size_t)(base + r)*256 + tid] = a16[r] + fb;
    }

    // gate (Wp1): split rows, reads ssil, writes sh (free after Wh2 barrier)
    {
        float ag[8];
        #pragma unroll
        for (int rr = 0; rr < 8; ++rr) ag[rr] = 0.0f;
        for (int f4 = 0; f4 < 32; ++f4) {
            const float w0 = Wp1[(4*f4+0)*128 + col];
            const float w1 = Wp1[(4*f4+1)*128 + col];
            const float w2 = Wp1[(4*f4+2)*128 + col];
            const float w3 = Wp1[(4*f4+3)*128 + col];
            #pragma unroll
            for (int rr = 0; rr < 8; ++rr) {
                const float4 v = *(const float4*)&ssil[rh*8 + rr][4*f4];
                float a = ag[rr];
                a = fmaf(v.x, w0, a); a = fmaf(v.y, w1, a);
                a = fmaf(v.z, w2, a); a = fmaf(v.w, w3, a);
                ag[rr] = a;
            }
        }
        const float bp = bp1[col];
        #pragma unroll
        for (int rr = 0; rr < 8; ++rr) {
            const int r = rh*8 + rr;
            const int node = base + r;
            const float g = 1.0f / (1.0f + __expf(-(ag[rr] + bp)));
            const float x = emb[S[node]*128 + col] * g;
            sh[r][col] = silu_f(x);
        }
    }
    __syncthreads();

    // Wr1: split rows, reads sh, writes sfA (free since Wh1)
    {
        float ar[8];
        #pragma unroll
        for (int rr = 0; rr < 8; ++rr) ar[rr] = 0.0f;
        for (int f4 = 0; f4 < 32; ++f4) {
            const float w0 = Wr1[(4*f4+0)*128 + col];
            const float w1 = Wr1[(4*f4+1)*128 + col];
            const float w2 = Wr1[(4*f4+2)*128 + col];
            const float w3 = Wr1[(4*f4+3)*128 + col];
            #pragma unroll
            for (int rr = 0; rr < 8; ++rr) {
                const float4 v = *(const float4*)&sh[rh*8 + rr][4*f4];
                float a = ar[rr];
                a = fmaf(v.x, w0, a); a = fmaf(v.y, w1, a);
                a = fmaf(v.z, w2, a); a = fmaf(v.w, w3, a);
                ar[rr] = a;
            }
        }
        const float br = br1[col];
        #pragma unroll
        for (int rr = 0; rr < 8; ++rr) sfA[rh*8 + rr][col] = silu_f(ar[rr] + br);
    }
    __syncthreads();

    // logits tail
    for (int o = tid; o < 16*NCLS; o += 256) {
        const int r = o / NCLS, j = o % NCLS;
        float s = 0.0f;
        for (int i = 0; i < 128; ++i) s += sfA[r][i] * Wr2[i*NCLS + j];
        outL[(size_t)(base + r)*NCLS + j] = s + br2[j];
    }

    // X_out
    for (int o = tid; o < 16*CC*3; o += 256) {
        const int r = o / (CC*3), q = o % (CC*3);
        const int node = base + r;
        const int b = node >> 10;
        const int c = q / 3, dc = q % 3;
        const float xv = X[((size_t)node*CC + c)*3 + dc];
        float a = 0.0f;
        for (int k = 0; k < KNN; ++k) {
            const int j = idxb[(size_t)node*KNN + k];
            const float xj = X[(((size_t)(b << 10) + j)*CC + c)*3 + dc];
            a += (xv - xj) * wbuf[(size_t)node*KNN + k];
        }
        outX[(size_t)node*CC*3 + q] = xv + a / 9.0f;
    }
}

// ---------------- K6: pd from precomputed A,B ----------------
__global__ __launch_bounds__(128) void k_pd2(
    const float* __restrict__ AB, const int* __restrict__ idxb,
    const float* __restrict__ Wd2, const float* __restrict__ bd2,
    float* __restrict__ outPd)
{
    const int tid  = threadIdx.x;
    const int lane = tid & 63, wv = tid >> 6;
    const int node = blockIdx.x * 2 + wv;
    const int b    = node >> 10;
    const int c0   = lane, c1 = lane + 64;

    int jv = 0;
    if (lane < KNN) jv = idxb[(size_t)node*KNN + lane];

    const float An0 = AB[(size_t)node*256 + c0];
    const float An1 = AB[(size_t)node*256 + c1];
    const float Bn0 = AB[(size_t)node*256 + 128 + c0];
    const float Bn1 = AB[(size_t)node*256 + 128 + c1];
    const float w0  = Wd2[c0], w1 = Wd2[c1];
    const float b2  = 2.0f * bd2[0];

    float Aj0[KNN], Aj1[KNN], Bj0[KNN], Bj1[KNN];
    #pragma unroll
    for (int e = 0; e < KNN; ++e) {
        const size_t jn = (size_t)((b << 10) + __shfl(jv, e)) * 256;
        Aj0[e] = AB[jn + c0];       Aj1[e] = AB[jn + c1];
        Bj0[e] = AB[jn + 128 + c0]; Bj1[e] = AB[jn + 128 + c1];
    }
    #pragma unroll
    for (int e = 0; e < KNN; ++e) {
        float p = (silu_f(An0 + Bj0[e]) + silu_f(Aj0[e] + Bn0)) * w0
                + (silu_f(An1 + Bj1[e]) + silu_f(Aj1[e] + Bn1)) * w1;
        #pragma unroll
        for (int off = 32; off; off >>= 1) p += __shfl_xor(p, off, 64);
        if (lane == 0) outPd[(size_t)node*KNN + e] = p + b2;
    }
}

extern "C" void kernel_launch(void* const* d_in, const int* in_sizes, int n_in,
                              void* d_out, int out_size, void* d_ws, size_t ws_size,
                              hipStream_t stream)
{
    const float* X   = (const float*)d_in[0];
    const int*   S   = (const int*)  d_in[1];
    const float* t   = (const float*)d_in[2];
    const float* emb = (const float*)d_in[3];
    const float* Wt1 = (const float*)d_in[4];
    const float* bt1 = (const float*)d_in[5];
    const float* Wt2 = (const float*)d_in[6];
    const float* bt2 = (const float*)d_in[7];
    const float* We1 = (const float*)d_in[8];
    const float* be1 = (const float*)d_in[9];
    const float* We2 = (const float*)d_in[10];
    const float* be2 = (const float*)d_in[11];
    const float* Wx1 = (const float*)d_in[12];
    const float* bx1 = (const float*)d_in[13];
    const float* Wx2 = (const float*)d_in[14];
    const float* bx2 = (const float*)d_in[15];
    const float* Wh1 = (const float*)d_in[16];
    const float* bh1 = (const float*)d_in[17];
    const float* Wh2 = (const float*)d_in[18];
    const float* bh2 = (const float*)d_in[19];
    const float* Wd1 = (const float*)d_in[20];
    const float* bd1 = (const float*)d_in[21];
    const float* Wd2 = (const float*)d_in[22];
    const float* bd2 = (const float*)d_in[23];
    const float* Wp1 = (const float*)d_in[24];
    const float* bp1 = (const float*)d_in[25];
    const float* Wr1 = (const float*)d_in[26];
    const float* br1 = (const float*)d_in[27];
    const float* Wr2 = (const float*)d_in[28];
    const float* br2 = (const float*)d_in[29];

    float* out   = (float*)d_out;
    float* outL  = out;
    float* outX  = out + (size_t)BN*NCLS;
    float* outPd = outX + (size_t)BN*CC*3;

    unsigned short* WeRt = (unsigned short*)d_ws;            // 128*224
    unsigned short* We2t = WeRt + 128*224;                   // 128*128
    unsigned short* Wx1t = We2t + 128*128;                   // 128*128
    float* Hh   = (float*)(Wx1t + 128*128);
    float* msum = Hh   + (size_t)BN*EDIM;
    float* Hn   = msum + (size_t)BN*HDIM;
    float* wbuf = Hn   + (size_t)BN*EDIM;
    float* P    = wbuf + (size_t)BN*KNN;                     // BN*256, also AB
    int*   idxb = (int*)(P + (size_t)BN*256);

    k_prep  <<<240,    256, 0, stream>>>(We1, We2, Wx1, WeRt, We2t, Wx1t);
    k_hhP   <<<BN/16,  256, 0, stream>>>(t, S, emb, Wt1, bt1, Wt2, bt2, We1, be1, Hh, P);
    k_knn   <<<BN/64,  256, 0, stream>>>(X, idxb);
    k_edge  <<<BN/4,   256, 0, stream>>>(X, idxb, P, WeRt, We2t, Wx1t,
                                         be2, bx1, Wx2, bx2, msum, wbuf);
    k_nodeF <<<BN/16,  256, 0, stream>>>(X, Hh, msum, idxb, wbuf,
                                         Wh1, bh1, Wh2, bh2, Wd1, bd1,
                                         S, emb, Wp1, bp1, Wr1, br1, Wr2, br2,
                                         Hn, P, outL, outX);
    k_pd2   <<<BN/2,   128, 0, stream>>>(P, idxb, Wd2, bd2, outPd);
}

// Round 6
// 631.977 us; speedup vs baseline: 4.5556x; 1.1786x over previous
//
#include <hip/hip_runtime.h>

#define BATCH 32
#define NPT   1024
#define CC    14
#define KNN   9
#define EDIM  128
#define HDIM  128
#define NCLS  25
#define BN    (BATCH*NPT)

// k_edge LDS strides (ushorts): start-bank-distinct (≡6/22 mod 32 dwords)
#define RSTR  236
#define NREG  3776      // 16*RSTR per node
#define SSTR  140

typedef float  v4f __attribute__((ext_vector_type(4)));
typedef __bf16 v8bf __attribute__((ext_vector_type(8)));

__device__ __forceinline__ float silu_f(float x) { return x / (1.0f + __expf(-x)); }

__device__ __forceinline__ unsigned short f2bf(float f) {
    union { float f; unsigned u; } v; v.f = f;
    unsigned r = v.u + 0x7fffu + ((v.u >> 16) & 1u);
    return (unsigned short)(r >> 16);
}

// ---------------- K0: weight prep (transpose + bf16) ----------------
__global__ __launch_bounds__(256) void k_prep(
    const float* __restrict__ We1, const float* __restrict__ We2,
    const float* __restrict__ Wx1, const float* __restrict__ Wh1,
    const float* __restrict__ Wh2, const float* __restrict__ Wd1,
    const float* __restrict__ Wp1, const float* __restrict__ Wr1,
    unsigned short* __restrict__ WeRt, unsigned short* __restrict__ We2t,
    unsigned short* __restrict__ Wx1t, unsigned short* __restrict__ Wh1t,
    unsigned short* __restrict__ Wh2t, unsigned short* __restrict__ Wd1t,
    unsigned short* __restrict__ Wp1t, unsigned short* __restrict__ Wr1t)
{
    int i = blockIdx.x * 256 + threadIdx.x;
    if (i < 128*224) {
        const int chan = i / 224, k = i % 224;
        WeRt[i] = (k < 196) ? f2bf(We1[(size_t)(256 + k)*128 + chan]) : (unsigned short)0;
        return;
    }
    i -= 128*224;
    if (i < 16384) { We2t[i] = f2bf(We2[(size_t)(i % 128)*128 + i/128]); return; }
    i -= 16384;
    if (i < 16384) { Wx1t[i] = f2bf(Wx1[(size_t)(i % 128)*128 + i/128]); return; }
    i -= 16384;
    if (i < 32768) { const int c = i/256, k = i%256; Wh1t[i] = f2bf(Wh1[(size_t)k*128 + c]); return; }
    i -= 32768;
    if (i < 16384) { Wh2t[i] = f2bf(Wh2[(size_t)(i % 128)*128 + i/128]); return; }
    i -= 16384;
    if (i < 32768) {
        const int t = i/128, k = i%128;
        Wd1t[i] = f2bf((t < 128) ? Wd1[(size_t)k*128 + t] : Wd1[(size_t)(128 + k)*128 + (t - 128)]);
        return;
    }
    i -= 32768;
    if (i < 16384) { Wp1t[i] = f2bf(Wp1[(size_t)(i % 128)*128 + i/128]); return; }
    i -= 16384;
    if (i < 16384) { Wr1t[i] = f2bf(Wr1[(size_t)(i % 128)*128 + i/128]); return; }
}

// ---------------- K1: fused Hh + P = silu(Hh)@We1[0:256]+be1 ----------------
__global__ __launch_bounds__(256) void k_hhP(
    const float* __restrict__ t, const int* __restrict__ S,
    const float* __restrict__ emb,
    const float* __restrict__ Wt1, const float* __restrict__ bt1,
    const float* __restrict__ Wt2, const float* __restrict__ bt2,
    const float* __restrict__ We1, const float* __restrict__ be1,
    float* __restrict__ Hh, float* __restrict__ P)
{
    const int tid = threadIdx.x;
    const int col = tid & 127, rh = tid >> 7;
    const int base = blockIdx.x * 16;
    __shared__ __align__(16) float sg[16][128];
    __shared__ __align__(16) float sh[16][128];

    const float step  = 1.0f / 127.0f;
    const float coeff = -0.5f / (step * step);
    const float off   = step * (float)col;

    #pragma unroll
    for (int rr = 0; rr < 8; ++rr) {
        const int r = rh*8 + rr;
        float d = t[base + r] - off + 1e-6f;
        sg[r][col] = __expf(coeff * d * d);
    }
    __syncthreads();

    float acc[8];
    #pragma unroll
    for (int rr = 0; rr < 8; ++rr) acc[rr] = 0.0f;
    for (int f4 = 0; f4 < 32; ++f4) {
        const float w0 = Wt1[(4*f4+0)*128 + col];
        const float w1 = Wt1[(4*f4+1)*128 + col];
        const float w2 = Wt1[(4*f4+2)*128 + col];
        const float w3 = Wt1[(4*f4+3)*128 + col];
        #pragma unroll
        for (int rr = 0; rr < 8; ++rr) {
            const float4 v = *(const float4*)&sg[rh*8 + rr][4*f4];
            float a = acc[rr];
            a = fmaf(v.x, w0, a); a = fmaf(v.y, w1, a);
            a = fmaf(v.z, w2, a); a = fmaf(v.w, w3, a);
            acc[rr] = a;
        }
    }
    const float b1 = bt1[col];
    #pragma unroll
    for (int rr = 0; rr < 8; ++rr) sh[rh*8 + rr][col] = fmaxf(acc[rr] + b1, 0.0f);
    __syncthreads();

    #pragma unroll
    for (int rr = 0; rr < 8; ++rr) acc[rr] = 0.0f;
    for (int f4 = 0; f4 < 32; ++f4) {
        const float w0 = Wt2[(4*f4+0)*128 + col];
        const float w1 = Wt2[(4*f4+1)*128 + col];
        const float w2 = Wt2[(4*f4+2)*128 + col];
        const float w3 = Wt2[(4*f4+3)*128 + col];
        #pragma unroll
        for (int rr = 0; rr < 8; ++rr) {
            const float4 v = *(const float4*)&sh[rh*8 + rr][4*f4];
            float a = acc[rr];
            a = fmaf(v.x, w0, a); a = fmaf(v.y, w1, a);
            a = fmaf(v.z, w2, a); a = fmaf(v.w, w3, a);
            acc[rr] = a;
        }
    }
    const float b2 = bt2[col];
    #pragma unroll
    for (int rr = 0; rr < 8; ++rr) {
        const int r = rh*8 + rr;
        const int node = base + r;
        const float hh = emb[S[node]*128 + col] + acc[rr] + b2;
        Hh[(size_t)node*128 + col] = hh;
        sg[r][col] = silu_f(hh);
    }
    __syncthreads();

    {
        const float* Wp = We1 + (size_t)(tid >> 7) * 128 * 128;
        float a16[16];
        #pragma unroll
        for (int r = 0; r < 16; ++r) a16[r] = 0.0f;
        for (int f4 = 0; f4 < 32; ++f4) {
            const float w0 = Wp[(4*f4+0)*128 + col];
            const float w1 = Wp[(4*f4+1)*128 + col];
            const float w2 = Wp[(4*f4+2)*128 + col];
            const float w3 = Wp[(4*f4+3)*128 + col];
            #pragma unroll
            for (int r = 0; r < 16; ++r) {
                const float4 v = *(const float4*)&sg[r][4*f4];
                float a = a16[r];
                a = fmaf(v.x, w0, a); a = fmaf(v.y, w1, a);
                a = fmaf(v.z, w2, a); a = fmaf(v.w, w3, a);
                a16[r] = a;
            }
        }
        const float fb = (tid < 128) ? be1[col] : 0.0f;
        #pragma unroll
        for (int r = 0; r < 16; ++r)
            P[(size_t)(base + r)*256 + tid] = a16[r] + fb;
    }
}

// ---------------- K2: KNN top-9, 4 waves split the scan ----------------
__global__ __launch_bounds__(256) void k_knn(
    const float* __restrict__ X, int* __restrict__ idxb)
{
    __shared__ __align__(16) float4 Cc[NPT];
    __shared__ float dsh[4][64][KNN];
    __shared__ int   ish[4][64][KNN];

    const int tid = threadIdx.x, lane = tid & 63, wv = tid >> 6;
    const int bb = blockIdx.x >> 4;
    const int n0 = (blockIdx.x & 15) << 6;
    const float* Xb = X + (size_t)bb * NPT * 42;

    for (int i = tid; i < NPT; i += 256) {
        const float* p = Xb + (size_t)i*42 + 3;
        Cc[i] = make_float4(p[0], p[1], p[2], 0.0f);
    }
    __syncthreads();

    const int n = n0 + lane;
    const float4 c = Cc[n];

    float dist[KNN]; int ind[KNN];
    #pragma unroll
    for (int k = 0; k < KNN; ++k) { dist[k] = 3.0e38f; ind[k] = -1; }

    const int j0 = wv * 256;
    for (int jj = 0; jj < 256; ++jj) {
        const int j = j0 + jj;
        const float4 q = Cc[j];
        const float dx = __fsub_rn(c.x, q.x);
        const float dy = __fsub_rn(c.y, q.y);
        const float dz = __fsub_rn(c.z, q.z);
        float d = __fadd_rn(__fadd_rn(__fmul_rn(dx,dx), __fmul_rn(dy,dy)), __fmul_rn(dz,dz));
        if (j == n) d = __fadd_rn(d, 1e10f);
        if (d < dist[KNN-1]) {
            dist[KNN-1] = d; ind[KNN-1] = j;
            #pragma unroll
            for (int p = KNN-1; p > 0; --p) {
                if (dist[p] < dist[p-1]) {
                    float td = dist[p]; dist[p] = dist[p-1]; dist[p-1] = td;
                    int   ti = ind[p];  ind[p]  = ind[p-1];  ind[p-1]  = ti;
                }
            }
        }
    }
    #pragma unroll
    for (int k = 0; k < KNN; ++k) { dsh[wv][lane][k] = dist[k]; ish[wv][lane][k] = ind[k]; }
    __syncthreads();

    if (tid < 64) {
        float fd[KNN]; int fi[KNN];
        #pragma unroll
        for (int k = 0; k < KNN; ++k) { fd[k] = 3.0e38f; fi[k] = -1; }
        for (int w = 0; w < 4; ++w)
            #pragma unroll
            for (int k = 0; k < KNN; ++k) {
                const float d = dsh[w][tid][k];
                const int   i = ish[w][tid][k];
                if (d < fd[KNN-1]) {
                    fd[KNN-1] = d; fi[KNN-1] = i;
                    #pragma unroll
                    for (int p = KNN-1; p > 0; --p) {
                        if (fd[p] < fd[p-1]) {
                            float td = fd[p]; fd[p] = fd[p-1]; fd[p-1] = td;
                            int   ti = fi[p]; fi[p] = fi[p-1]; fi[p-1] = ti;
                        }
                    }
                }
            }
        const int node = (bb << 10) + n0 + tid;
        #pragma unroll
        for (int k = 0; k < KNN; ++k) idxb[(size_t)node*KNN + k] = fi[k];
    }
}

// ---------------- K4: MFMA edge pipeline ----------------
__global__ __launch_bounds__(256) void k_edge(
    const float* __restrict__ X, const int* __restrict__ idxb,
    const float* __restrict__ P,
    const unsigned short* __restrict__ WeRt,
    const unsigned short* __restrict__ We2t,
    const unsigned short* __restrict__ Wx1t,
    const float* __restrict__ be2,
    const float* __restrict__ bx1, const float* __restrict__ Wx2,
    const float* __restrict__ bx2,
    float* __restrict__ msum, float* __restrict__ wbuf)
{
    __shared__ unsigned short smem[4*NREG];          // 30208 B
    __shared__ __align__(16) float relS[4][KNN][56]; // 8064 B
    __shared__ float wred[4][KNN][4];
    __shared__ int   jsh[4][16];

    const int tid  = threadIdx.x;
    const int wv   = tid >> 6, lane = tid & 63;
    const int quad = lane >> 4, r16 = lane & 15;
    const int node0  = blockIdx.x * 4;
    const int mynode = node0 + wv;
    const int b      = node0 >> 10;
    const int chan0  = (wv*2 + 0)*16 + r16;
    const int chan1  = (wv*2 + 1)*16 + r16;

    v8bf B1[2][7];
    #pragma unroll
    for (int c2 = 0; c2 < 2; ++c2) {
        const int ct = wv*2 + c2;
        #pragma unroll
        for (int ks = 0; ks < 7; ++ks)
            B1[c2][ks] = *(const v8bf*)(WeRt + (size_t)(ct*16 + r16)*224 + ks*32 + quad*8);
    }

    if (lane < KNN) jsh[wv][lane] = idxb[(size_t)mynode*KNN + lane];
    const float xn = (lane < 42) ? X[(size_t)mynode*42 + lane] : 0.0f;

    // zero K-pad cols 196..223 of rows 0..8
    for (int z = lane; z < KNN*28; z += 64)
        smem[wv*NREG + (z/28)*RSTR + 196 + (z%28)] = 0;

    // rel -> per-wave LDS, padded [c][4]  (jsh read: same-wave in-order DS)
    #pragma unroll
    for (int e = 0; e < KNN; ++e) {
        const int j = jsh[wv][e];
        if (lane < 42)
            relS[wv][e][(lane/3)*4 + (lane%3)] = xn - X[(size_t)((b << 10) + j)*42 + lane];
    }

    int offC[3], offE[3];
    #pragma unroll
    for (int rr = 0; rr < 3; ++rr) {
        const int f = rr*64 + lane;
        offC[rr] = (f / 14) * 4;
        offE[rr] = (f % 14) * 4;
    }
    const int f3 = 192 + lane;
    const int offC3 = (f3 / 14) * 4, offE3 = (f3 % 14) * 4;

    #pragma unroll
    for (int e = 0; e < KNN; ++e) {
        const float* rb = &relS[wv][e][0];
        #pragma unroll
        for (int rr = 0; rr < 3; ++rr) {
            const float4 a  = *(const float4*)(rb + offC[rr]);
            const float4 bb = *(const float4*)(rb + offE[rr]);
            const float v = (a.x*bb.x + a.y*bb.y + a.z*bb.z) * (1.0f/14.0f);
            smem[wv*NREG + e*RSTR + rr*64 + lane] = f2bf(silu_f(v));
        }
        if (lane < 4) {
            const float4 a  = *(const float4*)(rb + offC3);
            const float4 bb = *(const float4*)(rb + offE3);
            const float v = (a.x*bb.x + a.y*bb.y + a.z*bb.z) * (1.0f/14.0f);
            smem[wv*NREG + e*RSTR + 192 + lane] = f2bf(silu_f(v));
        }
    }
    __syncthreads();

    // ---- layer 1 MFMA ----
    v4f acc1[4][2];
    #pragma unroll
    for (int n = 0; n < 4; ++n) { acc1[n][0] = (v4f){0,0,0,0}; acc1[n][1] = (v4f){0,0,0,0}; }
    #pragma unroll
    for (int n = 0; n < 4; ++n) {
        v8bf a[7];
        #pragma unroll
        for (int ks = 0; ks < 7; ++ks)
            a[ks] = *(const v8bf*)(smem + n*NREG + r16*RSTR + ks*32 + quad*8);
        #pragma unroll
        for (int ks = 0; ks < 7; ++ks) {
            acc1[n][0] = __builtin_amdgcn_mfma_f32_16x16x32_bf16(a[ks], B1[0][ks], acc1[n][0], 0, 0, 0);
            acc1[n][1] = __builtin_amdgcn_mfma_f32_16x16x32_bf16(a[ks], B1[1][ks], acc1[n][1], 0, 0, 0);
        }
    }
    __syncthreads();

    // ---- epilogue 1: + Pn + Pj, silu -> sil (overlay stride SSTR) ----
    {
        float pn[4][2], pj[4][2][4];
        #pragma unroll
        for (int n = 0; n < 4; ++n) {
            pn[n][0] = P[(size_t)(node0 + n)*256 + chan0];
            pn[n][1] = P[(size_t)(node0 + n)*256 + chan1];
            #pragma unroll
            for (int rr = 0; rr < 4; ++rr) {
                const int e = quad*4 + rr;
                const int jq = jsh[n][(e < KNN) ? e : (KNN-1)];
                const size_t jrow = (size_t)((b << 10) + jq)*256 + 128;
                pj[n][0][rr] = P[jrow + chan0];
                pj[n][1][rr] = P[jrow + chan1];
            }
        }
        #pragma unroll
        for (int n = 0; n < 4; ++n)
            #pragma unroll
            for (int rr = 0; rr < 4; ++rr) {
                const int row = quad*4 + rr;
                smem[n*NREG + row*SSTR + chan0] = f2bf(silu_f(acc1[n][0][rr] + pn[n][0] + pj[n][0][rr]));
                smem[n*NREG + row*SSTR + chan1] = f2bf(silu_f(acc1[n][1][rr] + pn[n][1] + pj[n][1][rr]));
            }
    }
    v8bf B2[2][4];
    #pragma unroll
    for (int c2 = 0; c2 < 2; ++c2) {
        const int ct = wv*2 + c2;
        #pragma unroll
        for (int ks = 0; ks < 4; ++ks)
            B2[c2][ks] = *(const v8bf*)(We2t + (size_t)(ct*16 + r16)*128 + ks*32 + quad*8);
    }
    __syncthreads();

    // ---- layer 2 MFMA ----
    v4f acc2[4][2];
    #pragma unroll
    for (int n = 0; n < 4; ++n) { acc2[n][0] = (v4f){0,0,0,0}; acc2[n][1] = (v4f){0,0,0,0}; }
    #pragma unroll
    for (int n = 0; n < 4; ++n) {
        v8bf a[4];
        #pragma unroll
        for (int ks = 0; ks < 4; ++ks)
            a[ks] = *(const v8bf*)(smem + n*NREG + r16*SSTR + ks*32 + quad*8);
        #pragma unroll
        for (int ks = 0; ks < 4; ++ks) {
            acc2[n][0] = __builtin_amdgcn_mfma_f32_16x16x32_bf16(a[ks], B2[0][ks], acc2[n][0], 0, 0, 0);
            acc2[n][1] = __builtin_amdgcn_mfma_f32_16x16x32_bf16(a[ks], B2[1][ks], acc2[n][1], 0, 0, 0);
        }
    }
    __syncthreads();

    // ---- epilogue 2: msum + silu(m) -> sil ----
    {
        const float be2c0 = be2[chan0], be2c1 = be2[chan1];
        #pragma unroll
        for (int n = 0; n < 4; ++n) {
            float m0[4], m1[4];
            float s0 = 0.0f, s1 = 0.0f;
            #pragma unroll
            for (int rr = 0; rr < 4; ++rr) {
                m0[rr] = acc2[n][0][rr] + be2c0;
                m1[rr] = acc2[n][1][rr] + be2c1;
                if (quad*4 + rr < KNN) { s0 += m0[rr]; s1 += m1[rr]; }
            }
            s0 += __shfl_xor(s0, 16); s0 += __shfl_xor(s0, 32);
            s1 += __shfl_xor(s1, 16); s1 += __shfl_xor(s1, 32);
            if (quad == 0) {
                msum[(size_t)(node0 + n)*128 + chan0] = s0;
                msum[(size_t)(node0 + n)*128 + chan1] = s1;
            }
            #pragma unroll
            for (int rr = 0; rr < 4; ++rr) {
                const int row = quad*4 + rr;
                smem[n*NREG + row*SSTR + chan0] = f2bf(silu_f(m0[rr]));
                smem[n*NREG + row*SSTR + chan1] = f2bf(silu_f(m1[rr]));
            }
        }
    }
    v8bf B3[2][4];
    #pragma unroll
    for (int c2 = 0; c2 < 2; ++c2) {
        const int ct = wv*2 + c2;
        #pragma unroll
        for (int ks = 0; ks < 4; ++ks)
            B3[c2][ks] = *(const v8bf*)(Wx1t + (size_t)(ct*16 + r16)*128 + ks*32 + quad*8);
    }
    __syncthreads();

    // ---- layer 3 MFMA ----
    v4f acc3[4][2];
    #pragma unroll
    for (int n = 0; n < 4; ++n) { acc3[n][0] = (v4f){0,0,0,0}; acc3[n][1] = (v4f){0,0,0,0}; }
    #pragma unroll
    for (int n = 0; n < 4; ++n) {
        v8bf a[4];
        #pragma unroll
        for (int ks = 0; ks < 4; ++ks)
            a[ks] = *(const v8bf*)(smem + n*NREG + r16*SSTR + ks*32 + quad*8);
        #pragma unroll
        for (int ks = 0; ks < 4; ++ks) {
            acc3[n][0] = __builtin_amdgcn_mfma_f32_16x16x32_bf16(a[ks], B3[0][ks], acc3[n][0], 0, 0, 0);
            acc3[n][1] = __builtin_amdgcn_mfma_f32_16x16x32_bf16(a[ks], B3[1][ks], acc3[n][1], 0, 0, 0);
        }
    }

    // ---- epilogue 3 ----
    {
        const float bxc0 = bx1[chan0], bxc1 = bx1[chan1];
        const float wxc0 = Wx2[chan0], wxc1 = Wx2[chan1];
        #pragma unroll
        for (int n = 0; n < 4; ++n) {
            float pr[4];
            #pragma unroll
            for (int rr = 0; rr < 4; ++rr)
                pr[rr] = silu_f(acc3[n][0][rr] + bxc0) * wxc0
                       + silu_f(acc3[n][1][rr] + bxc1) * wxc1;
            #pragma unroll
            for (int rr = 0; rr < 4; ++rr) {
                pr[rr] += __shfl_xor(pr[rr], 1);
                pr[rr] += __shfl_xor(pr[rr], 2);
                pr[rr] += __shfl_xor(pr[rr], 4);
                pr[rr] += __shfl_xor(pr[rr], 8);
            }
            if (r16 == 0) {
                #pragma unroll
                for (int rr = 0; rr < 4; ++rr) {
                    const int e = quad*4 + rr;
                    if (e < KNN) wred[n][e][wv] = pr[rr];
                }
            }
        }
    }
    __syncthreads();
    if (tid < 4*KNN) {
        const int n = tid / KNN, e = tid % KNN;
        wbuf[(size_t)(node0 + n)*KNN + e] =
            wred[n][e][0] + wred[n][e][1] + wred[n][e][2] + wred[n][e][3] + bx2[0];
    }
}

// ---------------- K5: fused node pipeline, all-MFMA ----------------
// Block = 16 nodes = one 16-row MFMA tile (all rows real). 4 waves ct-split.
__global__ __launch_bounds__(256) void k_nodeF(
    const float* __restrict__ X, const float* __restrict__ Hh,
    const float* __restrict__ msum, const int* __restrict__ idxb,
    const float* __restrict__ wbuf,
    const unsigned short* __restrict__ Wh1t, const float* __restrict__ bh1,
    const unsigned short* __restrict__ Wh2t, const float* __restrict__ bh2,
    const unsigned short* __restrict__ Wd1t, const float* __restrict__ bd1,
    const int* __restrict__ S, const float* __restrict__ emb,
    const unsigned short* __restrict__ Wp1t, const float* __restrict__ bp1,
    const unsigned short* __restrict__ Wr1t, const float* __restrict__ br1,
    const float* __restrict__ Wr2, const float* __restrict__ br2,
    float* __restrict__ Hn, float* __restrict__ AB,
    float* __restrict__ outL, float* __restrict__ outX)
{
    __shared__ __align__(16) unsigned short A0[16*268];   // 8576 B; A4 fp32 overlay
    __shared__ __align__(16) unsigned short A1[16*140];
    __shared__ __align__(16) unsigned short A2[16*140];
    __shared__ __align__(16) unsigned short A3[16*140];
    __shared__ int sInt[16];
    float* A4 = (float*)A0;   // stride 134 fp32, 16*134*4 = 8576 B

    const int tid  = threadIdx.x;
    const int wv   = tid >> 6, lane = tid & 63;
    const int quad = lane >> 4, r16 = lane & 15;
    const int base = blockIdx.x * 16;

    if (tid < 16) sInt[tid] = S[base + tid];
    for (int r = 0; r < 16; ++r) {
        const int node = base + r;
        const float v = (tid < 128) ? Hh[(size_t)node*128 + tid]
                                    : msum[(size_t)node*128 + (tid - 128)];
        A0[r*268 + tid] = f2bf(silu_f(v));
    }
    __syncthreads();

    // ---- MM1: A0(16x256) @ Wh1t -> silu -> A1 ----
    {
        v8bf a[8];
        #pragma unroll
        for (int ks = 0; ks < 8; ++ks)
            a[ks] = *(const v8bf*)(A0 + r16*268 + ks*32 + quad*8);
        #pragma unroll
        for (int c2 = 0; c2 < 2; ++c2) {
            const int ch = (wv*2 + c2)*16 + r16;
            v4f acc = (v4f){0,0,0,0};
            #pragma unroll
            for (int ks = 0; ks < 8; ++ks) {
                const v8bf bb = *(const v8bf*)(Wh1t + (size_t)ch*256 + ks*32 + quad*8);
                acc = __builtin_amdgcn_mfma_f32_16x16x32_bf16(a[ks], bb, acc, 0, 0, 0);
            }
            const float bc = bh1[ch];
            #pragma unroll
            for (int rr = 0; rr < 4; ++rr)
                A1[(quad*4 + rr)*140 + ch] = f2bf(silu_f(acc[rr] + bc));
        }
    }
    __syncthreads();

    // ---- MM2: A1 @ Wh2t -> Hn (global) + silu -> A2 ----
    {
        v8bf a[4];
        #pragma unroll
        for (int ks = 0; ks < 4; ++ks)
            a[ks] = *(const v8bf*)(A1 + r16*140 + ks*32 + quad*8);
        #pragma unroll
        for (int c2 = 0; c2 < 2; ++c2) {
            const int ch = (wv*2 + c2)*16 + r16;
            v4f acc = (v4f){0,0,0,0};
            #pragma unroll
            for (int ks = 0; ks < 4; ++ks) {
                const v8bf bb = *(const v8bf*)(Wh2t + (size_t)ch*128 + ks*32 + quad*8);
                acc = __builtin_amdgcn_mfma_f32_16x16x32_bf16(a[ks], bb, acc, 0, 0, 0);
            }
            const float bc = bh2[ch];
            #pragma unroll
            for (int rr = 0; rr < 4; ++rr) {
                const int row = quad*4 + rr;
                const int node = base + row;
                const float hn = Hh[(size_t)node*128 + ch] + acc[rr] + bc;
                Hn[(size_t)node*128 + ch] = hn;
                A2[row*140 + ch] = f2bf(silu_f(hn));
            }
        }
    }
    __syncthreads();

    // ---- MM3 (AB = A2 @ Wd1t, N=256) + MM4 (gate path) both read A2 ----
    {
        v8bf a[4];
        #pragma unroll
        for (int ks = 0; ks < 4; ++ks)
            a[ks] = *(const v8bf*)(A2 + r16*140 + ks*32 + quad*8);

        #pragma unroll
        for (int cg = 0; cg < 2; ++cg) {
            #pragma unroll
            for (int c2 = 0; c2 < 2; ++c2) {
                const int ch = (wv*4 + cg*2 + c2)*16 + r16;    // 0..255
                v4f acc = (v4f){0,0,0,0};
                #pragma unroll
                for (int ks = 0; ks < 4; ++ks) {
                    const v8bf bb = *(const v8bf*)(Wd1t + (size_t)ch*128 + ks*32 + quad*8);
                    acc = __builtin_amdgcn_mfma_f32_16x16x32_bf16(a[ks], bb, acc, 0, 0, 0);
                }
                const float fb = (ch < 128) ? bd1[ch] : 0.0f;
                #pragma unroll
                for (int rr = 0; rr < 4; ++rr)
                    AB[(size_t)(base + quad*4 + rr)*256 + ch] = acc[rr] + fb;
            }
        }

        #pragma unroll
        for (int c2 = 0; c2 < 2; ++c2) {
            const int ch = (wv*2 + c2)*16 + r16;
            v4f acc = (v4f){0,0,0,0};
            #pragma unroll
            for (int ks = 0; ks < 4; ++ks) {
                const v8bf bb = *(const v8bf*)(Wp1t + (size_t)ch*128 + ks*32 + quad*8);
                acc = __builtin_amdgcn_mfma_f32_16x16x32_bf16(a[ks], bb, acc, 0, 0, 0);
            }
            const float bc = bp1[ch];
            #pragma unroll
            for (int rr = 0; rr < 4; ++rr) {
                const int row = quad*4 + rr;
                const float g = 1.0f / (1.0f + __expf(-(acc[rr] + bc)));
                const float x = emb[sInt[row]*128 + ch] * g;
                A3[row*140 + ch] = f2bf(silu_f(x));
            }
        }
    }
    __syncthreads();

    // ---- MM5: A3 @ Wr1t -> silu -> A4 (fp32, overlays A0) ----
    {
        v8bf a[4];
        #pragma unroll
        for (int ks = 0; ks < 4; ++ks)
            a[ks] = *(const v8bf*)(A3 + r16*140 + ks*32 + quad*8);
        #pragma unroll
        for (int c2 = 0; c2 < 2; ++c2) {
            const int ch = (wv*2 + c2)*16 + r16;
            v4f acc = (v4f){0,0,0,0};
            #pragma unroll
            for (int ks = 0; ks < 4; ++ks) {
                const v8bf bb = *(const v8bf*)(Wr1t + (size_t)ch*128 + ks*32 + quad*8);
                acc = __builtin_amdgcn_mfma_f32_16x16x32_bf16(a[ks], bb, acc, 0, 0, 0);
            }
            const float bc = br1[ch];
            #pragma unroll
            for (int rr = 0; rr < 4; ++rr)
                A4[(quad*4 + rr)*134 + ch] = silu_f(acc[rr] + bc);
        }
    }
    __syncthreads();

    // logits tail (fp32)
    for (int o = tid; o < 16*NCLS; o += 256) {
        const int r = o / NCLS, j = o % NCLS;
        float s = 0.0f;
        for (int i = 0; i < 128; ++i) s += A4[r*134 + i] * Wr2[i*NCLS + j];
        outL[(size_t)(base + r)*NCLS + j] = s + br2[j];
    }

    // X_out tail
    for (int o = tid; o < 16*CC*3; o += 256) {
        const int r = o / (CC*3), q = o % (CC*3);
        const int node = base + r;
        const int bq = node >> 10;
        const int cq = q / 3, dc = q % 3;
        const float xv = X[((size_t)node*CC + cq)*3 + dc];
        float a = 0.0f;
        for (int k = 0; k < KNN; ++k) {
            const int j = idxb[(size_t)node*KNN + k];
            const float xj = X[(((size_t)(bq << 10) + j)*CC + cq)*3 + dc];
            a += (xv - xj) * wbuf[(size_t)node*KNN + k];
        }
        outX[(size_t)node*CC*3 + q] = xv + a / 9.0f;
    }
}

// ---------------- K6: pd from precomputed A,B ----------------
__global__ __launch_bounds__(128) void k_pd2(
    const float* __restrict__ AB, const int* __restrict__ idxb,
    const float* __restrict__ Wd2, const float* __restrict__ bd2,
    float* __restrict__ outPd)
{
    const int tid  = threadIdx.x;
    const int lane = tid & 63, wv = tid >> 6;
    const int node = blockIdx.x * 2 + wv;
    const int b    = node >> 10;
    const int c0   = lane, c1 = lane + 64;

    int jv = 0;
    if (lane < KNN) jv = idxb[(size_t)node*KNN + lane];

    const float An0 = AB[(size_t)node*256 + c0];
    const float An1 = AB[(size_t)node*256 + c1];
    const float Bn0 = AB[(size_t)node*256 + 128 + c0];
    const float Bn1 = AB[(size_t)node*256 + 128 + c1];
    const float w0  = Wd2[c0], w1 = Wd2[c1];
    const float b2  = 2.0f * bd2[0];

    float Aj0[KNN], Aj1[KNN], Bj0[KNN], Bj1[KNN];
    #pragma unroll
    for (int e = 0; e < KNN; ++e) {
        const size_t jn = (size_t)((b << 10) + __shfl(jv, e)) * 256;
        Aj0[e] = AB[jn + c0];       Aj1[e] = AB[jn + c1];
        Bj0[e] = AB[jn + 128 + c0]; Bj1[e] = AB[jn + 128 + c1];
    }
    #pragma unroll
    for (int e = 0; e < KNN; ++e) {
        float p = (silu_f(An0 + Bj0[e]) + silu_f(Aj0[e] + Bn0)) * w0
                + (silu_f(An1 + Bj1[e]) + silu_f(Aj1[e] + Bn1)) * w1;
        #pragma unroll
        for (int off = 32; off; off >>= 1) p += __shfl_xor(p, off, 64);
        if (lane == 0) outPd[(size_t)node*KNN + e] = p + b2;
    }
}

extern "C" void kernel_launch(void* const* d_in, const int* in_sizes, int n_in,
                              void* d_out, int out_size, void* d_ws, size_t ws_size,
                              hipStream_t stream)
{
    const float* X   = (const float*)d_in[0];
    const int*   S   = (const int*)  d_in[1];
    const float* t   = (const float*)d_in[2];
    const float* emb = (const float*)d_in[3];
    const float* Wt1 = (const float*)d_in[4];
    const float* bt1 = (const float*)d_in[5];
    const float* Wt2 = (const float*)d_in[6];
    const float* bt2 = (const float*)d_in[7];
    const float* We1 = (const float*)d_in[8];
    const float* be1 = (const float*)d_in[9];
    const float* We2 = (const float*)d_in[10];
    const float* be2 = (const float*)d_in[11];
    const float* Wx1 = (const float*)d_in[12];
    const float* bx1 = (const float*)d_in[13];
    const float* Wx2 = (const float*)d_in[14];
    const float* bx2 = (const float*)d_in[15];
    const float* Wh1 = (const float*)d_in[16];
    const float* bh1 = (const float*)d_in[17];
    const float* Wh2 = (const float*)d_in[18];
    const float* bh2 = (const float*)d_in[19];
    const float* Wd1 = (const float*)d_in[20];
    const float* bd1 = (const float*)d_in[21];
    const float* Wd2 = (const float*)d_in[22];
    const float* bd2 = (const float*)d_in[23];
    const float* Wp1 = (const float*)d_in[24];
    const float* bp1 = (const float*)d_in[25];
    const float* Wr1 = (const float*)d_in[26];
    const float* br1 = (const float*)d_in[27];
    const float* Wr2 = (const float*)d_in[28];
    const float* br2 = (const float*)d_in[29];

    float* out   = (float*)d_out;
    float* outL  = out;
    float* outX  = out + (size_t)BN*NCLS;
    float* outPd = outX + (size_t)BN*CC*3;

    unsigned short* WeRt = (unsigned short*)d_ws;   // 128*224
    unsigned short* We2t = WeRt + 128*224;          // 16384
    unsigned short* Wx1t = We2t + 16384;            // 16384
    unsigned short* Wh1t = Wx1t + 16384;            // 32768
    unsigned short* Wh2t = Wh1t + 32768;            // 16384
    unsigned short* Wd1t = Wh2t + 16384;            // 32768
    unsigned short* Wp1t = Wd1t + 32768;            // 16384
    unsigned short* Wr1t = Wp1t + 16384;            // 16384
    float* Hh   = (float*)(Wr1t + 16384);
    float* msum = Hh   + (size_t)BN*EDIM;
    float* Hn   = msum + (size_t)BN*HDIM;
    float* wbuf = Hn   + (size_t)BN*EDIM;
    float* P    = wbuf + (size_t)BN*KNN;            // BN*256, reused as AB
    int*   idxb = (int*)(P + (size_t)BN*256);

    k_prep  <<<688,    256, 0, stream>>>(We1, We2, Wx1, Wh1, Wh2, Wd1, Wp1, Wr1,
                                         WeRt, We2t, Wx1t, Wh1t, Wh2t, Wd1t, Wp1t, Wr1t);
    k_hhP   <<<BN/16,  256, 0, stream>>>(t, S, emb, Wt1, bt1, Wt2, bt2, We1, be1, Hh, P);
    k_knn   <<<BN/64,  256, 0, stream>>>(X, idxb);
    k_edge  <<<BN/4,   256, 0, stream>>>(X, idxb, P, WeRt, We2t, Wx1t,
                                         be2, bx1, Wx2, bx2, msum, wbuf);
    k_nodeF <<<BN/16,  256, 0, stream>>>(X, Hh, msum, idxb, wbuf,
                                         Wh1t, bh1, Wh2t, bh2, Wd1t, bd1,
                                         S, emb, Wp1t, bp1, Wr1t, br1, Wr2, br2,
                                         Hn, P, outL, outX);
    k_pd2   <<<BN/2,   128, 0, stream>>>(P, idxb, Wd2, bd2, outPd);
}

// Round 7
// 574.722 us; speedup vs baseline: 5.0094x; 1.0996x over previous
//
#include <hip/hip_runtime.h>

#define BATCH 32
#define NPT   1024
#define CC    14
#define KNN   9
#define EDIM  128
#define HDIM  128
#define NCLS  25
#define BN    (BATCH*NPT)

#define RSTR  236
#define NREG  3776
#define SSTR  140

typedef float  v4f __attribute__((ext_vector_type(4)));
typedef __bf16 v8bf __attribute__((ext_vector_type(8)));

__device__ __forceinline__ float silu_f(float x) { return x / (1.0f + __expf(-x)); }

// RNE (for weights, once)
__device__ __forceinline__ unsigned short f2bf_rne(float f) {
    union { float f; unsigned u; } v; v.f = f;
    unsigned r = v.u + 0x7fffu + ((v.u >> 16) & 1u);
    return (unsigned short)(r >> 16);
}
// RNA (cheap, for activations)
__device__ __forceinline__ unsigned short f2bf(float f) {
    union { float f; unsigned u; } v; v.f = f;
    return (unsigned short)((v.u + 0x8000u) >> 16);
}

// ---------------- K0: weight prep (transpose + bf16) ----------------
__global__ __launch_bounds__(256) void k_prep(
    const float* __restrict__ We1, const float* __restrict__ We2,
    const float* __restrict__ Wx1, const float* __restrict__ Wh1,
    const float* __restrict__ Wh2, const float* __restrict__ Wd1,
    const float* __restrict__ Wp1, const float* __restrict__ Wr1,
    const float* __restrict__ Wt1, const float* __restrict__ Wt2,
    unsigned short* __restrict__ WeRt, unsigned short* __restrict__ We2t,
    unsigned short* __restrict__ Wx1t, unsigned short* __restrict__ Wh1t,
    unsigned short* __restrict__ Wh2t, unsigned short* __restrict__ Wd1t,
    unsigned short* __restrict__ Wp1t, unsigned short* __restrict__ Wr1t,
    unsigned short* __restrict__ Wt1t, unsigned short* __restrict__ Wt2t,
    unsigned short* __restrict__ We1Ft)
{
    int i = blockIdx.x * 256 + threadIdx.x;
    if (i < 128*224) {
        const int chan = i / 224, k = i % 224;
        WeRt[i] = (k < 196) ? f2bf_rne(We1[(size_t)(256 + k)*128 + chan]) : (unsigned short)0;
        return;
    }
    i -= 128*224;
    if (i < 16384) { We2t[i] = f2bf_rne(We2[(size_t)(i % 128)*128 + i/128]); return; }
    i -= 16384;
    if (i < 16384) { Wx1t[i] = f2bf_rne(Wx1[(size_t)(i % 128)*128 + i/128]); return; }
    i -= 16384;
    if (i < 32768) { const int c = i/256, k = i%256; Wh1t[i] = f2bf_rne(Wh1[(size_t)k*128 + c]); return; }
    i -= 32768;
    if (i < 16384) { Wh2t[i] = f2bf_rne(Wh2[(size_t)(i % 128)*128 + i/128]); return; }
    i -= 16384;
    if (i < 32768) {
        const int t = i/128, k = i%128;
        Wd1t[i] = f2bf_rne((t < 128) ? Wd1[(size_t)k*128 + t] : Wd1[(size_t)(128 + k)*128 + (t - 128)]);
        return;
    }
    i -= 32768;
    if (i < 16384) { Wp1t[i] = f2bf_rne(Wp1[(size_t)(i % 128)*128 + i/128]); return; }
    i -= 16384;
    if (i < 16384) { Wr1t[i] = f2bf_rne(Wr1[(size_t)(i % 128)*128 + i/128]); return; }
    i -= 16384;
    if (i < 16384) { Wt1t[i] = f2bf_rne(Wt1[(size_t)(i % 128)*128 + i/128]); return; }
    i -= 16384;
    if (i < 16384) { Wt2t[i] = f2bf_rne(Wt2[(size_t)(i % 128)*128 + i/128]); return; }
    i -= 16384;
    if (i < 32768) {
        const int t = i/128, k = i%128;
        We1Ft[i] = f2bf_rne((t < 128) ? We1[(size_t)k*128 + t] : We1[(size_t)(128 + k)*128 + (t - 128)]);
    }
}

// ---------------- K1: fused Hh + P, all-MFMA ----------------
// Block = 16 nodes. A-tiles ping-pong through padded LDS (stride 140).
__global__ __launch_bounds__(256) void k_hhP(
    const float* __restrict__ t, const int* __restrict__ S,
    const float* __restrict__ emb,
    const unsigned short* __restrict__ Wt1t, const float* __restrict__ bt1,
    const unsigned short* __restrict__ Wt2t, const float* __restrict__ bt2,
    const unsigned short* __restrict__ We1Ft, const float* __restrict__ be1,
    float* __restrict__ Hh, float* __restrict__ P)
{
    __shared__ __align__(16) unsigned short A0[16*140];
    __shared__ __align__(16) unsigned short A1[16*140];
    __shared__ __align__(16) unsigned short A2[16*140];
    __shared__ int sInt[16];

    const int tid  = threadIdx.x;
    const int wv   = tid >> 6, lane = tid & 63;
    const int quad = lane >> 4, r16 = lane & 15;
    const int col  = tid & 127, rh = tid >> 7;
    const int base = blockIdx.x * 16;

    if (tid < 16) sInt[tid] = S[base + tid];

    const float step  = 1.0f / 127.0f;
    const float coeff = -0.5f / (step * step);
    const float off   = step * (float)col;
    #pragma unroll
    for (int rr = 0; rr < 8; ++rr) {
        const int r = rh*8 + rr;
        const float d = t[base + r] - off + 1e-6f;
        A0[r*140 + col] = f2bf(__expf(coeff * d * d));
    }
    __syncthreads();

    // MM_t1: g @ Wt1t -> relu -> A1
    {
        v8bf a[4];
        #pragma unroll
        for (int ks = 0; ks < 4; ++ks)
            a[ks] = *(const v8bf*)(A0 + r16*140 + ks*32 + quad*8);
        #pragma unroll
        for (int c2 = 0; c2 < 2; ++c2) {
            const int ch = (wv*2 + c2)*16 + r16;
            v4f acc = (v4f){0,0,0,0};
            #pragma unroll
            for (int ks = 0; ks < 4; ++ks) {
                const v8bf bb = *(const v8bf*)(Wt1t + (size_t)ch*128 + ks*32 + quad*8);
                acc = __builtin_amdgcn_mfma_f32_16x16x32_bf16(a[ks], bb, acc, 0, 0, 0);
            }
            const float bc = bt1[ch];
            #pragma unroll
            for (int rr = 0; rr < 4; ++rr)
                A1[(quad*4 + rr)*140 + ch] = f2bf(fmaxf(acc[rr] + bc, 0.0f));
        }
    }
    __syncthreads();

    // MM_t2: A1 @ Wt2t -> + emb[S] + bt2 -> Hh (fp32) + silu -> A2
    {
        v8bf a[4];
        #pragma unroll
        for (int ks = 0; ks < 4; ++ks)
            a[ks] = *(const v8bf*)(A1 + r16*140 + ks*32 + quad*8);
        #pragma unroll
        for (int c2 = 0; c2 < 2; ++c2) {
            const int ch = (wv*2 + c2)*16 + r16;
            v4f acc = (v4f){0,0,0,0};
            #pragma unroll
            for (int ks = 0; ks < 4; ++ks) {
                const v8bf bb = *(const v8bf*)(Wt2t + (size_t)ch*128 + ks*32 + quad*8);
                acc = __builtin_amdgcn_mfma_f32_16x16x32_bf16(a[ks], bb, acc, 0, 0, 0);
            }
            const float bc = bt2[ch];
            #pragma unroll
            for (int rr = 0; rr < 4; ++rr) {
                const int row = quad*4 + rr;
                const int node = base + row;
                const float hh = emb[sInt[row]*128 + ch] + acc[rr] + bc;
                Hh[(size_t)node*128 + ch] = hh;
                A2[row*140 + ch] = f2bf(silu_f(hh));
            }
        }
    }
    __syncthreads();

    // MM_P: A2 @ We1Ft (256 cols) + be1(A half) -> P
    {
        v8bf a[4];
        #pragma unroll
        for (int ks = 0; ks < 4; ++ks)
            a[ks] = *(const v8bf*)(A2 + r16*140 + ks*32 + quad*8);
        #pragma unroll
        for (int c2 = 0; c2 < 4; ++c2) {
            const int ch = (wv*4 + c2)*16 + r16;    // 0..255
            v4f acc = (v4f){0,0,0,0};
            #pragma unroll
            for (int ks = 0; ks < 4; ++ks) {
                const v8bf bb = *(const v8bf*)(We1Ft + (size_t)ch*128 + ks*32 + quad*8);
                acc = __builtin_amdgcn_mfma_f32_16x16x32_bf16(a[ks], bb, acc, 0, 0, 0);
            }
            const float fb = (ch < 128) ? be1[ch] : 0.0f;
            #pragma unroll
            for (int rr = 0; rr < 4; ++rr)
                P[(size_t)(base + quad*4 + rr)*256 + ch] = acc[rr] + fb;
        }
    }
}

// ---------------- K2: KNN top-9, 4 waves split the scan ----------------
__global__ __launch_bounds__(256) void k_knn(
    const float* __restrict__ X, int* __restrict__ idxb)
{
    __shared__ __align__(16) float4 Cc[NPT];
    __shared__ float dsh[4][64][KNN];
    __shared__ int   ish[4][64][KNN];

    const int tid = threadIdx.x, lane = tid & 63, wv = tid >> 6;
    const int bb = blockIdx.x >> 4;
    const int n0 = (blockIdx.x & 15) << 6;
    const float* Xb = X + (size_t)bb * NPT * 42;

    for (int i = tid; i < NPT; i += 256) {
        const float* p = Xb + (size_t)i*42 + 3;
        Cc[i] = make_float4(p[0], p[1], p[2], 0.0f);
    }
    __syncthreads();

    const int n = n0 + lane;
    const float4 c = Cc[n];

    float dist[KNN]; int ind[KNN];
    #pragma unroll
    for (int k = 0; k < KNN; ++k) { dist[k] = 3.0e38f; ind[k] = -1; }

    const int j0 = wv * 256;
    for (int jj = 0; jj < 256; ++jj) {
        const int j = j0 + jj;
        const float4 q = Cc[j];
        const float dx = __fsub_rn(c.x, q.x);
        const float dy = __fsub_rn(c.y, q.y);
        const float dz = __fsub_rn(c.z, q.z);
        float d = __fadd_rn(__fadd_rn(__fmul_rn(dx,dx), __fmul_rn(dy,dy)), __fmul_rn(dz,dz));
        if (j == n) d = __fadd_rn(d, 1e10f);
        if (d < dist[KNN-1]) {
            dist[KNN-1] = d; ind[KNN-1] = j;
            #pragma unroll
            for (int p = KNN-1; p > 0; --p) {
                if (dist[p] < dist[p-1]) {
                    float td = dist[p]; dist[p] = dist[p-1]; dist[p-1] = td;
                    int   ti = ind[p];  ind[p]  = ind[p-1];  ind[p-1]  = ti;
                }
            }
        }
    }
    #pragma unroll
    for (int k = 0; k < KNN; ++k) { dsh[wv][lane][k] = dist[k]; ish[wv][lane][k] = ind[k]; }
    __syncthreads();

    if (tid < 64) {
        float fd[KNN]; int fi[KNN];
        #pragma unroll
        for (int k = 0; k < KNN; ++k) { fd[k] = 3.0e38f; fi[k] = -1; }
        for (int w = 0; w < 4; ++w)
            #pragma unroll
            for (int k = 0; k < KNN; ++k) {
                const float d = dsh[w][tid][k];
                const int   i = ish[w][tid][k];
                if (d < fd[KNN-1]) {
                    fd[KNN-1] = d; fi[KNN-1] = i;
                    #pragma unroll
                    for (int p = KNN-1; p > 0; --p) {
                        if (fd[p] < fd[p-1]) {
                            float td = fd[p]; fd[p] = fd[p-1]; fd[p-1] = td;
                            int   ti = fi[p]; fi[p] = fi[p-1]; fi[p-1] = ti;
                        }
                    }
                }
            }
        const int node = (bb << 10) + n0 + tid;
        #pragma unroll
        for (int k = 0; k < KNN; ++k) idxb[(size_t)node*KNN + k] = fi[k];
    }
}

// ---------------- K4: MFMA edge pipeline ----------------
__global__ __launch_bounds__(256) void k_edge(
    const float* __restrict__ X, const int* __restrict__ idxb,
    const float* __restrict__ P,
    const unsigned short* __restrict__ WeRt,
    const unsigned short* __restrict__ We2t,
    const unsigned short* __restrict__ Wx1t,
    const float* __restrict__ be2,
    const float* __restrict__ bx1, const float* __restrict__ Wx2,
    const float* __restrict__ bx2,
    float* __restrict__ msum, float* __restrict__ wbuf)
{
    __shared__ unsigned short smem[4*NREG];
    __shared__ __align__(16) float relS[4][KNN][56];
    __shared__ float wred[4][KNN][4];
    __shared__ int   jsh[4][16];

    const int tid  = threadIdx.x;
    const int wv   = tid >> 6, lane = tid & 63;
    const int quad = lane >> 4, r16 = lane & 15;
    const int node0  = blockIdx.x * 4;
    const int mynode = node0 + wv;
    const int b      = node0 >> 10;
    const int chan0  = (wv*2 + 0)*16 + r16;
    const int chan1  = (wv*2 + 1)*16 + r16;

    v8bf B1[2][7];
    #pragma unroll
    for (int c2 = 0; c2 < 2; ++c2) {
        const int ct = wv*2 + c2;
        #pragma unroll
        for (int ks = 0; ks < 7; ++ks)
            B1[c2][ks] = *(const v8bf*)(WeRt + (size_t)(ct*16 + r16)*224 + ks*32 + quad*8);
    }

    if (lane < KNN) jsh[wv][lane] = idxb[(size_t)mynode*KNN + lane];
    const float xn = (lane < 42) ? X[(size_t)mynode*42 + lane] : 0.0f;

    for (int z = lane; z < KNN*28; z += 64)
        smem[wv*NREG + (z/28)*RSTR + 196 + (z%28)] = 0;

    #pragma unroll
    for (int e = 0; e < KNN; ++e) {
        const int j = jsh[wv][e];
        if (lane < 42)
            relS[wv][e][(lane/3)*4 + (lane%3)] = xn - X[(size_t)((b << 10) + j)*42 + lane];
    }

    int offC[3], offE[3];
    #pragma unroll
    for (int rr = 0; rr < 3; ++rr) {
        const int f = rr*64 + lane;
        offC[rr] = (f / 14) * 4;
        offE[rr] = (f % 14) * 4;
    }
    const int f3 = 192 + lane;
    const int offC3 = (f3 / 14) * 4, offE3 = (f3 % 14) * 4;

    #pragma unroll
    for (int e = 0; e < KNN; ++e) {
        const float* rb = &relS[wv][e][0];
        #pragma unroll
        for (int rr = 0; rr < 3; ++rr) {
            const float4 a  = *(const float4*)(rb + offC[rr]);
            const float4 bb = *(const float4*)(rb + offE[rr]);
            const float v = (a.x*bb.x + a.y*bb.y + a.z*bb.z) * (1.0f/14.0f);
            smem[wv*NREG + e*RSTR + rr*64 + lane] = f2bf(silu_f(v));
        }
        if (lane < 4) {
            const float4 a  = *(const float4*)(rb + offC3);
            const float4 bb = *(const float4*)(rb + offE3);
            const float v = (a.x*bb.x + a.y*bb.y + a.z*bb.z) * (1.0f/14.0f);
            smem[wv*NREG + e*RSTR + 192 + lane] = f2bf(silu_f(v));
        }
    }
    __syncthreads();

    // ---- layer 1 MFMA ----
    v4f acc1[4][2];
    #pragma unroll
    for (int n = 0; n < 4; ++n) { acc1[n][0] = (v4f){0,0,0,0}; acc1[n][1] = (v4f){0,0,0,0}; }
    #pragma unroll
    for (int n = 0; n < 4; ++n) {
        v8bf a[7];
        #pragma unroll
        for (int ks = 0; ks < 7; ++ks)
            a[ks] = *(const v8bf*)(smem + n*NREG + r16*RSTR + ks*32 + quad*8);
        #pragma unroll
        for (int ks = 0; ks < 7; ++ks) {
            acc1[n][0] = __builtin_amdgcn_mfma_f32_16x16x32_bf16(a[ks], B1[0][ks], acc1[n][0], 0, 0, 0);
            acc1[n][1] = __builtin_amdgcn_mfma_f32_16x16x32_bf16(a[ks], B1[1][ks], acc1[n][1], 0, 0, 0);
        }
    }
    __syncthreads();

    // ---- epilogue 1 ----
    {
        float pn[4][2], pj[4][2][4];
        #pragma unroll
        for (int n = 0; n < 4; ++n) {
            pn[n][0] = P[(size_t)(node0 + n)*256 + chan0];
            pn[n][1] = P[(size_t)(node0 + n)*256 + chan1];
            #pragma unroll
            for (int rr = 0; rr < 4; ++rr) {
                const int e = quad*4 + rr;
                const int jq = jsh[n][(e < KNN) ? e : (KNN-1)];
                const size_t jrow = (size_t)((b << 10) + jq)*256 + 128;
                pj[n][0][rr] = P[jrow + chan0];
                pj[n][1][rr] = P[jrow + chan1];
            }
        }
        #pragma unroll
        for (int n = 0; n < 4; ++n)
            #pragma unroll
            for (int rr = 0; rr < 4; ++rr) {
                const int row = quad*4 + rr;
                smem[n*NREG + row*SSTR + chan0] = f2bf(silu_f(acc1[n][0][rr] + pn[n][0] + pj[n][0][rr]));
                smem[n*NREG + row*SSTR + chan1] = f2bf(silu_f(acc1[n][1][rr] + pn[n][1] + pj[n][1][rr]));
            }
    }
    v8bf B2[2][4];
    #pragma unroll
    for (int c2 = 0; c2 < 2; ++c2) {
        const int ct = wv*2 + c2;
        #pragma unroll
        for (int ks = 0; ks < 4; ++ks)
            B2[c2][ks] = *(const v8bf*)(We2t + (size_t)(ct*16 + r16)*128 + ks*32 + quad*8);
    }
    __syncthreads();

    // ---- layer 2 MFMA ----
    v4f acc2[4][2];
    #pragma unroll
    for (int n = 0; n < 4; ++n) { acc2[n][0] = (v4f){0,0,0,0}; acc2[n][1] = (v4f){0,0,0,0}; }
    #pragma unroll
    for (int n = 0; n < 4; ++n) {
        v8bf a[4];
        #pragma unroll
        for (int ks = 0; ks < 4; ++ks)
            a[ks] = *(const v8bf*)(smem + n*NREG + r16*SSTR + ks*32 + quad*8);
        #pragma unroll
        for (int ks = 0; ks < 4; ++ks) {
            acc2[n][0] = __builtin_amdgcn_mfma_f32_16x16x32_bf16(a[ks], B2[0][ks], acc2[n][0], 0, 0, 0);
            acc2[n][1] = __builtin_amdgcn_mfma_f32_16x16x32_bf16(a[ks], B2[1][ks], acc2[n][1], 0, 0, 0);
        }
    }
    __syncthreads();

    // ---- epilogue 2 ----
    {
        const float be2c0 = be2[chan0], be2c1 = be2[chan1];
        #pragma unroll
        for (int n = 0; n < 4; ++n) {
            float m0[4], m1[4];
            float s0 = 0.0f, s1 = 0.0f;
            #pragma unroll
            for (int rr = 0; rr < 4; ++rr) {
                m0[rr] = acc2[n][0][rr] + be2c0;
                m1[rr] = acc2[n][1][rr] + be2c1;
                if (quad*4 + rr < KNN) { s0 += m0[rr]; s1 += m1[rr]; }
            }
            s0 += __shfl_xor(s0, 16); s0 += __shfl_xor(s0, 32);
            s1 += __shfl_xor(s1, 16); s1 += __shfl_xor(s1, 32);
            if (quad == 0) {
                msum[(size_t)(node0 + n)*128 + chan0] = s0;
                msum[(size_t)(node0 + n)*128 + chan1] = s1;
            }
            #pragma unroll
            for (int rr = 0; rr < 4; ++rr) {
                const int row = quad*4 + rr;
                smem[n*NREG + row*SSTR + chan0] = f2bf(silu_f(m0[rr]));
                smem[n*NREG + row*SSTR + chan1] = f2bf(silu_f(m1[rr]));
            }
        }
    }
    v8bf B3[2][4];
    #pragma unroll
    for (int c2 = 0; c2 < 2; ++c2) {
        const int ct = wv*2 + c2;
        #pragma unroll
        for (int ks = 0; ks < 4; ++ks)
            B3[c2][ks] = *(const v8bf*)(Wx1t + (size_t)(ct*16 + r16)*128 + ks*32 + quad*8);
    }
    __syncthreads();

    // ---- layer 3 MFMA ----
    v4f acc3[4][2];
    #pragma unroll
    for (int n = 0; n < 4; ++n) { acc3[n][0] = (v4f){0,0,0,0}; acc3[n][1] = (v4f){0,0,0,0}; }
    #pragma unroll
    for (int n = 0; n < 4; ++n) {
        v8bf a[4];
        #pragma unroll
        for (int ks = 0; ks < 4; ++ks)
            a[ks] = *(const v8bf*)(smem + n*NREG + r16*SSTR + ks*32 + quad*8);
        #pragma unroll
        for (int ks = 0; ks < 4; ++ks) {
            acc3[n][0] = __builtin_amdgcn_mfma_f32_16x16x32_bf16(a[ks], B3[0][ks], acc3[n][0], 0, 0, 0);
            acc3[n][1] = __builtin_amdgcn_mfma_f32_16x16x32_bf16(a[ks], B3[1][ks], acc3[n][1], 0, 0, 0);
        }
    }

    // ---- epilogue 3 ----
    {
        const float bxc0 = bx1[chan0], bxc1 = bx1[chan1];
        const float wxc0 = Wx2[chan0], wxc1 = Wx2[chan1];
        #pragma unroll
        for (int n = 0; n < 4; ++n) {
            float pr[4];
            #pragma unroll
            for (int rr = 0; rr < 4; ++rr)
                pr[rr] = silu_f(acc3[n][0][rr] + bxc0) * wxc0
                       + silu_f(acc3[n][1][rr] + bxc1) * wxc1;
            #pragma unroll
            for (int rr = 0; rr < 4; ++rr) {
                pr[rr] += __shfl_xor(pr[rr], 1);
                pr[rr] += __shfl_xor(pr[rr], 2);
                pr[rr] += __shfl_xor(pr[rr], 4);
                pr[rr] += __shfl_xor(pr[rr], 8);
            }
            if (r16 == 0) {
                #pragma unroll
                for (int rr = 0; rr < 4; ++rr) {
                    const int e = quad*4 + rr;
                    if (e < KNN) wred[n][e][wv] = pr[rr];
                }
            }
        }
    }
    __syncthreads();
    if (tid < 4*KNN) {
        const int n = tid / KNN, e = tid % KNN;
        wbuf[(size_t)(node0 + n)*KNN + e] =
            wred[n][e][0] + wred[n][e][1] + wred[n][e][2] + wred[n][e][3] + bx2[0];
    }
}

// ---------------- K5: fused node pipeline, all-MFMA ----------------
__global__ __launch_bounds__(256) void k_nodeF(
    const float* __restrict__ X, const float* __restrict__ Hh,
    const float* __restrict__ msum, const int* __restrict__ idxb,
    const float* __restrict__ wbuf,
    const unsigned short* __restrict__ Wh1t, const float* __restrict__ bh1,
    const unsigned short* __restrict__ Wh2t, const float* __restrict__ bh2,
    const unsigned short* __restrict__ Wd1t, const float* __restrict__ bd1,
    const int* __restrict__ S, const float* __restrict__ emb,
    const unsigned short* __restrict__ Wp1t, const float* __restrict__ bp1,
    const unsigned short* __restrict__ Wr1t, const float* __restrict__ br1,
    const float* __restrict__ Wr2, const float* __restrict__ br2,
    float* __restrict__ Hn, float* __restrict__ AB,
    float* __restrict__ outL, float* __restrict__ outX)
{
    __shared__ __align__(16) unsigned short A0[16*268];
    __shared__ __align__(16) unsigned short A1[16*140];
    __shared__ __align__(16) unsigned short A2[16*140];
    __shared__ __align__(16) unsigned short A3[16*140];
    __shared__ int sInt[16];
    float* A4 = (float*)A0;

    const int tid  = threadIdx.x;
    const int wv   = tid >> 6, lane = tid & 63;
    const int quad = lane >> 4, r16 = lane & 15;
    const int base = blockIdx.x * 16;

    if (tid < 16) sInt[tid] = S[base + tid];
    for (int r = 0; r < 16; ++r) {
        const int node = base + r;
        const float v = (tid < 128) ? Hh[(size_t)node*128 + tid]
                                    : msum[(size_t)node*128 + (tid - 128)];
        A0[r*268 + tid] = f2bf(silu_f(v));
    }
    __syncthreads();

    // MM1
    {
        v8bf a[8];
        #pragma unroll
        for (int ks = 0; ks < 8; ++ks)
            a[ks] = *(const v8bf*)(A0 + r16*268 + ks*32 + quad*8);
        #pragma unroll
        for (int c2 = 0; c2 < 2; ++c2) {
            const int ch = (wv*2 + c2)*16 + r16;
            v4f acc = (v4f){0,0,0,0};
            #pragma unroll
            for (int ks = 0; ks < 8; ++ks) {
                const v8bf bb = *(const v8bf*)(Wh1t + (size_t)ch*256 + ks*32 + quad*8);
                acc = __builtin_amdgcn_mfma_f32_16x16x32_bf16(a[ks], bb, acc, 0, 0, 0);
            }
            const float bc = bh1[ch];
            #pragma unroll
            for (int rr = 0; rr < 4; ++rr)
                A1[(quad*4 + rr)*140 + ch] = f2bf(silu_f(acc[rr] + bc));
        }
    }
    __syncthreads();

    // MM2
    {
        v8bf a[4];
        #pragma unroll
        for (int ks = 0; ks < 4; ++ks)
            a[ks] = *(const v8bf*)(A1 + r16*140 + ks*32 + quad*8);
        #pragma unroll
        for (int c2 = 0; c2 < 2; ++c2) {
            const int ch = (wv*2 + c2)*16 + r16;
            v4f acc = (v4f){0,0,0,0};
            #pragma unroll
            for (int ks = 0; ks < 4; ++ks) {
                const v8bf bb = *(const v8bf*)(Wh2t + (size_t)ch*128 + ks*32 + quad*8);
                acc = __builtin_amdgcn_mfma_f32_16x16x32_bf16(a[ks], bb, acc, 0, 0, 0);
            }
            const float bc = bh2[ch];
            #pragma unroll
            for (int rr = 0; rr < 4; ++rr) {
                const int row = quad*4 + rr;
                const int node = base + row;
                const float hn = Hh[(size_t)node*128 + ch] + acc[rr] + bc;
                Hn[(size_t)node*128 + ch] = hn;
                A2[row*140 + ch] = f2bf(silu_f(hn));
            }
        }
    }
    __syncthreads();

    // MM3 + MM4
    {
        v8bf a[4];
        #pragma unroll
        for (int ks = 0; ks < 4; ++ks)
            a[ks] = *(const v8bf*)(A2 + r16*140 + ks*32 + quad*8);

        #pragma unroll
        for (int cg = 0; cg < 2; ++cg) {
            #pragma unroll
            for (int c2 = 0; c2 < 2; ++c2) {
                const int ch = (wv*4 + cg*2 + c2)*16 + r16;
                v4f acc = (v4f){0,0,0,0};
                #pragma unroll
                for (int ks = 0; ks < 4; ++ks) {
                    const v8bf bb = *(const v8bf*)(Wd1t + (size_t)ch*128 + ks*32 + quad*8);
                    acc = __builtin_amdgcn_mfma_f32_16x16x32_bf16(a[ks], bb, acc, 0, 0, 0);
                }
                const float fb = (ch < 128) ? bd1[ch] : 0.0f;
                #pragma unroll
                for (int rr = 0; rr < 4; ++rr)
                    AB[(size_t)(base + quad*4 + rr)*256 + ch] = acc[rr] + fb;
            }
        }

        #pragma unroll
        for (int c2 = 0; c2 < 2; ++c2) {
            const int ch = (wv*2 + c2)*16 + r16;
            v4f acc = (v4f){0,0,0,0};
            #pragma unroll
            for (int ks = 0; ks < 4; ++ks) {
                const v8bf bb = *(const v8bf*)(Wp1t + (size_t)ch*128 + ks*32 + quad*8);
                acc = __builtin_amdgcn_mfma_f32_16x16x32_bf16(a[ks], bb, acc, 0, 0, 0);
            }
            const float bc = bp1[ch];
            #pragma unroll
            for (int rr = 0; rr < 4; ++rr) {
                const int row = quad*4 + rr;
                const float g = 1.0f / (1.0f + __expf(-(acc[rr] + bc)));
                const float x = emb[sInt[row]*128 + ch] * g;
                A3[row*140 + ch] = f2bf(silu_f(x));
            }
        }
    }
    __syncthreads();

    // MM5
    {
        v8bf a[4];
        #pragma unroll
        for (int ks = 0; ks < 4; ++ks)
            a[ks] = *(const v8bf*)(A3 + r16*140 + ks*32 + quad*8);
        #pragma unroll
        for (int c2 = 0; c2 < 2; ++c2) {
            const int ch = (wv*2 + c2)*16 + r16;
            v4f acc = (v4f){0,0,0,0};
            #pragma unroll
            for (int ks = 0; ks < 4; ++ks) {
                const v8bf bb = *(const v8bf*)(Wr1t + (size_t)ch*128 + ks*32 + quad*8);
                acc = __builtin_amdgcn_mfma_f32_16x16x32_bf16(a[ks], bb, acc, 0, 0, 0);
            }
            const float bc = br1[ch];
            #pragma unroll
            for (int rr = 0; rr < 4; ++rr)
                A4[(quad*4 + rr)*134 + ch] = silu_f(acc[rr] + bc);
        }
    }
    __syncthreads();

    for (int o = tid; o < 16*NCLS; o += 256) {
        const int r = o / NCLS, j = o % NCLS;
        float s = 0.0f;
        for (int i = 0; i < 128; ++i) s += A4[r*134 + i] * Wr2[i*NCLS + j];
        outL[(size_t)(base + r)*NCLS + j] = s + br2[j];
    }

    for (int o = tid; o < 16*CC*3; o += 256) {
        const int r = o / (CC*3), q = o % (CC*3);
        const int node = base + r;
        const int bq = node >> 10;
        const int cq = q / 3, dc = q % 3;
        const float xv = X[((size_t)node*CC + cq)*3 + dc];
        float a = 0.0f;
        for (int k = 0; k < KNN; ++k) {
            const int j = idxb[(size_t)node*KNN + k];
            const float xj = X[(((size_t)(bq << 10) + j)*CC + cq)*3 + dc];
            a += (xv - xj) * wbuf[(size_t)node*KNN + k];
        }
        outX[(size_t)node*CC*3 + q] = xv + a / 9.0f;
    }
}

// ---------------- K6: pd, 8 nodes/block ----------------
__global__ __launch_bounds__(256) void k_pd2(
    const float* __restrict__ AB, const int* __restrict__ idxb,
    const float* __restrict__ Wd2, const float* __restrict__ bd2,
    float* __restrict__ outPd)
{
    const int tid  = threadIdx.x;
    const int lane = tid & 63, wv = tid >> 6;
    const int c0   = lane, c1 = lane + 64;
    const float w0 = Wd2[c0], w1 = Wd2[c1];
    const float b2 = 2.0f * bd2[0];

    #pragma unroll
    for (int s = 0; s < 2; ++s) {
        const int node = blockIdx.x * 8 + wv*2 + s;
        const int b    = node >> 10;

        int jv = 0;
        if (lane < KNN) jv = idxb[(size_t)node*KNN + lane];

        const float An0 = AB[(size_t)node*256 + c0];
        const float An1 = AB[(size_t)node*256 + c1];
        const float Bn0 = AB[(size_t)node*256 + 128 + c0];
        const float Bn1 = AB[(size_t)node*256 + 128 + c1];

        float Aj0[KNN], Aj1[KNN], Bj0[KNN], Bj1[KNN];
        #pragma unroll
        for (int e = 0; e < KNN; ++e) {
            const size_t jn = (size_t)((b << 10) + __shfl(jv, e)) * 256;
            Aj0[e] = AB[jn + c0];       Aj1[e] = AB[jn + c1];
            Bj0[e] = AB[jn + 128 + c0]; Bj1[e] = AB[jn + 128 + c1];
        }
        #pragma unroll
        for (int e = 0; e < KNN; ++e) {
            float p = (silu_f(An0 + Bj0[e]) + silu_f(Aj0[e] + Bn0)) * w0
                    + (silu_f(An1 + Bj1[e]) + silu_f(Aj1[e] + Bn1)) * w1;
            #pragma unroll
            for (int off = 32; off; off >>= 1) p += __shfl_xor(p, off, 64);
            if (lane == 0) outPd[(size_t)node*KNN + e] = p + b2;
        }
    }
}

extern "C" void kernel_launch(void* const* d_in, const int* in_sizes, int n_in,
                              void* d_out, int out_size, void* d_ws, size_t ws_size,
                              hipStream_t stream)
{
    const float* X   = (const float*)d_in[0];
    const int*   S   = (const int*)  d_in[1];
    const float* t   = (const float*)d_in[2];
    const float* emb = (const float*)d_in[3];
    const float* Wt1 = (const float*)d_in[4];
    const float* bt1 = (const float*)d_in[5];
    const float* Wt2 = (const float*)d_in[6];
    const float* bt2 = (const float*)d_in[7];
    const float* We1 = (const float*)d_in[8];
    const float* be1 = (const float*)d_in[9];
    const float* We2 = (const float*)d_in[10];
    const float* be2 = (const float*)d_in[11];
    const float* Wx1 = (const float*)d_in[12];
    const float* bx1 = (const float*)d_in[13];
    const float* Wx2 = (const float*)d_in[14];
    const float* bx2 = (const float*)d_in[15];
    const float* Wh1 = (const float*)d_in[16];
    const float* bh1 = (const float*)d_in[17];
    const float* Wh2 = (const float*)d_in[18];
    const float* bh2 = (const float*)d_in[19];
    const float* Wd1 = (const float*)d_in[20];
    const float* bd1 = (const float*)d_in[21];
    const float* Wd2 = (const float*)d_in[22];
    const float* bd2 = (const float*)d_in[23];
    const float* Wp1 = (const float*)d_in[24];
    const float* bp1 = (const float*)d_in[25];
    const float* Wr1 = (const float*)d_in[26];
    const float* br1 = (const float*)d_in[27];
    const float* Wr2 = (const float*)d_in[28];
    const float* br2 = (const float*)d_in[29];

    float* out   = (float*)d_out;
    float* outL  = out;
    float* outX  = out + (size_t)BN*NCLS;
    float* outPd = outX + (size_t)BN*CC*3;

    unsigned short* WeRt  = (unsigned short*)d_ws;   // 28672
    unsigned short* We2t  = WeRt  + 28672;           // 16384
    unsigned short* Wx1t  = We2t  + 16384;           // 16384
    unsigned short* Wh1t  = Wx1t  + 16384;           // 32768
    unsigned short* Wh2t  = Wh1t  + 32768;           // 16384
    unsigned short* Wd1t  = Wh2t  + 16384;           // 32768
    unsigned short* Wp1t  = Wd1t  + 32768;           // 16384
    unsigned short* Wr1t  = Wp1t  + 16384;           // 16384
    unsigned short* Wt1t  = Wr1t  + 16384;           // 16384
    unsigned short* Wt2t  = Wt1t  + 16384;           // 16384
    unsigned short* We1Ft = Wt2t  + 16384;           // 32768
    float* Hh   = (float*)(We1Ft + 32768);
    float* msum = Hh   + (size_t)BN*EDIM;
    float* Hn   = msum + (size_t)BN*HDIM;
    float* wbuf = Hn   + (size_t)BN*EDIM;
    float* P    = wbuf + (size_t)BN*KNN;            // BN*256, reused as AB
    int*   idxb = (int*)(P + (size_t)BN*256);

    k_prep  <<<944,    256, 0, stream>>>(We1, We2, Wx1, Wh1, Wh2, Wd1, Wp1, Wr1, Wt1, Wt2,
                                         WeRt, We2t, Wx1t, Wh1t, Wh2t, Wd1t, Wp1t, Wr1t,
                                         Wt1t, Wt2t, We1Ft);
    k_hhP   <<<BN/16,  256, 0, stream>>>(t, S, emb, Wt1t, bt1, Wt2t, bt2, We1Ft, be1, Hh, P);
    k_knn   <<<BN/64,  256, 0, stream>>>(X, idxb);
    k_edge  <<<BN/4,   256, 0, stream>>>(X, idxb, P, WeRt, We2t, Wx1t,
                                         be2, bx1, Wx2, bx2, msum, wbuf);
    k_nodeF <<<BN/16,  256, 0, stream>>>(X, Hh, msum, idxb, wbuf,
                                         Wh1t, bh1, Wh2t, bh2, Wd1t, bd1,
                                         S, emb, Wp1t, bp1, Wr1t, br1, Wr2, br2,
                                         Hn, P, outL, outX);
    k_pd2   <<<BN/8,   256, 0, stream>>>(P, idxb, Wd2, bd2, outPd);
}

// Round 8
// 503.860 us; speedup vs baseline: 5.7139x; 1.1406x over previous
//
#include <hip/hip_runtime.h>

#define BATCH 32
#define NPT   1024
#define CC    14
#define KNN   9
#define EDIM  128
#define HDIM  128
#define NCLS  25
#define BN    (BATCH*NPT)

#define RSTR  236     // radF row stride (ushort), 118 dw ≡ 22 mod 32
#define SSTR  140     // sil row stride (ushort), 70 dw ≡ 6 mod 32

typedef float  v4f __attribute__((ext_vector_type(4)));
typedef __bf16 v8bf __attribute__((ext_vector_type(8)));

__device__ __forceinline__ float silu_f(float x) {
    const float e = __expf(-x);
    return x * __builtin_amdgcn_rcpf(1.0f + e);
}
__device__ __forceinline__ float sigm_f(float x) {
    const float e = __expf(-x);
    return __builtin_amdgcn_rcpf(1.0f + e);
}

__device__ __forceinline__ unsigned short f2bf_rne(float f) {
    union { float f; unsigned u; } v; v.f = f;
    unsigned r = v.u + 0x7fffu + ((v.u >> 16) & 1u);
    return (unsigned short)(r >> 16);
}
__device__ __forceinline__ unsigned short f2bf(float f) {
    union { float f; unsigned u; } v; v.f = f;
    return (unsigned short)((v.u + 0x8000u) >> 16);
}

// ---------------- K0: weight prep (transpose + bf16) ----------------
__global__ __launch_bounds__(256) void k_prep(
    const float* __restrict__ We1, const float* __restrict__ We2,
    const float* __restrict__ Wx1, const float* __restrict__ Wh1,
    const float* __restrict__ Wh2, const float* __restrict__ Wd1,
    const float* __restrict__ Wp1, const float* __restrict__ Wr1,
    const float* __restrict__ Wt1, const float* __restrict__ Wt2,
    unsigned short* __restrict__ WeRt, unsigned short* __restrict__ We2t,
    unsigned short* __restrict__ Wx1t, unsigned short* __restrict__ Wh1t,
    unsigned short* __restrict__ Wh2t, unsigned short* __restrict__ Wd1t,
    unsigned short* __restrict__ Wp1t, unsigned short* __restrict__ Wr1t,
    unsigned short* __restrict__ Wt1t, unsigned short* __restrict__ Wt2t,
    unsigned short* __restrict__ We1Ft)
{
    int i = blockIdx.x * 256 + threadIdx.x;
    if (i < 128*224) {
        const int chan = i / 224, k = i % 224;
        WeRt[i] = (k < 196) ? f2bf_rne(We1[(size_t)(256 + k)*128 + chan]) : (unsigned short)0;
        return;
    }
    i -= 128*224;
    if (i < 16384) { We2t[i] = f2bf_rne(We2[(size_t)(i % 128)*128 + i/128]); return; }
    i -= 16384;
    if (i < 16384) { Wx1t[i] = f2bf_rne(Wx1[(size_t)(i % 128)*128 + i/128]); return; }
    i -= 16384;
    if (i < 32768) { const int c = i/256, k = i%256; Wh1t[i] = f2bf_rne(Wh1[(size_t)k*128 + c]); return; }
    i -= 32768;
    if (i < 16384) { Wh2t[i] = f2bf_rne(Wh2[(size_t)(i % 128)*128 + i/128]); return; }
    i -= 16384;
    if (i < 32768) {
        const int t = i/128, k = i%128;
        Wd1t[i] = f2bf_rne((t < 128) ? Wd1[(size_t)k*128 + t] : Wd1[(size_t)(128 + k)*128 + (t - 128)]);
        return;
    }
    i -= 32768;
    if (i < 16384) { Wp1t[i] = f2bf_rne(Wp1[(size_t)(i % 128)*128 + i/128]); return; }
    i -= 16384;
    if (i < 16384) { Wr1t[i] = f2bf_rne(Wr1[(size_t)(i % 128)*128 + i/128]); return; }
    i -= 16384;
    if (i < 16384) { Wt1t[i] = f2bf_rne(Wt1[(size_t)(i % 128)*128 + i/128]); return; }
    i -= 16384;
    if (i < 16384) { Wt2t[i] = f2bf_rne(Wt2[(size_t)(i % 128)*128 + i/128]); return; }
    i -= 16384;
    if (i < 32768) {
        const int t = i/128, k = i%128;
        We1Ft[i] = f2bf_rne((t < 128) ? We1[(size_t)k*128 + t] : We1[(size_t)(128 + k)*128 + (t - 128)]);
    }
}

// ---------------- K1: fused Hh + P, all-MFMA ----------------
__global__ __launch_bounds__(256) void k_hhP(
    const float* __restrict__ t, const int* __restrict__ S,
    const float* __restrict__ emb,
    const unsigned short* __restrict__ Wt1t, const float* __restrict__ bt1,
    const unsigned short* __restrict__ Wt2t, const float* __restrict__ bt2,
    const unsigned short* __restrict__ We1Ft, const float* __restrict__ be1,
    float* __restrict__ Hh, float* __restrict__ P)
{
    __shared__ __align__(16) unsigned short A0[16*140];
    __shared__ __align__(16) unsigned short A1[16*140];
    __shared__ __align__(16) unsigned short A2[16*140];
    __shared__ int sInt[16];

    const int tid  = threadIdx.x;
    const int wv   = tid >> 6, lane = tid & 63;
    const int quad = lane >> 4, r16 = lane & 15;
    const int col  = tid & 127, rh = tid >> 7;
    const int base = blockIdx.x * 16;

    if (tid < 16) sInt[tid] = S[base + tid];

    const float step  = 1.0f / 127.0f;
    const float coeff = -0.5f / (step * step);
    const float off   = step * (float)col;
    #pragma unroll
    for (int rr = 0; rr < 8; ++rr) {
        const int r = rh*8 + rr;
        const float d = t[base + r] - off + 1e-6f;
        A0[r*140 + col] = f2bf(__expf(coeff * d * d));
    }
    __syncthreads();

    {
        v8bf a[4];
        #pragma unroll
        for (int ks = 0; ks < 4; ++ks)
            a[ks] = *(const v8bf*)(A0 + r16*140 + ks*32 + quad*8);
        #pragma unroll
        for (int c2 = 0; c2 < 2; ++c2) {
            const int ch = (wv*2 + c2)*16 + r16;
            v4f acc = (v4f){0,0,0,0};
            #pragma unroll
            for (int ks = 0; ks < 4; ++ks) {
                const v8bf bb = *(const v8bf*)(Wt1t + (size_t)ch*128 + ks*32 + quad*8);
                acc = __builtin_amdgcn_mfma_f32_16x16x32_bf16(a[ks], bb, acc, 0, 0, 0);
            }
            const float bc = bt1[ch];
            #pragma unroll
            for (int rr = 0; rr < 4; ++rr)
                A1[(quad*4 + rr)*140 + ch] = f2bf(fmaxf(acc[rr] + bc, 0.0f));
        }
    }
    __syncthreads();

    {
        v8bf a[4];
        #pragma unroll
        for (int ks = 0; ks < 4; ++ks)
            a[ks] = *(const v8bf*)(A1 + r16*140 + ks*32 + quad*8);
        #pragma unroll
        for (int c2 = 0; c2 < 2; ++c2) {
            const int ch = (wv*2 + c2)*16 + r16;
            v4f acc = (v4f){0,0,0,0};
            #pragma unroll
            for (int ks = 0; ks < 4; ++ks) {
                const v8bf bb = *(const v8bf*)(Wt2t + (size_t)ch*128 + ks*32 + quad*8);
                acc = __builtin_amdgcn_mfma_f32_16x16x32_bf16(a[ks], bb, acc, 0, 0, 0);
            }
            const float bc = bt2[ch];
            #pragma unroll
            for (int rr = 0; rr < 4; ++rr) {
                const int row = quad*4 + rr;
                const int node = base + row;
                const float hh = emb[sInt[row]*128 + ch] + acc[rr] + bc;
                Hh[(size_t)node*128 + ch] = hh;
                A2[row*140 + ch] = f2bf(silu_f(hh));
            }
        }
    }
    __syncthreads();

    {
        v8bf a[4];
        #pragma unroll
        for (int ks = 0; ks < 4; ++ks)
            a[ks] = *(const v8bf*)(A2 + r16*140 + ks*32 + quad*8);
        #pragma unroll
        for (int c2 = 0; c2 < 4; ++c2) {
            const int ch = (wv*4 + c2)*16 + r16;
            v4f acc = (v4f){0,0,0,0};
            #pragma unroll
            for (int ks = 0; ks < 4; ++ks) {
                const v8bf bb = *(const v8bf*)(We1Ft + (size_t)ch*128 + ks*32 + quad*8);
                acc = __builtin_amdgcn_mfma_f32_16x16x32_bf16(a[ks], bb, acc, 0, 0, 0);
            }
            const float fb = (ch < 128) ? be1[ch] : 0.0f;
            #pragma unroll
            for (int rr = 0; rr < 4; ++rr)
                P[(size_t)(base + quad*4 + rr)*256 + ch] = acc[rr] + fb;
        }
    }
}

// ---------------- K2: KNN top-9, 4 waves split the scan ----------------
__global__ __launch_bounds__(256) void k_knn(
    const float* __restrict__ X, int* __restrict__ idxb)
{
    __shared__ __align__(16) float4 Cc[NPT];
    __shared__ float dsh[4][64][KNN];
    __shared__ int   ish[4][64][KNN];

    const int tid = threadIdx.x, lane = tid & 63, wv = tid >> 6;
    const int bb = blockIdx.x >> 4;
    const int n0 = (blockIdx.x & 15) << 6;
    const float* Xb = X + (size_t)bb * NPT * 42;

    for (int i = tid; i < NPT; i += 256) {
        const float* p = Xb + (size_t)i*42 + 3;
        Cc[i] = make_float4(p[0], p[1], p[2], 0.0f);
    }
    __syncthreads();

    const int n = n0 + lane;
    const float4 c = Cc[n];

    float dist[KNN]; int ind[KNN];
    #pragma unroll
    for (int k = 0; k < KNN; ++k) { dist[k] = 3.0e38f; ind[k] = -1; }

    const int j0 = wv * 256;
    for (int jj = 0; jj < 256; ++jj) {
        const int j = j0 + jj;
        const float4 q = Cc[j];
        const float dx = __fsub_rn(c.x, q.x);
        const float dy = __fsub_rn(c.y, q.y);
        const float dz = __fsub_rn(c.z, q.z);
        float d = __fadd_rn(__fadd_rn(__fmul_rn(dx,dx), __fmul_rn(dy,dy)), __fmul_rn(dz,dz));
        if (j == n) d = __fadd_rn(d, 1e10f);
        if (d < dist[KNN-1]) {
            dist[KNN-1] = d; ind[KNN-1] = j;
            #pragma unroll
            for (int p = KNN-1; p > 0; --p) {
                if (dist[p] < dist[p-1]) {
                    float td = dist[p]; dist[p] = dist[p-1]; dist[p-1] = td;
                    int   ti = ind[p];  ind[p]  = ind[p-1];  ind[p-1]  = ti;
                }
            }
        }
    }
    #pragma unroll
    for (int k = 0; k < KNN; ++k) { dsh[wv][lane][k] = dist[k]; ish[wv][lane][k] = ind[k]; }
    __syncthreads();

    if (tid < 64) {
        float fd[KNN]; int fi[KNN];
        #pragma unroll
        for (int k = 0; k < KNN; ++k) { fd[k] = 3.0e38f; fi[k] = -1; }
        for (int w = 0; w < 4; ++w)
            #pragma unroll
            for (int k = 0; k < KNN; ++k) {
                const float d = dsh[w][tid][k];
                const int   i = ish[w][tid][k];
                if (d < fd[KNN-1]) {
                    fd[KNN-1] = d; fi[KNN-1] = i;
                    #pragma unroll
                    for (int p = KNN-1; p > 0; --p) {
                        if (fd[p] < fd[p-1]) {
                            float td = fd[p]; fd[p] = fd[p-1]; fd[p-1] = td;
                            int   ti = fi[p]; fi[p] = fi[p-1]; fi[p-1] = ti;
                        }
                    }
                }
            }
        const int node = (bb << 10) + n0 + tid;
        #pragma unroll
        for (int k = 0; k < KNN; ++k) idxb[(size_t)node*KNN + k] = fi[k];
    }
}

// ---------------- K4: MFMA edge pipeline — row=node, tile=edge-slot ----------------
// Block = 16 nodes. For each of the 9 edge-slots: one 16-row MFMA tile
// (row r = node r's t-th edge) — zero row padding. msum accumulates in
// registers across the tile loop (rows ARE nodes). 4 waves ct-split the
// 128 output channels; B-fragments reused across all 9 tiles.
__global__ __launch_bounds__(256) void k_edge(
    const float* __restrict__ X, const int* __restrict__ idxb,
    const float* __restrict__ P,
    const unsigned short* __restrict__ WeRt,
    const unsigned short* __restrict__ We2t,
    const unsigned short* __restrict__ Wx1t,
    const float* __restrict__ be2,
    const float* __restrict__ bx1, const float* __restrict__ Wx2,
    const float* __restrict__ bx2,
    float* __restrict__ msum, float* __restrict__ wbuf)
{
    __shared__ unsigned short radF[16*RSTR];           // 7552 B
    __shared__ unsigned short silA[16*SSTR];           // 4480 B
    __shared__ unsigned short silB[16*SSTR];           // 4480 B
    __shared__ __align__(16) float relS[16][57];       // 3648 B
    __shared__ __align__(16) float xS[16][57];         // 3648 B
    __shared__ float wred[KNN][16][4];                 // 2304 B
    __shared__ int   jsh[16][12];                      //  768 B

    const int tid  = threadIdx.x;
    const int wv   = tid >> 6, lane = tid & 63;
    const int quad = lane >> 4, r16 = lane & 15;
    const int node0 = blockIdx.x * 16;
    const int b     = node0 >> 10;
    const int chan0 = (wv*2 + 0)*16 + r16;
    const int chan1 = (wv*2 + 1)*16 + r16;
    const int srow  = tid >> 4, c16 = tid & 15;   // staging coords

    // idx + own-node coords (staged once)
    if (tid < 144) jsh[tid/9][tid%9] = idxb[(size_t)(node0 + tid/9)*KNN + tid%9];
    {
        const int i0 = c16*3;
        if (i0 < 42) {
            #pragma unroll
            for (int k = 0; k < 3; ++k)
                xS[srow][c16*4 + k] = X[(size_t)(node0 + srow)*42 + i0 + k];
        }
    }

    // Pn (A-half of layer-1 per-node terms) — constant over tiles
    float pn0[4], pn1[4];
    #pragma unroll
    for (int rr = 0; rr < 4; ++rr) {
        pn0[rr] = P[(size_t)(node0 + quad*4 + rr)*256 + chan0];
        pn1[rr] = P[(size_t)(node0 + quad*4 + rr)*256 + chan1];
    }
    const float be2c0 = be2[chan0], be2c1 = be2[chan1];
    const float bxc0  = bx1[chan0], bxc1  = bx1[chan1];
    const float wxc0  = Wx2[chan0], wxc1  = Wx2[chan1];

    // B-fragments (reused across 9 tiles)
    v8bf B1[2][7], B2[2][4], B3[2][4];
    #pragma unroll
    for (int c2 = 0; c2 < 2; ++c2) {
        const int ct = wv*2 + c2;
        #pragma unroll
        for (int ks = 0; ks < 7; ++ks)
            B1[c2][ks] = *(const v8bf*)(WeRt + (size_t)(ct*16 + r16)*224 + ks*32 + quad*8);
        #pragma unroll
        for (int ks = 0; ks < 4; ++ks) {
            B2[c2][ks] = *(const v8bf*)(We2t + (size_t)(ct*16 + r16)*128 + ks*32 + quad*8);
            B3[c2][ks] = *(const v8bf*)(Wx1t + (size_t)(ct*16 + r16)*128 + ks*32 + quad*8);
        }
    }

    float msA0[4] = {0,0,0,0}, msA1[4] = {0,0,0,0};

    __syncthreads();   // jsh, xS ready

    for (int t = 0; t < KNN; ++t) {
        // ---- stage rel for edge-slot t of all 16 nodes ----
        {
            const int j  = jsh[srow][t];
            const int i0 = c16*3;
            if (i0 < 42) {
                const size_t jb = (size_t)((b << 10) + j)*42;
                #pragma unroll
                for (int k = 0; k < 3; ++k)
                    relS[srow][c16*4 + k] = xS[srow][c16*4 + k] - X[jb + i0 + k];
            }
        }
        __syncthreads();   // A

        // ---- radial -> silu -> bf16 radF ----
        {
            const float* rb = relS[srow];
            #pragma unroll
            for (int kk = 0; kk < 14; ++kk) {
                const int f = c16 + 16*kk;
                if (f < 196) {
                    const int cI = f / 14, eI = f % 14;
                    const float v = (rb[cI*4]*rb[eI*4] + rb[cI*4+1]*rb[eI*4+1]
                                   + rb[cI*4+2]*rb[eI*4+2]) * (1.0f/14.0f);
                    radF[srow*RSTR + f] = f2bf(silu_f(v));
                } else {
                    radF[srow*RSTR + f] = 0;
                }
            }
        }
        __syncthreads();   // B

        // ---- layer 1 MFMA (K=224) ----
        v4f acc10 = (v4f){0,0,0,0}, acc11 = (v4f){0,0,0,0};
        #pragma unroll
        for (int ks = 0; ks < 7; ++ks) {
            const v8bf a = *(const v8bf*)(radF + r16*RSTR + ks*32 + quad*8);
            acc10 = __builtin_amdgcn_mfma_f32_16x16x32_bf16(a, B1[0][ks], acc10, 0, 0, 0);
            acc11 = __builtin_amdgcn_mfma_f32_16x16x32_bf16(a, B1[1][ks], acc11, 0, 0, 0);
        }
        // ep1: + Pn + Pj, silu -> silA
        {
            float pj0[4], pj1[4];
            #pragma unroll
            for (int rr = 0; rr < 4; ++rr) {
                const int jq = jsh[quad*4 + rr][t];
                const size_t jrow = (size_t)((b << 10) + jq)*256 + 128;
                pj0[rr] = P[jrow + chan0];
                pj1[rr] = P[jrow + chan1];
            }
            #pragma unroll
            for (int rr = 0; rr < 4; ++rr) {
                const int rw = quad*4 + rr;
                silA[rw*SSTR + chan0] = f2bf(silu_f(acc10[rr] + pn0[rr] + pj0[rr]));
                silA[rw*SSTR + chan1] = f2bf(silu_f(acc11[rr] + pn1[rr] + pj1[rr]));
            }
        }
        __syncthreads();   // C

        // ---- layer 2 MFMA ----
        v4f acc20 = (v4f){0,0,0,0}, acc21 = (v4f){0,0,0,0};
        #pragma unroll
        for (int ks = 0; ks < 4; ++ks) {
            const v8bf a = *(const v8bf*)(silA + r16*SSTR + ks*32 + quad*8);
            acc20 = __builtin_amdgcn_mfma_f32_16x16x32_bf16(a, B2[0][ks], acc20, 0, 0, 0);
            acc21 = __builtin_amdgcn_mfma_f32_16x16x32_bf16(a, B2[1][ks], acc21, 0, 0, 0);
        }
        // ep2: m, register msum accumulation, silu(m) -> silB
        #pragma unroll
        for (int rr = 0; rr < 4; ++rr) {
            const float m0 = acc20[rr] + be2c0;
            const float m1 = acc21[rr] + be2c1;
            msA0[rr] += m0;  msA1[rr] += m1;
            const int rw = quad*4 + rr;
            silB[rw*SSTR + chan0] = f2bf(silu_f(m0));
            silB[rw*SSTR + chan1] = f2bf(silu_f(m1));
        }
        __syncthreads();   // D

        // ---- layer 3 MFMA ----
        v4f acc30 = (v4f){0,0,0,0}, acc31 = (v4f){0,0,0,0};
        #pragma unroll
        for (int ks = 0; ks < 4; ++ks) {
            const v8bf a = *(const v8bf*)(silB + r16*SSTR + ks*32 + quad*8);
            acc30 = __builtin_amdgcn_mfma_f32_16x16x32_bf16(a, B3[0][ks], acc30, 0, 0, 0);
            acc31 = __builtin_amdgcn_mfma_f32_16x16x32_bf16(a, B3[1][ks], acc31, 0, 0, 0);
        }
        // ep3: w partials -> wred[t]
        #pragma unroll
        for (int rr = 0; rr < 4; ++rr) {
            float pr = silu_f(acc30[rr] + bxc0) * wxc0
                     + silu_f(acc31[rr] + bxc1) * wxc1;
            pr += __shfl_xor(pr, 1);
            pr += __shfl_xor(pr, 2);
            pr += __shfl_xor(pr, 4);
            pr += __shfl_xor(pr, 8);
            if (r16 == 0) wred[t][quad*4 + rr][wv] = pr;
        }
        // no barrier: next tile's relS writes are protected by barrier A
    }

    // msum: complete per-register sums (rows are nodes)
    #pragma unroll
    for (int rr = 0; rr < 4; ++rr) {
        msum[(size_t)(node0 + quad*4 + rr)*128 + chan0] = msA0[rr];
        msum[(size_t)(node0 + quad*4 + rr)*128 + chan1] = msA1[rr];
    }
    __syncthreads();
    if (tid < 16*KNN) {
        const int tt = tid / 16, rw = tid % 16;
        wbuf[(size_t)(node0 + rw)*KNN + tt] =
            wred[tt][rw][0] + wred[tt][rw][1] + wred[tt][rw][2] + wred[tt][rw][3] + bx2[0];
    }
}

// ---------------- K5: fused node pipeline, all-MFMA ----------------
__global__ __launch_bounds__(256) void k_nodeF(
    const float* __restrict__ X, const float* __restrict__ Hh,
    const float* __restrict__ msum, const int* __restrict__ idxb,
    const float* __restrict__ wbuf,
    const unsigned short* __restrict__ Wh1t, const float* __restrict__ bh1,
    const unsigned short* __restrict__ Wh2t, const float* __restrict__ bh2,
    const unsigned short* __restrict__ Wd1t, const float* __restrict__ bd1,
    const int* __restrict__ S, const float* __restrict__ emb,
    const unsigned short* __restrict__ Wp1t, const float* __restrict__ bp1,
    const unsigned short* __restrict__ Wr1t, const float* __restrict__ br1,
    const float* __restrict__ Wr2, const float* __restrict__ br2,
    float* __restrict__ Hn, float* __restrict__ AB,
    float* __restrict__ outL, float* __restrict__ outX)
{
    __shared__ __align__(16) unsigned short A0[16*268];
    __shared__ __align__(16) unsigned short A1[16*140];
    __shared__ __align__(16) unsigned short A2[16*140];
    __shared__ __align__(16) unsigned short A3[16*140];
    __shared__ int sInt[16];
    float* A4 = (float*)A0;

    const int tid  = threadIdx.x;
    const int wv   = tid >> 6, lane = tid & 63;
    const int quad = lane >> 4, r16 = lane & 15;
    const int base = blockIdx.x * 16;

    if (tid < 16) sInt[tid] = S[base + tid];
    for (int r = 0; r < 16; ++r) {
        const int node = base + r;
        const float v = (tid < 128) ? Hh[(size_t)node*128 + tid]
                                    : msum[(size_t)node*128 + (tid - 128)];
        A0[r*268 + tid] = f2bf(silu_f(v));
    }
    __syncthreads();

    // MM1
    {
        v8bf a[8];
        #pragma unroll
        for (int ks = 0; ks < 8; ++ks)
            a[ks] = *(const v8bf*)(A0 + r16*268 + ks*32 + quad*8);
        #pragma unroll
        for (int c2 = 0; c2 < 2; ++c2) {
            const int ch = (wv*2 + c2)*16 + r16;
            v4f acc = (v4f){0,0,0,0};
            #pragma unroll
            for (int ks = 0; ks < 8; ++ks) {
                const v8bf bb = *(const v8bf*)(Wh1t + (size_t)ch*256 + ks*32 + quad*8);
                acc = __builtin_amdgcn_mfma_f32_16x16x32_bf16(a[ks], bb, acc, 0, 0, 0);
            }
            const float bc = bh1[ch];
            #pragma unroll
            for (int rr = 0; rr < 4; ++rr)
                A1[(quad*4 + rr)*140 + ch] = f2bf(silu_f(acc[rr] + bc));
        }
    }
    __syncthreads();

    // MM2
    {
        v8bf a[4];
        #pragma unroll
        for (int ks = 0; ks < 4; ++ks)
            a[ks] = *(const v8bf*)(A1 + r16*140 + ks*32 + quad*8);
        #pragma unroll
        for (int c2 = 0; c2 < 2; ++c2) {
            const int ch = (wv*2 + c2)*16 + r16;
            v4f acc = (v4f){0,0,0,0};
            #pragma unroll
            for (int ks = 0; ks < 4; ++ks) {
                const v8bf bb = *(const v8bf*)(Wh2t + (size_t)ch*128 + ks*32 + quad*8);
                acc = __builtin_amdgcn_mfma_f32_16x16x32_bf16(a[ks], bb, acc, 0, 0, 0);
            }
            const float bc = bh2[ch];
            #pragma unroll
            for (int rr = 0; rr < 4; ++rr) {
                const int row = quad*4 + rr;
                const int node = base + row;
                const float hn = Hh[(size_t)node*128 + ch] + acc[rr] + bc;
                Hn[(size_t)node*128 + ch] = hn;
                A2[row*140 + ch] = f2bf(silu_f(hn));
            }
        }
    }
    __syncthreads();

    // MM3 + MM4
    {
        v8bf a[4];
        #pragma unroll
        for (int ks = 0; ks < 4; ++ks)
            a[ks] = *(const v8bf*)(A2 + r16*140 + ks*32 + quad*8);

        #pragma unroll
        for (int cg = 0; cg < 2; ++cg) {
            #pragma unroll
            for (int c2 = 0; c2 < 2; ++c2) {
                const int ch = (wv*4 + cg*2 + c2)*16 + r16;
                v4f acc = (v4f){0,0,0,0};
                #pragma unroll
                for (int ks = 0; ks < 4; ++ks) {
                    const v8bf bb = *(const v8bf*)(Wd1t + (size_t)ch*128 + ks*32 + quad*8);
                    acc = __builtin_amdgcn_mfma_f32_16x16x32_bf16(a[ks], bb, acc, 0, 0, 0);
                }
                const float fb = (ch < 128) ? bd1[ch] : 0.0f;
                #pragma unroll
                for (int rr = 0; rr < 4; ++rr)
                    AB[(size_t)(base + quad*4 + rr)*256 + ch] = acc[rr] + fb;
            }
        }

        #pragma unroll
        for (int c2 = 0; c2 < 2; ++c2) {
            const int ch = (wv*2 + c2)*16 + r16;
            v4f acc = (v4f){0,0,0,0};
            #pragma unroll
            for (int ks = 0; ks < 4; ++ks) {
                const v8bf bb = *(const v8bf*)(Wp1t + (size_t)ch*128 + ks*32 + quad*8);
                acc = __builtin_amdgcn_mfma_f32_16x16x32_bf16(a[ks], bb, acc, 0, 0, 0);
            }
            const float bc = bp1[ch];
            #pragma unroll
            for (int rr = 0; rr < 4; ++rr) {
                const int row = quad*4 + rr;
                const float g = sigm_f(acc[rr] + bc);
                const float x = emb[sInt[row]*128 + ch] * g;
                A3[row*140 + ch] = f2bf(silu_f(x));
            }
        }
    }
    __syncthreads();

    // MM5
    {
        v8bf a[4];
        #pragma unroll
        for (int ks = 0; ks < 4; ++ks)
            a[ks] = *(const v8bf*)(A3 + r16*140 + ks*32 + quad*8);
        #pragma unroll
        for (int c2 = 0; c2 < 2; ++c2) {
            const int ch = (wv*2 + c2)*16 + r16;
            v4f acc = (v4f){0,0,0,0};
            #pragma unroll
            for (int ks = 0; ks < 4; ++ks) {
                const v8bf bb = *(const v8bf*)(Wr1t + (size_t)ch*128 + ks*32 + quad*8);
                acc = __builtin_amdgcn_mfma_f32_16x16x32_bf16(a[ks], bb, acc, 0, 0, 0);
            }
            const float bc = br1[ch];
            #pragma unroll
            for (int rr = 0; rr < 4; ++rr)
                A4[(quad*4 + rr)*134 + ch] = silu_f(acc[rr] + bc);
        }
    }
    __syncthreads();

    for (int o = tid; o < 16*NCLS; o += 256) {
        const int r = o / NCLS, j = o % NCLS;
        float s = 0.0f;
        for (int i = 0; i < 128; ++i) s += A4[r*134 + i] * Wr2[i*NCLS + j];
        outL[(size_t)(base + r)*NCLS + j] = s + br2[j];
    }

    for (int o = tid; o < 16*CC*3; o += 256) {
        const int r = o / (CC*3), q = o % (CC*3);
        const int node = base + r;
        const int bq = node >> 10;
        const int cq = q / 3, dc = q % 3;
        const float xv = X[((size_t)node*CC + cq)*3 + dc];
        float a = 0.0f;
        for (int k = 0; k < KNN; ++k) {
            const int j = idxb[(size_t)node*KNN + k];
            const float xj = X[(((size_t)(bq << 10) + j)*CC + cq)*3 + dc];
            a += (xv - xj) * wbuf[(size_t)node*KNN + k];
        }
        outX[(size_t)node*CC*3 + q] = xv + a / 9.0f;
    }
}

// ---------------- K6: pd, 8 nodes/block ----------------
__global__ __launch_bounds__(256) void k_pd2(
    const float* __restrict__ AB, const int* __restrict__ idxb,
    const float* __restrict__ Wd2, const float* __restrict__ bd2,
    float* __restrict__ outPd)
{
    const int tid  = threadIdx.x;
    const int lane = tid & 63, wv = tid >> 6;
    const int c0   = lane, c1 = lane + 64;
    const float w0 = Wd2[c0], w1 = Wd2[c1];
    const float b2 = 2.0f * bd2[0];

    #pragma unroll
    for (int s = 0; s < 2; ++s) {
        const int node = blockIdx.x * 8 + wv*2 + s;
        const int b    = node >> 10;

        int jv = 0;
        if (lane < KNN) jv = idxb[(size_t)node*KNN + lane];

        const float An0 = AB[(size_t)node*256 + c0];
        const float An1 = AB[(size_t)node*256 + c1];
        const float Bn0 = AB[(size_t)node*256 + 128 + c0];
        const float Bn1 = AB[(size_t)node*256 + 128 + c1];

        float Aj0[KNN], Aj1[KNN], Bj0[KNN], Bj1[KNN];
        #pragma unroll
        for (int e = 0; e < KNN; ++e) {
            const size_t jn = (size_t)((b << 10) + __shfl(jv, e)) * 256;
            Aj0[e] = AB[jn + c0];       Aj1[e] = AB[jn + c1];
            Bj0[e] = AB[jn + 128 + c0]; Bj1[e] = AB[jn + 128 + c1];
        }
        #pragma unroll
        for (int e = 0; e < KNN; ++e) {
            float p = (silu_f(An0 + Bj0[e]) + silu_f(Aj0[e] + Bn0)) * w0
                    + (silu_f(An1 + Bj1[e]) + silu_f(Aj1[e] + Bn1)) * w1;
            #pragma unroll
            for (int off = 32; off; off >>= 1) p += __shfl_xor(p, off, 64);
            if (lane == 0) outPd[(size_t)node*KNN + e] = p + b2;
        }
    }
}

extern "C" void kernel_launch(void* const* d_in, const int* in_sizes, int n_in,
                              void* d_out, int out_size, void* d_ws, size_t ws_size,
                              hipStream_t stream)
{
    const float* X   = (const float*)d_in[0];
    const int*   S   = (const int*)  d_in[1];
    const float* t   = (const float*)d_in[2];
    const float* emb = (const float*)d_in[3];
    const float* Wt1 = (const float*)d_in[4];
    const float* bt1 = (const float*)d_in[5];
    const float* Wt2 = (const float*)d_in[6];
    const float* bt2 = (const float*)d_in[7];
    const float* We1 = (const float*)d_in[8];
    const float* be1 = (const float*)d_in[9];
    const float* We2 = (const float*)d_in[10];
    const float* be2 = (const float*)d_in[11];
    const float* Wx1 = (const float*)d_in[12];
    const float* bx1 = (const float*)d_in[13];
    const float* Wx2 = (const float*)d_in[14];
    const float* bx2 = (const float*)d_in[15];
    const float* Wh1 = (const float*)d_in[16];
    const float* bh1 = (const float*)d_in[17];
    const float* Wh2 = (const float*)d_in[18];
    const float* bh2 = (const float*)d_in[19];
    const float* Wd1 = (const float*)d_in[20];
    const float* bd1 = (const float*)d_in[21];
    const float* Wd2 = (const float*)d_in[22];
    const float* bd2 = (const float*)d_in[23];
    const float* Wp1 = (const float*)d_in[24];
    const float* bp1 = (const float*)d_in[25];
    const float* Wr1 = (const float*)d_in[26];
    const float* br1 = (const float*)d_in[27];
    const float* Wr2 = (const float*)d_in[28];
    const float* br2 = (const float*)d_in[29];

    float* out   = (float*)d_out;
    float* outL  = out;
    float* outX  = out + (size_t)BN*NCLS;
    float* outPd = outX + (size_t)BN*CC*3;

    unsigned short* WeRt  = (unsigned short*)d_ws;   // 28672
    unsigned short* We2t  = WeRt  + 28672;
    unsigned short* Wx1t  = We2t  + 16384;
    unsigned short* Wh1t  = Wx1t  + 16384;
    unsigned short* Wh2t  = Wh1t  + 32768;
    unsigned short* Wd1t  = Wh2t  + 16384;
    unsigned short* Wp1t  = Wd1t  + 32768;
    unsigned short* Wr1t  = Wp1t  + 16384;
    unsigned short* Wt1t  = Wr1t  + 16384;
    unsigned short* Wt2t  = Wt1t  + 16384;
    unsigned short* We1Ft = Wt2t  + 16384;
    float* Hh   = (float*)(We1Ft + 32768);
    float* msum = Hh   + (size_t)BN*EDIM;
    float* Hn   = msum + (size_t)BN*HDIM;
    float* wbuf = Hn   + (size_t)BN*EDIM;
    float* P    = wbuf + (size_t)BN*KNN;
    int*   idxb = (int*)(P + (size_t)BN*256);

    k_prep  <<<944,    256, 0, stream>>>(We1, We2, Wx1, Wh1, Wh2, Wd1, Wp1, Wr1, Wt1, Wt2,
                                         WeRt, We2t, Wx1t, Wh1t, Wh2t, Wd1t, Wp1t, Wr1t,
                                         Wt1t, Wt2t, We1Ft);
    k_hhP   <<<BN/16,  256, 0, stream>>>(t, S, emb, Wt1t, bt1, Wt2t, bt2, We1Ft, be1, Hh, P);
    k_knn   <<<BN/64,  256, 0, stream>>>(X, idxb);
    k_edge  <<<BN/16,  256, 0, stream>>>(X, idxb, P, WeRt, We2t, Wx1t,
                                         be2, bx1, Wx2, bx2, msum, wbuf);
    k_nodeF <<<BN/16,  256, 0, stream>>>(X, Hh, msum, idxb, wbuf,
                                         Wh1t, bh1, Wh2t, bh2, Wd1t, bd1,
                                         S, emb, Wp1t, bp1, Wr1t, br1, Wr2, br2,
                                         Hn, P, outL, outX);
    k_pd2   <<<BN/8,   256, 0, stream>>>(P, idxb, Wd2, bd2, outPd);
}